// Round 15
// baseline (1516.620 us; speedup 1.0000x reference)
//
#include <hip/hip_runtime.h>
#include <cstdint>
#include <cstddef>

#define B_TOTAL 65536
#define SDIM 64
#define ADIM 32
#define LDIM 64
#define HDIM 1024
#define NEMB 1024
#define TAU 0.125f
#define FMAX 6144

typedef __attribute__((ext_vector_type(8))) short short8;
typedef __attribute__((ext_vector_type(8))) _Float16 half8;
typedef __attribute__((ext_vector_type(4))) float f32x4;

__device__ inline unsigned short f2bf(float f) {
    unsigned int u = __float_as_uint(f);
    u += 0x7fffu + ((u >> 16) & 1u);
    return (unsigned short)(u >> 16);
}
__device__ inline float bf2f(unsigned short s) {
    return __uint_as_float(((unsigned int)s) << 16);
}
__device__ inline unsigned short f2h(float f) {
    _Float16 h = (_Float16)f;
    return __builtin_bit_cast(unsigned short, h);
}
__device__ inline float h2f(unsigned short s) {
    return (float)__builtin_bit_cast(_Float16, s);
}
__device__ inline half8 H8(short8 v) { return __builtin_bit_cast(half8, v); }

// async global->LDS, 16B per lane; LDS dest = wave-uniform base + lane*16.
__device__ inline void gload16(const unsigned short* g, unsigned short* l) {
    __builtin_amdgcn_global_load_lds(
        (__attribute__((address_space(1))) void*)(g),
        (__attribute__((address_space(3))) void*)(l), 16, 0, 0);
}

// exact counted vmcnt (wt always lands on an enumerated value)
__device__ inline void vm_wait(int wt) {
    if (wt >= 16)      asm volatile("s_waitcnt vmcnt(16)" ::: "memory");
    else if (wt >= 12) asm volatile("s_waitcnt vmcnt(12)" ::: "memory");
    else if (wt >= 8)  asm volatile("s_waitcnt vmcnt(8)" ::: "memory");
    else if (wt >= 6)  asm volatile("s_waitcnt vmcnt(6)" ::: "memory");
    else if (wt >= 4)  asm volatile("s_waitcnt vmcnt(4)" ::: "memory");
    else               asm volatile("s_waitcnt vmcnt(0)" ::: "memory");
}

// ---------------------------------------------------------------------------
__global__ void cb_norms(const float* __restrict__ codebook, float* __restrict__ cbn)
{
    int i = blockIdx.x * 256 + threadIdx.x;
    if (i < NEMB) {
        float s = 0.f;
#pragma unroll
        for (int k = 0; k < LDIM; ++k) {
            float v = codebook[(size_t)i * LDIM + k];
            s = fmaf(v, v, s);
        }
        cbn[i] = s;
    }
}

__global__ void zero_ctr(int* ctr) { if (threadIdx.x == 0) *ctr = 0; }

// ---------------------------------------------------------------------------
// Weight pre-transform: W[K][N] fp32 -> MFMA-B-ready plane(s).
// NT==1: bf16 single. NT==2: fp16 single. NT==3: bf16 hi+lo.
// ---------------------------------------------------------------------------
template <int NT, int BN>
__global__ __launch_bounds__(256) void w_xform(
    const float* __restrict__ W, int K, int N,
    unsigned short* __restrict__ Ph, unsigned short* __restrict__ Pl)
{
    __shared__ float Ws[32][BN + 4];
    const int tid = threadIdx.x;
    const int ks = blockIdx.x, nb = blockIdx.y;
    const int k0 = ks * 32, n0 = nb * BN;
    constexpr int LT = 32 * (BN / 4);
#pragma unroll
    for (int it = 0; it < (LT + 255) / 256; ++it) {
        int idx = tid + it * 256;
        if (LT % 256 == 0 || idx < LT) {
            int k = idx / (BN / 4);
            int nf = idx % (BN / 4);
            *(f32x4*)&Ws[k][nf * 4] =
                *(const f32x4*)&W[(size_t)(k0 + k) * N + n0 + nf * 4];
        }
    }
    __syncthreads();
    const int KS = K >> 5;
    size_t bo = ((size_t)nb * KS + ks) * (BN * 32);
    constexpr int WT = BN * 4;
#pragma unroll
    for (int it = 0; it < (WT + 255) / 256; ++it) {
        int idx = tid + it * 256;
        if (WT % 256 == 0 || idx < WT) {
            int kb = idx / BN;
            int n = idx % BN;
            short8 h, l;
#pragma unroll
            for (int j = 0; j < 8; ++j) {
                float x = Ws[kb * 8 + j][n];
                if (NT == 2) {
                    h[j] = (short)f2h(x);
                } else {
                    unsigned short hb_ = f2bf(x);
                    h[j] = (short)hb_;
                    if (NT == 3) l[j] = (short)f2bf(x - bf2f(hb_));
                }
            }
            *(short8*)&Ph[bo + (size_t)idx * 8] = h;
            if (NT == 3) *(short8*)&Pl[bo + (size_t)idx * 8] = l;
        }
    }
}

// ---------------------------------------------------------------------------
// OLD proven BF16/FP16 MFMA GEMM, 2-buf full-drain (fallback only).
// ---------------------------------------------------------------------------
template <int NT, int BN, int OUT, int ACT>
__global__ __launch_bounds__(256, 2) void mfma_gemm(
    const unsigned short* __restrict__ Ah_g, const unsigned short* __restrict__ Al_g,
    int K,
    const unsigned short* __restrict__ Wh, const unsigned short* __restrict__ Wl,
    const float* __restrict__ bias,
    void* __restrict__ out0, void* __restrict__ out1, int NTOT)
{
    constexpr int NWC = (BN == 128) ? 2 : 1;
    constexpr int WM = (BN == 128) ? 4 : 2;
    constexpr int WN = (BN == 32) ? 2 : 4;
    constexpr int ABUF = (NT >= 2) ? 8192 : 4096;
    constexpr int BBUF = 4 * BN * 8 * ((NT == 3) ? 2 : 1);
    constexpr int BUFSH = ABUF + BBUF;

    __shared__ unsigned short smem[2 * BUFSH];

    const int tid = threadIdx.x;
    int row_t, nb;
    if constexpr (BN == 128) {
        int per = gridDim.x >> 3;
        int xcd = blockIdx.x & 7;
        int lid = blockIdx.x >> 3;
        int tile = xcd * per + lid;
        row_t = tile >> 3;
        nb = tile & 7;
    } else {
        row_t = blockIdx.x;
        nb = 0;
    }
    const int m0 = row_t * 128;
    const int n0 = nb * BN;
    const int w = tid >> 6, lane = tid & 63;
    const int g = lane >> 4, lr = lane & 15;
    const int wrow0 = (w / NWC) * (WM * 16);
    const int wcol0 = (w % NWC) * (WN * 16);
    const int KS = K >> 5;

    auto stage = [&](unsigned short* buf, int ks) {
        unsigned short* Ah = buf;
        unsigned short* Al = buf + 4096;
        unsigned short* Bh = buf + ABUF;
        unsigned short* Bl = Bh + 4 * BN * 8;
#pragma unroll
        for (int it = 0; it < 2; ++it) {
            int t0 = it * 256 + w * 64;
            int t = t0 + lane;
            int row = t & 127, kb = t >> 7;
            size_t go = (size_t)(m0 + row) * K + ks * 32 + kb * 8;
            gload16(Ah_g + go, Ah + (size_t)t0 * 8);
            if constexpr (NT >= 2) gload16(Al_g + go, Al + (size_t)t0 * 8);
        }
        size_t bo = ((size_t)nb * KS + ks) * (BN * 32);
        constexpr int BT = 4 * BN;
#pragma unroll
        for (int it = 0; it < BT / 256; ++it) {
            int t0 = it * 256 + w * 64;
            size_t go = bo + (size_t)(t0 + lane) * 8;
            gload16(Wh + go, Bh + (size_t)t0 * 8);
            if constexpr (NT == 3) gload16(Wl + go, Bl + (size_t)t0 * 8);
        }
    };

    f32x4 acc[WM][WN];
#pragma unroll
    for (int m = 0; m < WM; ++m)
#pragma unroll
        for (int n = 0; n < WN; ++n) {
            acc[m][n][0] = 0.f; acc[m][n][1] = 0.f;
            acc[m][n][2] = 0.f; acc[m][n][3] = 0.f;
        }

    stage(smem, 0);

    for (int ks = 0; ks < KS; ++ks) {
        __syncthreads();
        unsigned short* buf = smem + (size_t)(ks & 1) * BUFSH;
        if (ks + 1 < KS)
            stage(smem + (size_t)((ks + 1) & 1) * BUFSH, ks + 1);

        unsigned short* Ah = buf;
        unsigned short* Al = buf + 4096;
        unsigned short* Bh = buf + ABUF;
        unsigned short* Bl = Bh + 4 * BN * 8;

        short8 ah[WM], bh[WN];
        short8 al[WM], bl[WN];
#pragma unroll
        for (int m = 0; m < WM; ++m) {
            int ro = (g << 7) + wrow0 + m * 16 + lr;
            ah[m] = *(const short8*)&Ah[ro * 8];
            if constexpr (NT >= 2) al[m] = *(const short8*)&Al[ro * 8];
        }
#pragma unroll
        for (int n = 0; n < WN; ++n) {
            int co = g * BN + wcol0 + n * 16 + lr;
            bh[n] = *(const short8*)&Bh[co * 8];
            if constexpr (NT == 3) bl[n] = *(const short8*)&Bl[co * 8];
        }
#pragma unroll
        for (int m = 0; m < WM; ++m)
#pragma unroll
            for (int n = 0; n < WN; ++n) {
                if constexpr (NT == 2) {
                    acc[m][n] = __builtin_amdgcn_mfma_f32_16x16x32_f16(
                        H8(ah[m]), H8(bh[n]), acc[m][n], 0, 0, 0);
                    acc[m][n] = __builtin_amdgcn_mfma_f32_16x16x32_f16(
                        H8(al[m]), H8(bh[n]), acc[m][n], 0, 0, 0);
                } else {
                    acc[m][n] = __builtin_amdgcn_mfma_f32_16x16x32_bf16(
                        ah[m], bh[n], acc[m][n], 0, 0, 0);
                    if constexpr (NT == 3) {
                        acc[m][n] = __builtin_amdgcn_mfma_f32_16x16x32_bf16(
                            ah[m], bl[n], acc[m][n], 0, 0, 0);
                        acc[m][n] = __builtin_amdgcn_mfma_f32_16x16x32_bf16(
                            al[m], bh[n], acc[m][n], 0, 0, 0);
                    }
                }
            }
    }

    float bv[WN];
#pragma unroll
    for (int n = 0; n < WN; ++n) bv[n] = bias[n0 + wcol0 + n * 16 + lr];

    unsigned short* Sb = smem;
    float* Sf = (float*)smem;
    constexpr int NPASS = (OUT == 0 || OUT == 3) ? 2 : 1;

#pragma unroll
    for (int p = 0; p < NPASS; ++p) {
        __syncthreads();
#pragma unroll
        for (int m = 0; m < WM; ++m)
#pragma unroll
            for (int n = 0; n < WN; ++n)
#pragma unroll
                for (int q = 0; q < 4; ++q) {
                    int rl = wrow0 + m * 16 + g * 4 + q;
                    int cl = wcol0 + n * 16 + lr;
                    float x = acc[m][n][q] + bv[n];
                    if (ACT == 0) x = fmaxf(x, 0.f);
                    else x = tanhf(x);
                    if constexpr (OUT == 2) {
                        Sf[rl * BN + cl] = x;
                    } else if constexpr (OUT == 3) {
                        unsigned short hh = f2h(x);
                        Sb[rl * BN + cl] = (p == 0) ? hh : f2h(x - h2f(hh));
                    } else {
                        unsigned short hb_ = f2bf(x);
                        Sb[rl * BN + cl] = (p == 0) ? hb_ : f2bf(x - bf2f(hb_));
                    }
                }
        __syncthreads();
        if constexpr (OUT == 2) {
            constexpr int SL = BN / 4;
#pragma unroll
            for (int it = 0; it < (128 * SL) / 256; ++it) {
                int idx = tid + it * 256;
                int row = idx / SL, sl = idx % SL;
                *(f32x4*)((float*)out0 + (size_t)(m0 + row) * NTOT + sl * 4)
                    = *(const f32x4*)&Sf[row * BN + sl * 4];
            }
        } else {
            constexpr int SL = BN / 8;
            unsigned short* dst = (unsigned short*)((p == 0) ? out0 : out1);
#pragma unroll
            for (int it = 0; it < (128 * SL) / 256; ++it) {
                int idx = tid + it * 256;
                int row = idx / SL, sl = idx % SL;
                *(short8*)&dst[(size_t)(m0 + row) * NTOT + n0 + sl * 8]
                    = *(const short8*)&Sb[row * BN + sl * 8];
            }
        }
    }
}

// ---------------------------------------------------------------------------
// BN=128 MFMA GEMM, PAIRED D-deep counted-vmcnt pipeline (round-14 postmortem:
// A deeper than B breaks vmcnt FIFO retirement — B(ks) sat behind A(ks+1) in
// the queue and was never retired before use -> NaN).  Fix: issue {B,A} pairs
// at the SAME depth; wait = futurePairs * PAIR retires exactly the oldest
// pairs (hand-verified for prologue / steady / tails at KS in {3,4,32}).
// NT1: D=4, PAIR=4 (64 KB LDS).  NT2: D=3, PAIR=6 (72 KB LDS). 2 blocks/CU.
// ---------------------------------------------------------------------------
template <int NT, int D, int OUT, int ACT>
__global__ __launch_bounds__(256, 2) void mfma_gemm128(
    const unsigned short* __restrict__ Ah_g, const unsigned short* __restrict__ Al_g,
    int K,
    const unsigned short* __restrict__ Wh, const unsigned short* __restrict__ Wl,
    const float* __restrict__ bias,
    void* __restrict__ out0, void* __restrict__ out1, int NTOT)
{
    constexpr int BN = 128;
    constexpr int WM = 4, WN = 4, NWC = 2;
    constexpr int ASTR = (NT >= 2) ? 8192 : 4096;   // shorts per A buffer
    constexpr int BSTR = (NT == 3) ? 8192 : 4096;   // shorts per B buffer
    constexpr int BOFF = D * ASTR;
    constexpr int PAIR = (NT == 1) ? 4 : ((NT == 2) ? 6 : 8);  // loads per {B,A} pair
    extern __shared__ unsigned short smem[];

    const int tid = threadIdx.x;
    int per = gridDim.x >> 3;
    int xcd = blockIdx.x & 7;
    int lid = blockIdx.x >> 3;
    int tile = xcd * per + lid;
    const int m0 = (tile >> 3) * 128;
    const int nb = tile & 7;
    const int n0 = nb * BN;
    const int w = tid >> 6, lane = tid & 63;
    const int g = lane >> 4, lr = lane & 15;
    const int wrow0 = (w / NWC) * (WM * 16);
    const int wcol0 = (w % NWC) * (WN * 16);
    const int KS = K >> 5;

    auto stageA = [&](int i, int ks) {
        unsigned short* Ah = smem + i * ASTR;
        unsigned short* Al = Ah + 4096;
#pragma unroll
        for (int it = 0; it < 2; ++it) {
            int t0 = it * 256 + w * 64;
            int t = t0 + lane;
            int row = t & 127, kb = t >> 7;
            size_t go = (size_t)(m0 + row) * K + ks * 32 + kb * 8;
            gload16(Ah_g + go, Ah + (size_t)t0 * 8);
            if constexpr (NT >= 2) gload16(Al_g + go, Al + (size_t)t0 * 8);
        }
    };
    auto stageB = [&](int j, int ks) {
        unsigned short* Bh = smem + BOFF + j * BSTR;
        unsigned short* Bl = Bh + 4096;
        size_t bo = ((size_t)nb * KS + ks) * (BN * 32);
#pragma unroll
        for (int it = 0; it < 2; ++it) {
            int t0 = it * 256 + w * 64;
            size_t go = bo + (size_t)(t0 + lane) * 8;
            gload16(Wh + go, Bh + (size_t)t0 * 8);
            if constexpr (NT == 3) gload16(Wl + go, Bl + (size_t)t0 * 8);
        }
    };

    // bias first: oldest in vmcnt queue, retired by the first counted wait.
    float bv[WN];
#pragma unroll
    for (int n = 0; n < WN; ++n) bv[n] = bias[n0 + wcol0 + n * 16 + lr];
    __builtin_amdgcn_sched_barrier(0);

    f32x4 acc[WM][WN];
#pragma unroll
    for (int m = 0; m < WM; ++m)
#pragma unroll
        for (int n = 0; n < WN; ++n) {
            acc[m][n][0] = 0.f; acc[m][n][1] = 0.f;
            acc[m][n][2] = 0.f; acc[m][n][3] = 0.f;
        }

    // prologue: pairs {B(i),A(i)} for i = 0..D-2
#pragma unroll
    for (int i = 0; i < D - 1; ++i)
        if (i < KS) { stageB(i, i); stageA(i, i); }

    for (int ks = 0; ks < KS; ++ks) {
        __builtin_amdgcn_s_barrier();          // all waves done reading iter ks-1
        if (ks + D - 1 < KS) {                 // issue the pair for iter ks+D-1
            stageB((ks + D - 1) % D, ks + D - 1);
            stageA((ks + D - 1) % D, ks + D - 1);
        }
        int futP = KS - 1 - ks; if (futP > D - 1) futP = D - 1;
        vm_wait(futP * PAIR);                  // retire through pair(ks) exactly
        __builtin_amdgcn_s_barrier();          // all waves' pair(ks) landed
        __builtin_amdgcn_sched_barrier(0);

        unsigned short* Ah = smem + (ks % D) * ASTR;
        unsigned short* Al = Ah + 4096;
        unsigned short* Bh = smem + BOFF + (ks % D) * BSTR;
        unsigned short* Bl = Bh + 4096;

        short8 ah[WM], bh[WN];
        short8 al[WM], bl[WN];
#pragma unroll
        for (int m = 0; m < WM; ++m) {
            int ro = (g << 7) + wrow0 + m * 16 + lr;
            ah[m] = *(const short8*)&Ah[ro * 8];
            if constexpr (NT >= 2) al[m] = *(const short8*)&Al[ro * 8];
        }
#pragma unroll
        for (int n = 0; n < WN; ++n) {
            int co = g * BN + wcol0 + n * 16 + lr;
            bh[n] = *(const short8*)&Bh[co * 8];
            if constexpr (NT == 3) bl[n] = *(const short8*)&Bl[co * 8];
        }
#pragma unroll
        for (int m = 0; m < WM; ++m)
#pragma unroll
            for (int n = 0; n < WN; ++n) {
                if constexpr (NT == 2) {
                    acc[m][n] = __builtin_amdgcn_mfma_f32_16x16x32_f16(
                        H8(ah[m]), H8(bh[n]), acc[m][n], 0, 0, 0);
                    acc[m][n] = __builtin_amdgcn_mfma_f32_16x16x32_f16(
                        H8(al[m]), H8(bh[n]), acc[m][n], 0, 0, 0);
                } else {
                    acc[m][n] = __builtin_amdgcn_mfma_f32_16x16x32_bf16(
                        ah[m], bh[n], acc[m][n], 0, 0, 0);
                    if constexpr (NT == 3) {
                        acc[m][n] = __builtin_amdgcn_mfma_f32_16x16x32_bf16(
                            ah[m], bl[n], acc[m][n], 0, 0, 0);
                        acc[m][n] = __builtin_amdgcn_mfma_f32_16x16x32_bf16(
                            al[m], bh[n], acc[m][n], 0, 0, 0);
                    }
                }
            }
    }

    unsigned short* Sb = smem;
    float* Sf = (float*)smem;
    constexpr int NPASS = (OUT == 0 || OUT == 3) ? 2 : 1;

#pragma unroll
    for (int p = 0; p < NPASS; ++p) {
        __syncthreads();
#pragma unroll
        for (int m = 0; m < WM; ++m)
#pragma unroll
            for (int n = 0; n < WN; ++n)
#pragma unroll
                for (int q = 0; q < 4; ++q) {
                    int rl = wrow0 + m * 16 + g * 4 + q;
                    int cl = wcol0 + n * 16 + lr;
                    float x = acc[m][n][q] + bv[n];
                    if (ACT == 0) x = fmaxf(x, 0.f);
                    else x = tanhf(x);
                    if constexpr (OUT == 2) {
                        Sf[rl * BN + cl] = x;
                    } else if constexpr (OUT == 3) {
                        unsigned short hh = f2h(x);
                        Sb[rl * BN + cl] = (p == 0) ? hh : f2h(x - h2f(hh));
                    } else {
                        unsigned short hb_ = f2bf(x);
                        Sb[rl * BN + cl] = (p == 0) ? hb_ : f2bf(x - bf2f(hb_));
                    }
                }
        __syncthreads();
        if constexpr (OUT == 2) {
            constexpr int SL = BN / 4;
#pragma unroll
            for (int it = 0; it < (128 * SL) / 256; ++it) {
                int idx = tid + it * 256;
                int row = idx / SL, sl = idx % SL;
                *(f32x4*)((float*)out0 + (size_t)(m0 + row) * NTOT + sl * 4)
                    = *(const f32x4*)&Sf[row * BN + sl * 4];
            }
        } else {
            constexpr int SL = BN / 8;
            unsigned short* dst = (unsigned short*)((p == 0) ? out0 : out1);
#pragma unroll
            for (int it = 0; it < (128 * SL) / 256; ++it) {
                int idx = tid + it * 256;
                int row = idx / SL, sl = idx % SL;
                *(short8*)&dst[(size_t)(m0 + row) * NTOT + n0 + sl * 8]
                    = *(const short8*)&Sb[row * BN + sl * 8];
            }
        }
    }
}

// ---------------------------------------------------------------------------
// BM=64 MFMA GEMM for small-N layers (G3: NT2/BN64 fp16, G6: NT1/BN32 bf16).
// ---------------------------------------------------------------------------
template <int NT, int BN, int ACT>
__global__ __launch_bounds__(256) void mfma_gemm64(
    const unsigned short* __restrict__ Ah_g, const unsigned short* __restrict__ Al_g,
    int K,
    const unsigned short* __restrict__ Wh, const unsigned short* __restrict__ Wl,
    const float* __restrict__ bias,
    float* __restrict__ out, int NTOT)
{
    constexpr int WM = (BN == 64) ? 2 : 1;
    constexpr int WN = 2;
    constexpr int ABUF = (NT >= 2) ? 4096 : 2048;          // shorts
    constexpr int BBUF = BN * 32 * ((NT == 3) ? 2 : 1);
    constexpr int BUFSH = ABUF + BBUF;
    __shared__ unsigned short smem[2 * BUFSH];

    const int tid = threadIdx.x;
    const int m0 = blockIdx.x * 64;
    const int w = tid >> 6, lane = tid & 63;
    const int g = lane >> 4, lr = lane & 15;
    const int wrow0 = (BN == 64) ? ((w >> 1) * 32) : (w * 16);
    const int wcol0 = (BN == 64) ? ((w & 1) * 32) : 0;
    const int KS = K >> 5;

    auto stage = [&](unsigned short* buf, int ks) {
        unsigned short* Ah = buf;
        unsigned short* Al = buf + 2048;
        unsigned short* Bh = buf + ABUF;
        unsigned short* Bl = Bh + BN * 32;
        {
            int t0 = w * 64;
            int t = t0 + lane;
            int row = t & 63, kb = t >> 6;
            size_t go = (size_t)(m0 + row) * K + ks * 32 + kb * 8;
            gload16(Ah_g + go, Ah + (size_t)t0 * 8);
            if constexpr (NT >= 2) gload16(Al_g + go, Al + (size_t)t0 * 8);
        }
        size_t bo = (size_t)ks * (BN * 32);
        constexpr int BT = BN * 4;
        if constexpr (BT == 256) {
            int t0 = w * 64;
            size_t go = bo + (size_t)(t0 + lane) * 8;
            gload16(Wh + go, Bh + (size_t)t0 * 8);
            if constexpr (NT == 3) gload16(Wl + go, Bl + (size_t)t0 * 8);
        } else {
            if (tid < BT) {
                int t0 = w * 64;
                size_t go = bo + (size_t)(t0 + lane) * 8;
                gload16(Wh + go, Bh + (size_t)t0 * 8);
                if constexpr (NT == 3) gload16(Wl + go, Bl + (size_t)t0 * 8);
            }
        }
    };

    f32x4 acc[WM][WN];
#pragma unroll
    for (int m = 0; m < WM; ++m)
#pragma unroll
        for (int n = 0; n < WN; ++n) {
            acc[m][n][0] = 0.f; acc[m][n][1] = 0.f;
            acc[m][n][2] = 0.f; acc[m][n][3] = 0.f;
        }

    stage(smem, 0);

    for (int ks = 0; ks < KS; ++ks) {
        __syncthreads();
        unsigned short* buf = smem + (size_t)(ks & 1) * BUFSH;
        if (ks + 1 < KS)
            stage(smem + (size_t)((ks + 1) & 1) * BUFSH, ks + 1);

        unsigned short* Ah = buf;
        unsigned short* Al = buf + 2048;
        unsigned short* Bh = buf + ABUF;
        unsigned short* Bl = Bh + BN * 32;

        short8 ah[WM], bh[WN];
        short8 al[WM], bl[WN];
#pragma unroll
        for (int m = 0; m < WM; ++m) {
            int ro = (g << 6) + wrow0 + m * 16 + lr;
            ah[m] = *(const short8*)&Ah[ro * 8];
            if constexpr (NT >= 2) al[m] = *(const short8*)&Al[ro * 8];
        }
#pragma unroll
        for (int n = 0; n < WN; ++n) {
            int co = g * BN + wcol0 + n * 16 + lr;
            bh[n] = *(const short8*)&Bh[co * 8];
            if constexpr (NT == 3) bl[n] = *(const short8*)&Bl[co * 8];
        }
#pragma unroll
        for (int m = 0; m < WM; ++m)
#pragma unroll
            for (int n = 0; n < WN; ++n) {
                if constexpr (NT == 2) {
                    acc[m][n] = __builtin_amdgcn_mfma_f32_16x16x32_f16(
                        H8(ah[m]), H8(bh[n]), acc[m][n], 0, 0, 0);
                    acc[m][n] = __builtin_amdgcn_mfma_f32_16x16x32_f16(
                        H8(al[m]), H8(bh[n]), acc[m][n], 0, 0, 0);
                } else {
                    acc[m][n] = __builtin_amdgcn_mfma_f32_16x16x32_bf16(
                        ah[m], bh[n], acc[m][n], 0, 0, 0);
                    if constexpr (NT == 3) {
                        acc[m][n] = __builtin_amdgcn_mfma_f32_16x16x32_bf16(
                            ah[m], bl[n], acc[m][n], 0, 0, 0);
                        acc[m][n] = __builtin_amdgcn_mfma_f32_16x16x32_bf16(
                            al[m], bh[n], acc[m][n], 0, 0, 0);
                    }
                }
            }
    }

    float bv[WN];
#pragma unroll
    for (int n = 0; n < WN; ++n) bv[n] = bias[wcol0 + n * 16 + lr];

    float* Sf = (float*)smem;
    __syncthreads();
#pragma unroll
    for (int m = 0; m < WM; ++m)
#pragma unroll
        for (int n = 0; n < WN; ++n)
#pragma unroll
            for (int q = 0; q < 4; ++q) {
                int rl = wrow0 + m * 16 + g * 4 + q;
                int cl = wcol0 + n * 16 + lr;
                float x = acc[m][n][q] + bv[n];
                if (ACT == 0) x = fmaxf(x, 0.f);
                else x = tanhf(x);
                Sf[rl * BN + cl] = x;
            }
    __syncthreads();
    constexpr int SL = BN / 4;
#pragma unroll
    for (int it = 0; it < (64 * SL) / 256; ++it) {
        int idx = tid + it * 256;
        int row = idx / SL, sl = idx % SL;
        *(f32x4*)(out + (size_t)(m0 + row) * NTOT + sl * 4)
            = *(const f32x4*)&Sf[row * BN + sl * 4];
    }
}

// ---------------------------------------------------------------------------
// fp32 fixup GEMM, 32-row tiles (proven round 9).
// ---------------------------------------------------------------------------
template <int BN, int ACT>
__global__ __launch_bounds__(256) void gemm_fix(
    const int* __restrict__ mrows,
    const float* __restrict__ A, int K,
    const float* __restrict__ W, const float* __restrict__ bias,
    float* __restrict__ Co, int N)
{
    const int m0 = blockIdx.x * 32;
    if (m0 >= *mrows) return;

    constexpr int TN = BN / 16;
    __shared__ float At[16][36];
    __shared__ float Bt[16][BN + 4];

    const int tid = threadIdx.x;
    const int n0 = blockIdx.y * BN;
    const int r = tid >> 4;
    const int c = tid & 15;

    float acc[2][TN];
#pragma unroll
    for (int i = 0; i < 2; ++i)
#pragma unroll
        for (int j = 0; j < TN; ++j) acc[i][j] = 0.f;

    for (int k0 = 0; k0 < K; k0 += 16) {
        if (tid < 128) {
            int row = tid >> 2;
            int lf = tid & 3;
            float4 v = *(const float4*)(A + (size_t)(m0 + row) * K + k0 + lf * 4);
            At[lf * 4 + 0][row] = v.x;
            At[lf * 4 + 1][row] = v.y;
            At[lf * 4 + 2][row] = v.z;
            At[lf * 4 + 3][row] = v.w;
        }
        constexpr int NF4 = BN / 4;
        constexpr int NEL = 16 * NF4;
#pragma unroll
        for (int it = 0; it < NEL / 256; ++it) {
            int idx = tid + it * 256;
            int kk = idx / NF4;
            int f = idx % NF4;
            float4 v = *(const float4*)(W + (size_t)(k0 + kk) * N + n0 + f * 4);
            *(float4*)&Bt[kk][f * 4] = v;
        }
        __syncthreads();

#pragma unroll
        for (int kk = 0; kk < 16; ++kk) {
            float a0 = At[kk][r * 2];
            float a1 = At[kk][r * 2 + 1];
            float b[TN];
            if constexpr (BN == 128) {
                float4 b0 = *(const float4*)&Bt[kk][c * 4];
                float4 b1 = *(const float4*)&Bt[kk][64 + c * 4];
                b[0] = b0.x; b[1] = b0.y; b[2] = b0.z; b[3] = b0.w;
                b[4] = b1.x; b[5] = b1.y; b[6] = b1.z; b[7] = b1.w;
            } else {
                float4 b0 = *(const float4*)&Bt[kk][c * 4];
                b[0] = b0.x; b[1] = b0.y; b[2] = b0.z; b[3] = b0.w;
            }
#pragma unroll
            for (int j = 0; j < TN; ++j) {
                acc[0][j] = fmaf(a0, b[j], acc[0][j]);
                acc[1][j] = fmaf(a1, b[j], acc[1][j]);
            }
        }
        __syncthreads();
    }

#pragma unroll
    for (int i = 0; i < 2; ++i) {
        size_t row = (size_t)(m0 + r * 2 + i);
        if constexpr (BN == 128) {
            float e[8];
#pragma unroll
            for (int j = 0; j < 8; ++j) {
                int col = (j < 4) ? (c * 4 + j) : (64 + c * 4 + (j - 4));
                float v = acc[i][j] + bias[n0 + col];
                if (ACT == 0) v = fmaxf(v, 0.f);
                e[j] = v;
            }
            float4 v0, v1;
            v0.x = e[0]; v0.y = e[1]; v0.z = e[2]; v0.w = e[3];
            v1.x = e[4]; v1.y = e[5]; v1.z = e[6]; v1.w = e[7];
            *(float4*)&Co[row * N + n0 + c * 4] = v0;
            *(float4*)&Co[row * N + n0 + 64 + c * 4] = v1;
        } else {
            float e[4];
#pragma unroll
            for (int j = 0; j < 4; ++j) {
                float v = acc[i][j] + bias[n0 + c * 4 + j];
                if (ACT == 0) v = fmaxf(v, 0.f);
                e[j] = v;
            }
            float4 v0;
            v0.x = e[0]; v0.y = e[1]; v0.z = e[2]; v0.w = e[3];
            *(float4*)&Co[row * N + n0 + c * 4] = v0;
        }
    }
}

// ---------------------------------------------------------------------------
// sa planes fp16 hi + lo.
// ---------------------------------------------------------------------------
__global__ void sa_pre(const float* __restrict__ state, const float* __restrict__ action,
                       unsigned short* __restrict__ saH, unsigned short* __restrict__ saL)
{
    int idx = blockIdx.x * 256 + threadIdx.x;
    int row = idx / 12, q = idx % 12;
    const float* src = (q < 8) ? (state + (size_t)row * 64 + q * 8)
                               : (action + (size_t)row * 32 + (q - 8) * 8);
    f32x4 v0 = *(const f32x4*)src;
    f32x4 v1 = *(const f32x4*)(src + 4);
    short8 h, l;
#pragma unroll
    for (int j = 0; j < 8; ++j) {
        float x = (j < 4) ? v0[j] : v1[j - 4];
        unsigned short hh = f2h(x);
        h[j] = (short)hh;
        l[j] = (short)f2h(x - h2f(hh));
    }
    *(short8*)&saH[(size_t)row * 96 + q * 8] = h;
    *(short8*)&saL[(size_t)row * 96 + q * 8] = l;
}

// ---------------------------------------------------------------------------
// VQ score kernel: 64 rows x 512 codes per block, grid (M/64, 2).
// ---------------------------------------------------------------------------
__global__ __launch_bounds__(256) void vq_score(
    const float* __restrict__ midz,
    const float* __restrict__ codebook,
    const float* __restrict__ cbn,
    float4* __restrict__ part)
{
    __shared__ float Zt[64 * 68];
    __shared__ float Ct[64 * 68];
    __shared__ float cn[64];

    const int tid = threadIdx.x;
    const int m0 = blockIdx.x * 64;
    const int eh = blockIdx.y;
    const int r = tid >> 4;
    const int c = tid & 15;

#pragma unroll
    for (int it = 0; it < 4; ++it) {
        int idx = tid + it * 256;
        int row = idx >> 4, f = idx & 15;
        float4 v = *(const float4*)(midz + (size_t)(m0 + row) * 64 + f * 4);
        Zt[(f * 4 + 0) * 68 + row] = v.x;
        Zt[(f * 4 + 1) * 68 + row] = v.y;
        Zt[(f * 4 + 2) * 68 + row] = v.z;
        Zt[(f * 4 + 3) * 68 + row] = v.w;
    }

    float best[4], sec[4];
    int bidx[4];
#pragma unroll
    for (int i = 0; i < 4; ++i) { best[i] = 3.4e38f; sec[i] = 3.4e38f; bidx[i] = 0x7fffffff; }

    for (int ch = 0; ch < 8; ++ch) {
        int e0 = eh * 512 + ch * 64;
        __syncthreads();
#pragma unroll
        for (int it = 0; it < 4; ++it) {
            int idx = tid + it * 256;
            int e = idx >> 4, f = idx & 15;
            float4 v = *(const float4*)(codebook + (size_t)(e0 + e) * 64 + f * 4);
            Ct[(f * 4 + 0) * 68 + e] = v.x;
            Ct[(f * 4 + 1) * 68 + e] = v.y;
            Ct[(f * 4 + 2) * 68 + e] = v.z;
            Ct[(f * 4 + 3) * 68 + e] = v.w;
        }
        if (tid < 64) cn[tid] = cbn[e0 + tid];
        __syncthreads();

        float acc[4][4];
#pragma unroll
        for (int i = 0; i < 4; ++i)
#pragma unroll
            for (int j = 0; j < 4; ++j) acc[i][j] = 0.f;

#pragma unroll 8
        for (int kk = 0; kk < 64; ++kk) {
            float4 a = *(const float4*)&Zt[kk * 68 + r * 4];
            float4 b = *(const float4*)&Ct[kk * 68 + c * 4];
            acc[0][0] = fmaf(a.x, b.x, acc[0][0]);
            acc[0][1] = fmaf(a.x, b.y, acc[0][1]);
            acc[0][2] = fmaf(a.x, b.z, acc[0][2]);
            acc[0][3] = fmaf(a.x, b.w, acc[0][3]);
            acc[1][0] = fmaf(a.y, b.x, acc[1][0]);
            acc[1][1] = fmaf(a.y, b.y, acc[1][1]);
            acc[1][2] = fmaf(a.y, b.z, acc[1][2]);
            acc[1][3] = fmaf(a.y, b.w, acc[1][3]);
            acc[2][0] = fmaf(a.z, b.x, acc[2][0]);
            acc[2][1] = fmaf(a.z, b.y, acc[2][1]);
            acc[2][2] = fmaf(a.z, b.z, acc[2][2]);
            acc[2][3] = fmaf(a.z, b.w, acc[2][3]);
            acc[3][0] = fmaf(a.w, b.x, acc[3][0]);
            acc[3][1] = fmaf(a.w, b.y, acc[3][1]);
            acc[3][2] = fmaf(a.w, b.z, acc[3][2]);
            acc[3][3] = fmaf(a.w, b.w, acc[3][3]);
        }
#pragma unroll
        for (int i = 0; i < 4; ++i)
#pragma unroll
            for (int j = 0; j < 4; ++j) {
                int e = c * 4 + j;
                float s = cn[e] - 2.0f * acc[i][j];
                int gi = e0 + e;
                if (s < best[i] || (s == best[i] && gi < bidx[i])) {
                    sec[i] = best[i];
                    best[i] = s;
                    bidx[i] = gi;
                } else {
                    sec[i] = fminf(sec[i], s);
                }
            }
    }

#pragma unroll
    for (int i = 0; i < 4; ++i) {
#pragma unroll
        for (int m = 1; m < 16; m <<= 1) {
            float ob = __shfl_xor(best[i], m, 64);
            int oi = __shfl_xor(bidx[i], m, 64);
            float os = __shfl_xor(sec[i], m, 64);
            if (ob < best[i] || (ob == best[i] && oi < bidx[i])) {
                sec[i] = fminf(best[i], os);
                best[i] = ob;
                bidx[i] = oi;
            } else {
                sec[i] = fminf(sec[i], ob);
            }
        }
    }
    if (c == 0) {
#pragma unroll
        for (int i = 0; i < 4; ++i) {
            float4 p;
            p.x = best[i];
            p.y = sec[i];
            p.z = __int_as_float(bidx[i]);
            p.w = 0.f;
            part[(size_t)(m0 + r * 4 + i) * 2 + eh] = p;
        }
    }
}

// ---------------------------------------------------------------------------
// VQ merge + flag + latent head + state half of xz.  128 rows/block, grid mt.
// ---------------------------------------------------------------------------
__global__ __launch_bounds__(256) void vq_merge(
    const float4* __restrict__ part,
    const float* __restrict__ state_c,
    const float* __restrict__ codebook,
    const float* __restrict__ mean_w, const float* __restrict__ mean_b,
    const float* __restrict__ logstd_w, const float* __restrict__ logstd_b,
    const float* __restrict__ eps,
    float* __restrict__ mean_out, float* __restrict__ std_out,
    unsigned short* __restrict__ xz,
    int* __restrict__ ctr, int* __restrict__ list, int rowbase)
{
    __shared__ float mw[4160];
    __shared__ float lw[4160];
    __shared__ int sidx[128];

    const int tid = threadIdx.x;
    const int m0 = blockIdx.x * 128;

    if (tid < 128) {
        size_t row = (size_t)(m0 + tid);
        float4 p0 = part[row * 2 + 0];
        float4 p1 = part[row * 2 + 1];
        int i0 = __float_as_int(p0.z), i1 = __float_as_int(p1.z);
        float b, s;
        int ix;
        if (p0.x < p1.x || (p0.x == p1.x && i0 < i1)) {
            b = p0.x; ix = i0; s = fminf(p0.y, p1.x);
        } else {
            b = p1.x; ix = i1; s = fminf(p1.y, p0.x);
        }
        sidx[tid] = ix;
        if (s - b < TAU) {
            int p = atomicAdd(ctr, 1);
            list[p] = rowbase + m0 + tid;
        }
    }
#pragma unroll
    for (int it = 0; it < 4; ++it) {
        int idx = tid + it * 256;
        int k = idx >> 4, f = idx & 15;
        float4 v = *(const float4*)(mean_w + (size_t)k * 64 + f * 4);
        mw[k * 65 + f * 4 + 0] = v.x;
        mw[k * 65 + f * 4 + 1] = v.y;
        mw[k * 65 + f * 4 + 2] = v.z;
        mw[k * 65 + f * 4 + 3] = v.w;
        float4 w2 = *(const float4*)(logstd_w + (size_t)k * 64 + f * 4);
        lw[k * 65 + f * 4 + 0] = w2.x;
        lw[k * 65 + f * 4 + 1] = w2.y;
        lw[k * 65 + f * 4 + 2] = w2.z;
        lw[k * 65 + f * 4 + 3] = w2.w;
    }

    // state half -> xz cols 0..63 (independent of merge; no sync needed)
    {
        int row = tid >> 1;
        int d0 = (tid & 1) * 32;
        size_t so = (size_t)(m0 + row) * 64 + d0;
        size_t xo = (size_t)(m0 + row) * 128 + d0;
#pragma unroll
        for (int q = 0; q < 8; ++q) {
            f32x4 v = *(const f32x4*)&state_c[so + q * 4];
            unsigned short o[4];
            o[0] = f2bf(v[0]); o[1] = f2bf(v[1]);
            o[2] = f2bf(v[2]); o[3] = f2bf(v[3]);
            *(uint2*)&xz[xo + q * 4] = *(uint2*)o;
        }
    }
    __syncthreads();

    {
        int row = tid >> 1;
        int d0 = (tid & 1) * 32;
        int e = sidx[row];
        const float* cb = codebook + (size_t)e * 64;
        float mv[32], lv[32];
#pragma unroll
        for (int d = 0; d < 32; ++d) {
            mv[d] = mean_b[d0 + d];
            lv[d] = logstd_b[d0 + d];
        }
        for (int k = 0; k < 64; ++k) {
            float zk = cb[k];
#pragma unroll
            for (int d = 0; d < 32; ++d) {
                mv[d] = fmaf(zk, mw[k * 65 + d0 + d], mv[d]);
                lv[d] = fmaf(zk, lw[k * 65 + d0 + d], lv[d]);
            }
        }
        size_t ro = (size_t)(m0 + row) * 64 + d0;
        size_t xo = (size_t)(m0 + row) * 128 + 64 + d0;
#pragma unroll
        for (int d = 0; d < 32; ++d) {
            float mean = mv[d];
            float ls = fminf(fmaxf(lv[d], -4.f), 15.f);
            float sd = expf(ls);
            float z = fmaf(sd, eps[ro + d], mean);
            mean_out[ro + d] = mean;
            std_out[ro + d] = sd;
            xz[xo + d] = f2bf(z);
        }
    }
}

// ---------------------------------------------------------------------------
__global__ void gather_fix(const int* __restrict__ ctr, int* __restrict__ meta,
                           const int* __restrict__ list,
                           const float* __restrict__ state,
                           const float* __restrict__ action,
                           float* __restrict__ sa_fix)
{
    int cnt = *ctr; if (cnt > FMAX) cnt = FMAX;
    if (blockIdx.x == 0 && threadIdx.x == 0)
        meta[0] = (cnt + 31) & ~31;
    int t = blockIdx.x * 256 + threadIdx.x;
    if (t >= cnt * 24) return;
    int f = t / 24, q = t % 24;
    size_t g = (size_t)list[f];
    f32x4 v = (q < 16) ? *(const f32x4*)&state[g * 64 + q * 4]
                       : *(const f32x4*)&action[g * 32 + (q - 16) * 4];
    *(f32x4*)&sa_fix[(size_t)f * 96 + q * 4] = v;
}

// ---------------------------------------------------------------------------
__global__ __launch_bounds__(256) void vq_fix(
    const int* __restrict__ ctr, const int* __restrict__ list,
    const float* __restrict__ mz_fix,
    const float* __restrict__ codebook, const float* __restrict__ cbn,
    const float* __restrict__ mean_w, const float* __restrict__ mean_b,
    const float* __restrict__ logstd_w, const float* __restrict__ logstd_b,
    const float* __restrict__ eps,
    float* __restrict__ mean_out, float* __restrict__ std_out,
    unsigned short* __restrict__ xz)
{
    __shared__ float mzs[8][64];
    __shared__ float zns[8];
    __shared__ float sv[2048];
    __shared__ int si[2048];
    __shared__ int am_s[8];

    int cnt = *ctr; if (cnt > FMAX) cnt = FMAX;
    const int base = blockIdx.x * 8;
    if (base >= cnt) return;
    const int nr = min(8, cnt - base);
    const int tid = threadIdx.x;

    if (tid < 128) {
        int rr = tid >> 4, q = tid & 15;
        int src = base + ((rr < nr) ? rr : 0);
        *(f32x4*)&mzs[rr][q * 4] = *(const f32x4*)&mz_fix[(size_t)src * 64 + q * 4];
    }
    __syncthreads();
    if (tid < 8) {
        float s = 0.f;
#pragma unroll
        for (int k = 0; k < 64; ++k) s = fmaf(mzs[tid][k], mzs[tid][k], s);
        zns[tid] = s;
    }
    __syncthreads();

    float bb[8];
    int bi[8];
#pragma unroll
    for (int rr = 0; rr < 8; ++rr) { bb[rr] = 3.4e38f; bi[rr] = 0x7fffffff; }
    for (int j = 0; j < 4; ++j) {
        int code = tid + j * 256;
        const f32x4* cp = (const f32x4*)(codebook + (size_t)code * 64);
        float dot[8];
#pragma unroll
        for (int rr = 0; rr < 8; ++rr) dot[rr] = 0.f;
        for (int t = 0; t < 16; ++t) {
            f32x4 cv = cp[t];
#pragma unroll
            for (int e = 0; e < 4; ++e) {
                float cvv = cv[e];
#pragma unroll
                for (int rr = 0; rr < 8; ++rr)
                    dot[rr] = fmaf(mzs[rr][t * 4 + e], cvv, dot[rr]);
            }
        }
        float cnv = cbn[code];
#pragma unroll
        for (int rr = 0; rr < 8; ++rr) {
            float s = (zns[rr] + cnv) - 2.0f * dot[rr];
            if (s < bb[rr] || (s == bb[rr] && code < bi[rr])) {
                bb[rr] = s; bi[rr] = code;
            }
        }
    }
#pragma unroll
    for (int rr = 0; rr < 8; ++rr) {
        sv[rr * 256 + tid] = bb[rr];
        si[rr * 256 + tid] = bi[rr];
    }
    __syncthreads();
    if (tid < 8) {
        float b = 3.4e38f;
        int ix = 0x7fffffff;
        for (int t = 0; t < 256; ++t) {
            float v = sv[tid * 256 + t];
            int iv = si[tid * 256 + t];
            if (v < b || (v == b && iv < ix)) { b = v; ix = iv; }
        }
        am_s[tid] = ix;
    }
    __syncthreads();

    for (int jo = 0; jo < 2; ++jo) {
        int o = tid + jo * 256;
        int rr = o >> 6, d = o & 63;
        if (rr < nr) {
            int e = am_s[rr];
            size_t g = (size_t)list[base + rr];
            float mv = mean_b[d], lv = logstd_b[d];
            const float* cb = codebook + (size_t)e * 64;
            for (int k = 0; k < 64; ++k) {
                float zk = cb[k];
                mv = fmaf(zk, mean_w[(size_t)k * 64 + d], mv);
                lv = fmaf(zk, logstd_w[(size_t)k * 64 + d], lv);
            }
            float ls = fminf(fmaxf(lv, -4.f), 15.f);
            float sd = expf(ls);
            float z = fmaf(sd, eps[g * 64 + d], mv);
            mean_out[g * 64 + d] = mv;
            std_out[g * 64 + d] = sd;
            xz[g * 128 + 64 + d] = f2bf(z);
        }
    }
}

// ---------------------------------------------------------------------------
extern "C" void kernel_launch(void* const* d_in, const int* in_sizes, int n_in,
                              void* d_out, int out_size, void* d_ws, size_t ws_size,
                              hipStream_t stream)
{
    const float* state    = (const float*)d_in[0];
    const float* action   = (const float*)d_in[1];
    const float* eps      = (const float*)d_in[2];
    const float* enc_w1   = (const float*)d_in[3];
    const float* enc_b1   = (const float*)d_in[4];
    const float* enc_w2   = (const float*)d_in[5];
    const float* enc_b2   = (const float*)d_in[6];
    const float* enc_w3   = (const float*)d_in[7];
    const float* enc_b3   = (const float*)d_in[8];
    const float* mean_w   = (const float*)d_in[9];
    const float* mean_b   = (const float*)d_in[10];
    const float* logstd_w = (const float*)d_in[11];
    const float* logstd_b = (const float*)d_in[12];
    const float* codebook = (const float*)d_in[13];
    const float* dec_w1   = (const float*)d_in[14];
    const float* dec_b1   = (const float*)d_in[15];
    const float* dec_w2   = (const float*)d_in[16];
    const float* dec_b2   = (const float*)d_in[17];
    const float* dec_w3   = (const float*)d_in[18];
    const float* dec_b3   = (const float*)d_in[19];

    float* out = (float*)d_out;
    float* u_out = out;
    float* mean_out = out + (size_t)B_TOTAL * 32;
    float* std_out = mean_out + (size_t)B_TOTAL * 64;

    // ---- fixed ws region (~9.6 MB; fix buffers alias the dyn area) ----
    char* base = (char*)d_ws;
    float* cbn = (float*)base;                                   // 4096
    unsigned short* W1h = (unsigned short*)(base + 4096);        // fp16
    unsigned short* W2h = (unsigned short*)(base + 397312);      // fp16
    unsigned short* W3h = (unsigned short*)(base + 4591616);     // fp16
    unsigned short* W4h = (unsigned short*)(base + 4853760);     // bf16
    unsigned short* W5h = (unsigned short*)(base + 5115904);     // bf16
    unsigned short* W6h = (unsigned short*)(base + 7213056);     // bf16
    int* ctr            = (int*)(base + 7278592);                // 256
    int* flag_list      = (int*)(base + 7278848);                // 262144
    int* meta           = (int*)(base + 7540992);                // 256
    float4* part        = (float4*)(base + 7541248);             // 2097152
    const size_t FIXED  = 9638400;

    unsigned short* xz_g = (unsigned short*)(base + FIXED);      // 16 MB
    const size_t XZ_SZ = (size_t)B_TOTAL * 128 * 2;

    // dyn region: per-chunk staging; per_row = 384 + 8192 + 256 = 8832 B
    const size_t per_row = 8832;
    size_t avail = (ws_size > FIXED + XZ_SZ) ? (ws_size - FIXED - XZ_SZ) : 0;
    long maxC = (long)(avail / per_row);
    int C = (int)(maxC / 1024) * 1024;
    if (C > B_TOTAL) C = B_TOTAL;
    if (C < 6144) C = 6144;   // >= fix-alias region

    char* dyn = base + FIXED + XZ_SZ;
    unsigned short* saH = (unsigned short*)dyn;                   // [C,96] fp16
    unsigned short* saL = saH + (size_t)C * 96;
    unsigned short* h1H = saL + (size_t)C * 96;                   // [C,1024] fp16
    unsigned short* h1L = h1H + (size_t)C * 1024;
    unsigned short* h2H = h1L + (size_t)C * 1024;
    unsigned short* h2L = h2H + (size_t)C * 1024;
    float* mz = (float*)(h2L + (size_t)C * 1024);                 // [C,64]
    unsigned short* hc = h1H;   // decoder reuse (bf16)
    unsigned short* hd = h2H;

    // fixup buffers alias dyn (phase B runs after all of phase A)
    float* sa_fix = (float*)dyn;                                  // 2359296
    float* h1_fix = (float*)(dyn + 2359296);                      // 25165824
    float* h2_fix = (float*)(dyn + 27525120);                     // 25165824
    float* mz_fix = (float*)(dyn + 52690944);                     // 1572864

    // dynamic-LDS attrs for the pipelined kernels (fallback to old if denied)
    bool deep = hipFuncSetAttribute(
        reinterpret_cast<const void*>(&mfma_gemm128<2, 3, 3, 0>),
        hipFuncAttributeMaxDynamicSharedMemorySize, 73728) == hipSuccess;
    deep = deep && hipFuncSetAttribute(
        reinterpret_cast<const void*>(&mfma_gemm128<1, 4, 1, 0>),
        hipFuncAttributeMaxDynamicSharedMemorySize, 65536) == hipSuccess;

    // ---- once per call ----
    cb_norms<<<dim3(4), dim3(256), 0, stream>>>(codebook, cbn);
    zero_ctr<<<dim3(1), dim3(64), 0, stream>>>(ctr);
    w_xform<2, 128><<<dim3(3, 8), dim3(256), 0, stream>>>(enc_w1, 96, 1024, W1h, nullptr);
    w_xform<2, 128><<<dim3(32, 8), dim3(256), 0, stream>>>(enc_w2, 1024, 1024, W2h, nullptr);
    w_xform<2, 64><<<dim3(32, 1), dim3(256), 0, stream>>>(enc_w3, 1024, 64, W3h, nullptr);
    w_xform<1, 128><<<dim3(4, 8), dim3(256), 0, stream>>>(dec_w1, 128, 1024, W4h, nullptr);
    w_xform<1, 128><<<dim3(32, 8), dim3(256), 0, stream>>>(dec_w2, 1024, 1024, W5h, nullptr);
    w_xform<1, 32><<<dim3(32, 1), dim3(256), 0, stream>>>(dec_w3, 1024, 32, W6h, nullptr);

    // ---- phase A: encoder (fp16 2-term, paired 3-deep) + VQ ----
    for (int r0 = 0; r0 < B_TOTAL; r0 += C) {
        int M = (r0 + C <= B_TOTAL) ? C : (B_TOTAL - r0);
        int mt = M / 128;

        sa_pre<<<dim3(M * 12 / 256), dim3(256), 0, stream>>>(
            state + (size_t)r0 * SDIM, action + (size_t)r0 * ADIM, saH, saL);

        if (deep) {
            mfma_gemm128<2, 3, 3, 0><<<dim3(mt * 8), dim3(256), 73728, stream>>>(
                saH, saL, 96, W1h, nullptr, enc_b1, h1H, h1L, 1024);
            mfma_gemm128<2, 3, 3, 0><<<dim3(mt * 8), dim3(256), 73728, stream>>>(
                h1H, h1L, 1024, W2h, nullptr, enc_b2, h2H, h2L, 1024);
        } else {
            mfma_gemm<2, 128, 3, 0><<<dim3(mt * 8), dim3(256), 0, stream>>>(
                saH, saL, 96, W1h, nullptr, enc_b1, h1H, h1L, 1024);
            mfma_gemm<2, 128, 3, 0><<<dim3(mt * 8), dim3(256), 0, stream>>>(
                h1H, h1L, 1024, W2h, nullptr, enc_b2, h2H, h2L, 1024);
        }
        mfma_gemm64<2, 64, 0><<<dim3(M / 64), dim3(256), 0, stream>>>(
            h2H, h2L, 1024, W3h, nullptr, enc_b3, mz, 64);

        vq_score<<<dim3(M / 64, 2), dim3(256), 0, stream>>>(
            mz, codebook, cbn, part + (size_t)r0 * 2);
        vq_merge<<<dim3(mt), dim3(256), 0, stream>>>(
            part + (size_t)r0 * 2, state + (size_t)r0 * SDIM, codebook,
            mean_w, mean_b, logstd_w, logstd_b,
            eps + (size_t)r0 * LDIM,
            mean_out + (size_t)r0 * LDIM, std_out + (size_t)r0 * LDIM,
            xz_g + (size_t)r0 * 128, ctr, flag_list, r0);
    }

    // ---- phase B: exact-fp32 fixup as 32-row-tile GEMMs on gathered rows ----
    gather_fix<<<dim3(FMAX * 24 / 256), dim3(256), 0, stream>>>(
        ctr, meta, flag_list, state, action, sa_fix);
    gemm_fix<128, 0><<<dim3(FMAX / 32, 8), dim3(256), 0, stream>>>(
        meta, sa_fix, 96, enc_w1, enc_b1, h1_fix, 1024);
    gemm_fix<128, 0><<<dim3(FMAX / 32, 8), dim3(256), 0, stream>>>(
        meta, h1_fix, 1024, enc_w2, enc_b2, h2_fix, 1024);
    gemm_fix<64, 0><<<dim3(FMAX / 32, 1), dim3(256), 0, stream>>>(
        meta, h2_fix, 1024, enc_w3, enc_b3, mz_fix, 64);
    vq_fix<<<dim3(FMAX / 8), dim3(256), 0, stream>>>(
        ctr, flag_list, mz_fix, codebook, cbn,
        mean_w, mean_b, logstd_w, logstd_b, eps,
        mean_out, std_out, xz_g);

    // ---- phase C: decoder (bf16 1-term, paired 4-deep) ----
    for (int r0 = 0; r0 < B_TOTAL; r0 += C) {
        int M = (r0 + C <= B_TOTAL) ? C : (B_TOTAL - r0);
        int mt = M / 128;

        if (deep) {
            mfma_gemm128<1, 4, 1, 0><<<dim3(mt * 8), dim3(256), 65536, stream>>>(
                xz_g + (size_t)r0 * 128, nullptr, 128, W4h, nullptr, dec_b1,
                hc, nullptr, 1024);
            mfma_gemm128<1, 4, 1, 0><<<dim3(mt * 8), dim3(256), 65536, stream>>>(
                hc, nullptr, 1024, W5h, nullptr, dec_b2, hd, nullptr, 1024);
        } else {
            mfma_gemm<1, 128, 1, 0><<<dim3(mt * 8), dim3(256), 0, stream>>>(
                xz_g + (size_t)r0 * 128, nullptr, 128, W4h, nullptr, dec_b1,
                hc, nullptr, 1024);
            mfma_gemm<1, 128, 1, 0><<<dim3(mt * 8), dim3(256), 0, stream>>>(
                hc, nullptr, 1024, W5h, nullptr, dec_b2, hd, nullptr, 1024);
        }
        mfma_gemm64<1, 32, 1><<<dim3(M / 64), dim3(256), 0, stream>>>(
            hd, nullptr, 1024, W6h, nullptr, dec_b3,
            u_out + (size_t)r0 * ADIM, 32);
    }
}

// Round 16
// 1199.607 us; speedup vs baseline: 1.2643x; 1.2643x over previous
//
#include <hip/hip_runtime.h>
#include <cstdint>
#include <cstddef>

#define B_TOTAL 65536
#define SDIM 64
#define ADIM 32
#define LDIM 64
#define HDIM 1024
#define NEMB 1024
#define TAU 0.125f
#define FMAX 6144

typedef __attribute__((ext_vector_type(8))) short short8;
typedef __attribute__((ext_vector_type(8))) _Float16 half8;
typedef __attribute__((ext_vector_type(4))) float f32x4;

__device__ inline unsigned short f2bf(float f) {
    unsigned int u = __float_as_uint(f);
    u += 0x7fffu + ((u >> 16) & 1u);
    return (unsigned short)(u >> 16);
}
__device__ inline float bf2f(unsigned short s) {
    return __uint_as_float(((unsigned int)s) << 16);
}
__device__ inline unsigned short f2h(float f) {
    _Float16 h = (_Float16)f;
    return __builtin_bit_cast(unsigned short, h);
}
__device__ inline float h2f(unsigned short s) {
    return (float)__builtin_bit_cast(_Float16, s);
}
__device__ inline half8 H8(short8 v) { return __builtin_bit_cast(half8, v); }

// async global->LDS, 16B per lane; LDS dest = wave-uniform base + lane*16.
__device__ inline void gload16(const unsigned short* g, unsigned short* l) {
    __builtin_amdgcn_global_load_lds(
        (__attribute__((address_space(1))) void*)(g),
        (__attribute__((address_space(3))) void*)(l), 16, 0, 0);
}

// exact counted vmcnt (wt always lands on an enumerated value)
__device__ inline void vm_wait(int wt) {
    if (wt >= 12)      asm volatile("s_waitcnt vmcnt(12)" ::: "memory");
    else if (wt >= 8)  asm volatile("s_waitcnt vmcnt(8)" ::: "memory");
    else if (wt >= 6)  asm volatile("s_waitcnt vmcnt(6)" ::: "memory");
    else if (wt >= 4)  asm volatile("s_waitcnt vmcnt(4)" ::: "memory");
    else               asm volatile("s_waitcnt vmcnt(0)" ::: "memory");
}

// ---------------------------------------------------------------------------
__global__ void cb_norms(const float* __restrict__ codebook, float* __restrict__ cbn)
{
    int i = blockIdx.x * 256 + threadIdx.x;
    if (i < NEMB) {
        float s = 0.f;
#pragma unroll
        for (int k = 0; k < LDIM; ++k) {
            float v = codebook[(size_t)i * LDIM + k];
            s = fmaf(v, v, s);
        }
        cbn[i] = s;
    }
}

__global__ void zero_ctr(int* ctr) { if (threadIdx.x == 0) *ctr = 0; }

// ---------------------------------------------------------------------------
// Weight pre-transform: W[K][N] fp32 -> MFMA-B-ready plane(s).
// NT==1: bf16 single. NT==2: fp16 single. NT==3: bf16 hi+lo.
// ---------------------------------------------------------------------------
template <int NT, int BN>
__global__ __launch_bounds__(256) void w_xform(
    const float* __restrict__ W, int K, int N,
    unsigned short* __restrict__ Ph, unsigned short* __restrict__ Pl)
{
    __shared__ float Ws[32][BN + 4];
    const int tid = threadIdx.x;
    const int ks = blockIdx.x, nb = blockIdx.y;
    const int k0 = ks * 32, n0 = nb * BN;
    constexpr int LT = 32 * (BN / 4);
#pragma unroll
    for (int it = 0; it < (LT + 255) / 256; ++it) {
        int idx = tid + it * 256;
        if (LT % 256 == 0 || idx < LT) {
            int k = idx / (BN / 4);
            int nf = idx % (BN / 4);
            *(f32x4*)&Ws[k][nf * 4] =
                *(const f32x4*)&W[(size_t)(k0 + k) * N + n0 + nf * 4];
        }
    }
    __syncthreads();
    const int KS = K >> 5;
    size_t bo = ((size_t)nb * KS + ks) * (BN * 32);
    constexpr int WT = BN * 4;
#pragma unroll
    for (int it = 0; it < (WT + 255) / 256; ++it) {
        int idx = tid + it * 256;
        if (WT % 256 == 0 || idx < WT) {
            int kb = idx / BN;
            int n = idx % BN;
            short8 h, l;
#pragma unroll
            for (int j = 0; j < 8; ++j) {
                float x = Ws[kb * 8 + j][n];
                if (NT == 2) {
                    h[j] = (short)f2h(x);
                } else {
                    unsigned short hb_ = f2bf(x);
                    h[j] = (short)hb_;
                    if (NT == 3) l[j] = (short)f2bf(x - bf2f(hb_));
                }
            }
            *(short8*)&Ph[bo + (size_t)idx * 8] = h;
            if (NT == 3) *(short8*)&Pl[bo + (size_t)idx * 8] = l;
        }
    }
}

// ---------------------------------------------------------------------------
// OLD proven MFMA GEMM, 2-buf full-drain (fallback only).
// NT: 1=bf16 1-term, 2=fp16 A-split 2-term, 4=fp16 1-term.
// OUT: 1=bf16, 2=fp32, 4=fp16.
// ---------------------------------------------------------------------------
template <int NT, int BN, int OUT, int ACT>
__global__ __launch_bounds__(256, 2) void mfma_gemm(
    const unsigned short* __restrict__ Ah_g, const unsigned short* __restrict__ Al_g,
    int K,
    const unsigned short* __restrict__ Wh, const unsigned short* __restrict__ Wl,
    const float* __restrict__ bias,
    void* __restrict__ out0, void* __restrict__ out1, int NTOT)
{
    constexpr int NWC = (BN == 128) ? 2 : 1;
    constexpr int WM = (BN == 128) ? 4 : 2;
    constexpr int WN = (BN == 32) ? 2 : 4;
    constexpr int ABUF = (NT == 2 || NT == 3) ? 8192 : 4096;
    constexpr int BBUF = 4 * BN * 8;
    constexpr int BUFSH = ABUF + BBUF;

    __shared__ unsigned short smem[2 * BUFSH];

    const int tid = threadIdx.x;
    int row_t, nb;
    if constexpr (BN == 128) {
        int per = gridDim.x >> 3;
        int xcd = blockIdx.x & 7;
        int lid = blockIdx.x >> 3;
        int tile = xcd * per + lid;
        row_t = tile >> 3;
        nb = tile & 7;
    } else {
        row_t = blockIdx.x;
        nb = 0;
    }
    const int m0 = row_t * 128;
    const int n0 = nb * BN;
    const int w = tid >> 6, lane = tid & 63;
    const int g = lane >> 4, lr = lane & 15;
    const int wrow0 = (w / NWC) * (WM * 16);
    const int wcol0 = (w % NWC) * (WN * 16);
    const int KS = K >> 5;

    auto stage = [&](unsigned short* buf, int ks) {
        unsigned short* Ah = buf;
        unsigned short* Al = buf + 4096;
        unsigned short* Bh = buf + ABUF;
#pragma unroll
        for (int it = 0; it < 2; ++it) {
            int t0 = it * 256 + w * 64;
            int t = t0 + lane;
            int row = t & 127, kb = t >> 7;
            size_t go = (size_t)(m0 + row) * K + ks * 32 + kb * 8;
            gload16(Ah_g + go, Ah + (size_t)t0 * 8);
            if constexpr (NT == 2) gload16(Al_g + go, Al + (size_t)t0 * 8);
        }
        size_t bo = ((size_t)nb * KS + ks) * (BN * 32);
        constexpr int BT = 4 * BN;
#pragma unroll
        for (int it = 0; it < BT / 256; ++it) {
            int t0 = it * 256 + w * 64;
            size_t go = bo + (size_t)(t0 + lane) * 8;
            gload16(Wh + go, Bh + (size_t)t0 * 8);
        }
    };

    f32x4 acc[WM][WN];
#pragma unroll
    for (int m = 0; m < WM; ++m)
#pragma unroll
        for (int n = 0; n < WN; ++n) {
            acc[m][n][0] = 0.f; acc[m][n][1] = 0.f;
            acc[m][n][2] = 0.f; acc[m][n][3] = 0.f;
        }

    stage(smem, 0);

    for (int ks = 0; ks < KS; ++ks) {
        __syncthreads();
        unsigned short* buf = smem + (size_t)(ks & 1) * BUFSH;
        if (ks + 1 < KS)
            stage(smem + (size_t)((ks + 1) & 1) * BUFSH, ks + 1);

        unsigned short* Ah = buf;
        unsigned short* Al = buf + 4096;
        unsigned short* Bh = buf + ABUF;

        short8 ah[WM], bh[WN], al[WM];
#pragma unroll
        for (int m = 0; m < WM; ++m) {
            int ro = (g << 7) + wrow0 + m * 16 + lr;
            ah[m] = *(const short8*)&Ah[ro * 8];
            if constexpr (NT == 2) al[m] = *(const short8*)&Al[ro * 8];
        }
#pragma unroll
        for (int n = 0; n < WN; ++n) {
            int co = g * BN + wcol0 + n * 16 + lr;
            bh[n] = *(const short8*)&Bh[co * 8];
        }
#pragma unroll
        for (int m = 0; m < WM; ++m)
#pragma unroll
            for (int n = 0; n < WN; ++n) {
                if constexpr (NT == 2 || NT == 4) {
                    acc[m][n] = __builtin_amdgcn_mfma_f32_16x16x32_f16(
                        H8(ah[m]), H8(bh[n]), acc[m][n], 0, 0, 0);
                    if constexpr (NT == 2)
                        acc[m][n] = __builtin_amdgcn_mfma_f32_16x16x32_f16(
                            H8(al[m]), H8(bh[n]), acc[m][n], 0, 0, 0);
                } else {
                    acc[m][n] = __builtin_amdgcn_mfma_f32_16x16x32_bf16(
                        ah[m], bh[n], acc[m][n], 0, 0, 0);
                }
            }
    }

    float bv[WN];
#pragma unroll
    for (int n = 0; n < WN; ++n) bv[n] = bias[n0 + wcol0 + n * 16 + lr];

    unsigned short* Sb = smem;
    float* Sf = (float*)smem;

    __syncthreads();
#pragma unroll
    for (int m = 0; m < WM; ++m)
#pragma unroll
        for (int n = 0; n < WN; ++n)
#pragma unroll
            for (int q = 0; q < 4; ++q) {
                int rl = wrow0 + m * 16 + g * 4 + q;
                int cl = wcol0 + n * 16 + lr;
                float x = acc[m][n][q] + bv[n];
                if (ACT == 0) x = fmaxf(x, 0.f);
                else x = tanhf(x);
                if constexpr (OUT == 2) Sf[rl * BN + cl] = x;
                else if constexpr (OUT == 4) Sb[rl * BN + cl] = f2h(x);
                else Sb[rl * BN + cl] = f2bf(x);
            }
    __syncthreads();
    if constexpr (OUT == 2) {
        constexpr int SL = BN / 4;
#pragma unroll
        for (int it = 0; it < (128 * SL) / 256; ++it) {
            int idx = tid + it * 256;
            int row = idx / SL, sl = idx % SL;
            *(f32x4*)((float*)out0 + (size_t)(m0 + row) * NTOT + sl * 4)
                = *(const f32x4*)&Sf[row * BN + sl * 4];
        }
    } else {
        constexpr int SL = BN / 8;
        unsigned short* dst = (unsigned short*)out0;
#pragma unroll
        for (int it = 0; it < (128 * SL) / 256; ++it) {
            int idx = tid + it * 256;
            int row = idx / SL, sl = idx % SL;
            *(short8*)&dst[(size_t)(m0 + row) * NTOT + n0 + sl * 8]
                = *(const short8*)&Sb[row * BN + sl * 8];
        }
    }
}

// ---------------------------------------------------------------------------
// BN=128 MFMA GEMM, PAIRED D-deep counted-vmcnt pipeline (proven round 15).
// NT: 1=bf16 1-term (PAIR=4), 2=fp16 2-term (PAIR=6), 4=fp16 1-term (PAIR=4).
// NT4 D=3: 48 KB LDS -> 3 blocks/CU (round-16 occupancy lever).
// ---------------------------------------------------------------------------
template <int NT, int D, int OUT, int ACT>
__global__ __launch_bounds__(256, 2) void mfma_gemm128(
    const unsigned short* __restrict__ Ah_g, const unsigned short* __restrict__ Al_g,
    int K,
    const unsigned short* __restrict__ Wh, const unsigned short* __restrict__ Wl,
    const float* __restrict__ bias,
    void* __restrict__ out0, void* __restrict__ out1, int NTOT)
{
    constexpr int BN = 128;
    constexpr int WM = 4, WN = 4, NWC = 2;
    constexpr int ASTR = (NT == 2) ? 8192 : 4096;   // shorts per A buffer
    constexpr int BSTR = 4096;                      // shorts per B buffer
    constexpr int BOFF = D * ASTR;
    constexpr int PAIR = (NT == 2) ? 6 : 4;         // loads per {B,A} pair
    extern __shared__ unsigned short smem[];

    const int tid = threadIdx.x;
    int per = gridDim.x >> 3;
    int xcd = blockIdx.x & 7;
    int lid = blockIdx.x >> 3;
    int tile = xcd * per + lid;
    const int m0 = (tile >> 3) * 128;
    const int nb = tile & 7;
    const int n0 = nb * BN;
    const int w = tid >> 6, lane = tid & 63;
    const int g = lane >> 4, lr = lane & 15;
    const int wrow0 = (w / NWC) * (WM * 16);
    const int wcol0 = (w % NWC) * (WN * 16);
    const int KS = K >> 5;

    auto stageA = [&](int i, int ks) {
        unsigned short* Ah = smem + i * ASTR;
        unsigned short* Al = Ah + 4096;
#pragma unroll
        for (int it = 0; it < 2; ++it) {
            int t0 = it * 256 + w * 64;
            int t = t0 + lane;
            int row = t & 127, kb = t >> 7;
            size_t go = (size_t)(m0 + row) * K + ks * 32 + kb * 8;
            gload16(Ah_g + go, Ah + (size_t)t0 * 8);
            if constexpr (NT == 2) gload16(Al_g + go, Al + (size_t)t0 * 8);
        }
    };
    auto stageB = [&](int j, int ks) {
        unsigned short* Bh = smem + BOFF + j * BSTR;
        size_t bo = ((size_t)nb * KS + ks) * (BN * 32);
#pragma unroll
        for (int it = 0; it < 2; ++it) {
            int t0 = it * 256 + w * 64;
            size_t go = bo + (size_t)(t0 + lane) * 8;
            gload16(Wh + go, Bh + (size_t)t0 * 8);
        }
    };

    // bias first: oldest in vmcnt queue, retired by the first counted wait.
    float bv[WN];
#pragma unroll
    for (int n = 0; n < WN; ++n) bv[n] = bias[n0 + wcol0 + n * 16 + lr];
    __builtin_amdgcn_sched_barrier(0);

    f32x4 acc[WM][WN];
#pragma unroll
    for (int m = 0; m < WM; ++m)
#pragma unroll
        for (int n = 0; n < WN; ++n) {
            acc[m][n][0] = 0.f; acc[m][n][1] = 0.f;
            acc[m][n][2] = 0.f; acc[m][n][3] = 0.f;
        }

    // prologue: pairs {B(i),A(i)} for i = 0..D-2
#pragma unroll
    for (int i = 0; i < D - 1; ++i)
        if (i < KS) { stageB(i, i); stageA(i, i); }

    for (int ks = 0; ks < KS; ++ks) {
        __builtin_amdgcn_s_barrier();          // all waves done reading iter ks-1
        if (ks + D - 1 < KS) {                 // issue the pair for iter ks+D-1
            stageB((ks + D - 1) % D, ks + D - 1);
            stageA((ks + D - 1) % D, ks + D - 1);
        }
        int futP = KS - 1 - ks; if (futP > D - 1) futP = D - 1;
        vm_wait(futP * PAIR);                  // retire through pair(ks) exactly
        __builtin_amdgcn_s_barrier();          // all waves' pair(ks) landed
        __builtin_amdgcn_sched_barrier(0);

        unsigned short* Ah = smem + (ks % D) * ASTR;
        unsigned short* Al = Ah + 4096;
        unsigned short* Bh = smem + BOFF + (ks % D) * BSTR;

        short8 ah[WM], bh[WN], al[WM];
#pragma unroll
        for (int m = 0; m < WM; ++m) {
            int ro = (g << 7) + wrow0 + m * 16 + lr;
            ah[m] = *(const short8*)&Ah[ro * 8];
            if constexpr (NT == 2) al[m] = *(const short8*)&Al[ro * 8];
        }
#pragma unroll
        for (int n = 0; n < WN; ++n) {
            int co = g * BN + wcol0 + n * 16 + lr;
            bh[n] = *(const short8*)&Bh[co * 8];
        }
#pragma unroll
        for (int m = 0; m < WM; ++m)
#pragma unroll
            for (int n = 0; n < WN; ++n) {
                if constexpr (NT == 2 || NT == 4) {
                    acc[m][n] = __builtin_amdgcn_mfma_f32_16x16x32_f16(
                        H8(ah[m]), H8(bh[n]), acc[m][n], 0, 0, 0);
                    if constexpr (NT == 2)
                        acc[m][n] = __builtin_amdgcn_mfma_f32_16x16x32_f16(
                            H8(al[m]), H8(bh[n]), acc[m][n], 0, 0, 0);
                } else {
                    acc[m][n] = __builtin_amdgcn_mfma_f32_16x16x32_bf16(
                        ah[m], bh[n], acc[m][n], 0, 0, 0);
                }
            }
    }

    unsigned short* Sb = smem;
    float* Sf = (float*)smem;

    __syncthreads();
#pragma unroll
    for (int m = 0; m < WM; ++m)
#pragma unroll
        for (int n = 0; n < WN; ++n)
#pragma unroll
            for (int q = 0; q < 4; ++q) {
                int rl = wrow0 + m * 16 + g * 4 + q;
                int cl = wcol0 + n * 16 + lr;
                float x = acc[m][n][q] + bv[n];
                if (ACT == 0) x = fmaxf(x, 0.f);
                else x = tanhf(x);
                if constexpr (OUT == 2) Sf[rl * BN + cl] = x;
                else if constexpr (OUT == 4) Sb[rl * BN + cl] = f2h(x);
                else Sb[rl * BN + cl] = f2bf(x);
            }
    __syncthreads();
    if constexpr (OUT == 2) {
        constexpr int SL = BN / 4;
#pragma unroll
        for (int it = 0; it < (128 * SL) / 256; ++it) {
            int idx = tid + it * 256;
            int row = idx / SL, sl = idx % SL;
            *(f32x4*)((float*)out0 + (size_t)(m0 + row) * NTOT + sl * 4)
                = *(const f32x4*)&Sf[row * BN + sl * 4];
        }
    } else {
        constexpr int SL = BN / 8;
        unsigned short* dst = (unsigned short*)out0;
#pragma unroll
        for (int it = 0; it < (128 * SL) / 256; ++it) {
            int idx = tid + it * 256;
            int row = idx / SL, sl = idx % SL;
            *(short8*)&dst[(size_t)(m0 + row) * NTOT + n0 + sl * 8]
                = *(const short8*)&Sb[row * BN + sl * 8];
        }
    }
}

// ---------------------------------------------------------------------------
// BM=64 MFMA GEMM for small-N layers (G3: NT4/BN64 fp16, G6: NT1/BN32 bf16).
// ---------------------------------------------------------------------------
template <int NT, int BN, int ACT>
__global__ __launch_bounds__(256) void mfma_gemm64(
    const unsigned short* __restrict__ Ah_g, const unsigned short* __restrict__ Al_g,
    int K,
    const unsigned short* __restrict__ Wh, const unsigned short* __restrict__ Wl,
    const float* __restrict__ bias,
    float* __restrict__ out, int NTOT)
{
    constexpr int WM = (BN == 64) ? 2 : 1;
    constexpr int WN = 2;
    constexpr int ABUF = (NT == 2) ? 4096 : 2048;          // shorts
    constexpr int BBUF = BN * 32;
    constexpr int BUFSH = ABUF + BBUF;
    __shared__ unsigned short smem[2 * BUFSH];

    const int tid = threadIdx.x;
    const int m0 = blockIdx.x * 64;
    const int w = tid >> 6, lane = tid & 63;
    const int g = lane >> 4, lr = lane & 15;
    const int wrow0 = (BN == 64) ? ((w >> 1) * 32) : (w * 16);
    const int wcol0 = (BN == 64) ? ((w & 1) * 32) : 0;
    const int KS = K >> 5;

    auto stage = [&](unsigned short* buf, int ks) {
        unsigned short* Ah = buf;
        unsigned short* Al = buf + 2048;
        unsigned short* Bh = buf + ABUF;
        {
            int t0 = w * 64;
            int t = t0 + lane;
            int row = t & 63, kb = t >> 6;
            size_t go = (size_t)(m0 + row) * K + ks * 32 + kb * 8;
            gload16(Ah_g + go, Ah + (size_t)t0 * 8);
            if constexpr (NT == 2) gload16(Al_g + go, Al + (size_t)t0 * 8);
        }
        size_t bo = (size_t)ks * (BN * 32);
        constexpr int BT = BN * 4;
        if constexpr (BT == 256) {
            int t0 = w * 64;
            size_t go = bo + (size_t)(t0 + lane) * 8;
            gload16(Wh + go, Bh + (size_t)t0 * 8);
        } else {
            if (tid < BT) {
                int t0 = w * 64;
                size_t go = bo + (size_t)(t0 + lane) * 8;
                gload16(Wh + go, Bh + (size_t)t0 * 8);
            }
        }
    };

    f32x4 acc[WM][WN];
#pragma unroll
    for (int m = 0; m < WM; ++m)
#pragma unroll
        for (int n = 0; n < WN; ++n) {
            acc[m][n][0] = 0.f; acc[m][n][1] = 0.f;
            acc[m][n][2] = 0.f; acc[m][n][3] = 0.f;
        }

    stage(smem, 0);

    for (int ks = 0; ks < KS; ++ks) {
        __syncthreads();
        unsigned short* buf = smem + (size_t)(ks & 1) * BUFSH;
        if (ks + 1 < KS)
            stage(smem + (size_t)((ks + 1) & 1) * BUFSH, ks + 1);

        unsigned short* Ah = buf;
        unsigned short* Al = buf + 2048;
        unsigned short* Bh = buf + ABUF;

        short8 ah[WM], bh[WN], al[WM];
#pragma unroll
        for (int m = 0; m < WM; ++m) {
            int ro = (g << 6) + wrow0 + m * 16 + lr;
            ah[m] = *(const short8*)&Ah[ro * 8];
            if constexpr (NT == 2) al[m] = *(const short8*)&Al[ro * 8];
        }
#pragma unroll
        for (int n = 0; n < WN; ++n) {
            int co = g * BN + wcol0 + n * 16 + lr;
            bh[n] = *(const short8*)&Bh[co * 8];
        }
#pragma unroll
        for (int m = 0; m < WM; ++m)
#pragma unroll
            for (int n = 0; n < WN; ++n) {
                if constexpr (NT == 2 || NT == 4) {
                    acc[m][n] = __builtin_amdgcn_mfma_f32_16x16x32_f16(
                        H8(ah[m]), H8(bh[n]), acc[m][n], 0, 0, 0);
                    if constexpr (NT == 2)
                        acc[m][n] = __builtin_amdgcn_mfma_f32_16x16x32_f16(
                            H8(al[m]), H8(bh[n]), acc[m][n], 0, 0, 0);
                } else {
                    acc[m][n] = __builtin_amdgcn_mfma_f32_16x16x32_bf16(
                        ah[m], bh[n], acc[m][n], 0, 0, 0);
                }
            }
    }

    float bv[WN];
#pragma unroll
    for (int n = 0; n < WN; ++n) bv[n] = bias[wcol0 + n * 16 + lr];

    float* Sf = (float*)smem;
    __syncthreads();
#pragma unroll
    for (int m = 0; m < WM; ++m)
#pragma unroll
        for (int n = 0; n < WN; ++n)
#pragma unroll
            for (int q = 0; q < 4; ++q) {
                int rl = wrow0 + m * 16 + g * 4 + q;
                int cl = wcol0 + n * 16 + lr;
                float x = acc[m][n][q] + bv[n];
                if (ACT == 0) x = fmaxf(x, 0.f);
                else x = tanhf(x);
                Sf[rl * BN + cl] = x;
            }
    __syncthreads();
    constexpr int SL = BN / 4;
#pragma unroll
    for (int it = 0; it < (64 * SL) / 256; ++it) {
        int idx = tid + it * 256;
        int row = idx / SL, sl = idx % SL;
        *(f32x4*)(out + (size_t)(m0 + row) * NTOT + sl * 4)
            = *(const f32x4*)&Sf[row * BN + sl * 4];
    }
}

// ---------------------------------------------------------------------------
// fp32 fixup GEMM, 32-row tiles (proven round 9).
// ---------------------------------------------------------------------------
template <int BN, int ACT>
__global__ __launch_bounds__(256) void gemm_fix(
    const int* __restrict__ mrows,
    const float* __restrict__ A, int K,
    const float* __restrict__ W, const float* __restrict__ bias,
    float* __restrict__ Co, int N)
{
    const int m0 = blockIdx.x * 32;
    if (m0 >= *mrows) return;

    constexpr int TN = BN / 16;
    __shared__ float At[16][36];
    __shared__ float Bt[16][BN + 4];

    const int tid = threadIdx.x;
    const int n0 = blockIdx.y * BN;
    const int r = tid >> 4;
    const int c = tid & 15;

    float acc[2][TN];
#pragma unroll
    for (int i = 0; i < 2; ++i)
#pragma unroll
        for (int j = 0; j < TN; ++j) acc[i][j] = 0.f;

    for (int k0 = 0; k0 < K; k0 += 16) {
        if (tid < 128) {
            int row = tid >> 2;
            int lf = tid & 3;
            float4 v = *(const float4*)(A + (size_t)(m0 + row) * K + k0 + lf * 4);
            At[lf * 4 + 0][row] = v.x;
            At[lf * 4 + 1][row] = v.y;
            At[lf * 4 + 2][row] = v.z;
            At[lf * 4 + 3][row] = v.w;
        }
        constexpr int NF4 = BN / 4;
        constexpr int NEL = 16 * NF4;
#pragma unroll
        for (int it = 0; it < NEL / 256; ++it) {
            int idx = tid + it * 256;
            int kk = idx / NF4;
            int f = idx % NF4;
            float4 v = *(const float4*)(W + (size_t)(k0 + kk) * N + n0 + f * 4);
            *(float4*)&Bt[kk][f * 4] = v;
        }
        __syncthreads();

#pragma unroll
        for (int kk = 0; kk < 16; ++kk) {
            float a0 = At[kk][r * 2];
            float a1 = At[kk][r * 2 + 1];
            float b[TN];
            if constexpr (BN == 128) {
                float4 b0 = *(const float4*)&Bt[kk][c * 4];
                float4 b1 = *(const float4*)&Bt[kk][64 + c * 4];
                b[0] = b0.x; b[1] = b0.y; b[2] = b0.z; b[3] = b0.w;
                b[4] = b1.x; b[5] = b1.y; b[6] = b1.z; b[7] = b1.w;
            } else {
                float4 b0 = *(const float4*)&Bt[kk][c * 4];
                b[0] = b0.x; b[1] = b0.y; b[2] = b0.z; b[3] = b0.w;
            }
#pragma unroll
            for (int j = 0; j < TN; ++j) {
                acc[0][j] = fmaf(a0, b[j], acc[0][j]);
                acc[1][j] = fmaf(a1, b[j], acc[1][j]);
            }
        }
        __syncthreads();
    }

#pragma unroll
    for (int i = 0; i < 2; ++i) {
        size_t row = (size_t)(m0 + r * 2 + i);
        if constexpr (BN == 128) {
            float e[8];
#pragma unroll
            for (int j = 0; j < 8; ++j) {
                int col = (j < 4) ? (c * 4 + j) : (64 + c * 4 + (j - 4));
                float v = acc[i][j] + bias[n0 + col];
                if (ACT == 0) v = fmaxf(v, 0.f);
                e[j] = v;
            }
            float4 v0, v1;
            v0.x = e[0]; v0.y = e[1]; v0.z = e[2]; v0.w = e[3];
            v1.x = e[4]; v1.y = e[5]; v1.z = e[6]; v1.w = e[7];
            *(float4*)&Co[row * N + n0 + c * 4] = v0;
            *(float4*)&Co[row * N + n0 + 64 + c * 4] = v1;
        } else {
            float e[4];
#pragma unroll
            for (int j = 0; j < 4; ++j) {
                float v = acc[i][j] + bias[n0 + c * 4 + j];
                if (ACT == 0) v = fmaxf(v, 0.f);
                e[j] = v;
            }
            float4 v0;
            v0.x = e[0]; v0.y = e[1]; v0.z = e[2]; v0.w = e[3];
            *(float4*)&Co[row * N + n0 + c * 4] = v0;
        }
    }
}

// ---------------------------------------------------------------------------
// sa plane: fp16 single (round-16: A-low plane dropped; error analysis in log).
// ---------------------------------------------------------------------------
__global__ void sa_pre(const float* __restrict__ state, const float* __restrict__ action,
                       unsigned short* __restrict__ saH)
{
    int idx = blockIdx.x * 256 + threadIdx.x;
    int row = idx / 12, q = idx % 12;
    const float* src = (q < 8) ? (state + (size_t)row * 64 + q * 8)
                               : (action + (size_t)row * 32 + (q - 8) * 8);
    f32x4 v0 = *(const f32x4*)src;
    f32x4 v1 = *(const f32x4*)(src + 4);
    short8 h;
#pragma unroll
    for (int j = 0; j < 8; ++j) {
        float x = (j < 4) ? v0[j] : v1[j - 4];
        h[j] = (short)f2h(x);
    }
    *(short8*)&saH[(size_t)row * 96 + q * 8] = h;
}

// ---------------------------------------------------------------------------
// VQ score kernel: 64 rows x 512 codes per block, grid (M/64, 2).
// ---------------------------------------------------------------------------
__global__ __launch_bounds__(256) void vq_score(
    const float* __restrict__ midz,
    const float* __restrict__ codebook,
    const float* __restrict__ cbn,
    float4* __restrict__ part)
{
    __shared__ float Zt[64 * 68];
    __shared__ float Ct[64 * 68];
    __shared__ float cn[64];

    const int tid = threadIdx.x;
    const int m0 = blockIdx.x * 64;
    const int eh = blockIdx.y;
    const int r = tid >> 4;
    const int c = tid & 15;

#pragma unroll
    for (int it = 0; it < 4; ++it) {
        int idx = tid + it * 256;
        int row = idx >> 4, f = idx & 15;
        float4 v = *(const float4*)(midz + (size_t)(m0 + row) * 64 + f * 4);
        Zt[(f * 4 + 0) * 68 + row] = v.x;
        Zt[(f * 4 + 1) * 68 + row] = v.y;
        Zt[(f * 4 + 2) * 68 + row] = v.z;
        Zt[(f * 4 + 3) * 68 + row] = v.w;
    }

    float best[4], sec[4];
    int bidx[4];
#pragma unroll
    for (int i = 0; i < 4; ++i) { best[i] = 3.4e38f; sec[i] = 3.4e38f; bidx[i] = 0x7fffffff; }

    for (int ch = 0; ch < 8; ++ch) {
        int e0 = eh * 512 + ch * 64;
        __syncthreads();
#pragma unroll
        for (int it = 0; it < 4; ++it) {
            int idx = tid + it * 256;
            int e = idx >> 4, f = idx & 15;
            float4 v = *(const float4*)(codebook + (size_t)(e0 + e) * 64 + f * 4);
            Ct[(f * 4 + 0) * 68 + e] = v.x;
            Ct[(f * 4 + 1) * 68 + e] = v.y;
            Ct[(f * 4 + 2) * 68 + e] = v.z;
            Ct[(f * 4 + 3) * 68 + e] = v.w;
        }
        if (tid < 64) cn[tid] = cbn[e0 + tid];
        __syncthreads();

        float acc[4][4];
#pragma unroll
        for (int i = 0; i < 4; ++i)
#pragma unroll
            for (int j = 0; j < 4; ++j) acc[i][j] = 0.f;

#pragma unroll 8
        for (int kk = 0; kk < 64; ++kk) {
            float4 a = *(const float4*)&Zt[kk * 68 + r * 4];
            float4 b = *(const float4*)&Ct[kk * 68 + c * 4];
            acc[0][0] = fmaf(a.x, b.x, acc[0][0]);
            acc[0][1] = fmaf(a.x, b.y, acc[0][1]);
            acc[0][2] = fmaf(a.x, b.z, acc[0][2]);
            acc[0][3] = fmaf(a.x, b.w, acc[0][3]);
            acc[1][0] = fmaf(a.y, b.x, acc[1][0]);
            acc[1][1] = fmaf(a.y, b.y, acc[1][1]);
            acc[1][2] = fmaf(a.y, b.z, acc[1][2]);
            acc[1][3] = fmaf(a.y, b.w, acc[1][3]);
            acc[2][0] = fmaf(a.z, b.x, acc[2][0]);
            acc[2][1] = fmaf(a.z, b.y, acc[2][1]);
            acc[2][2] = fmaf(a.z, b.z, acc[2][2]);
            acc[2][3] = fmaf(a.z, b.w, acc[2][3]);
            acc[3][0] = fmaf(a.w, b.x, acc[3][0]);
            acc[3][1] = fmaf(a.w, b.y, acc[3][1]);
            acc[3][2] = fmaf(a.w, b.z, acc[3][2]);
            acc[3][3] = fmaf(a.w, b.w, acc[3][3]);
        }
#pragma unroll
        for (int i = 0; i < 4; ++i)
#pragma unroll
            for (int j = 0; j < 4; ++j) {
                int e = c * 4 + j;
                float s = cn[e] - 2.0f * acc[i][j];
                int gi = e0 + e;
                if (s < best[i] || (s == best[i] && gi < bidx[i])) {
                    sec[i] = best[i];
                    best[i] = s;
                    bidx[i] = gi;
                } else {
                    sec[i] = fminf(sec[i], s);
                }
            }
    }

#pragma unroll
    for (int i = 0; i < 4; ++i) {
#pragma unroll
        for (int m = 1; m < 16; m <<= 1) {
            float ob = __shfl_xor(best[i], m, 64);
            int oi = __shfl_xor(bidx[i], m, 64);
            float os = __shfl_xor(sec[i], m, 64);
            if (ob < best[i] || (ob == best[i] && oi < bidx[i])) {
                sec[i] = fminf(best[i], os);
                best[i] = ob;
                bidx[i] = oi;
            } else {
                sec[i] = fminf(sec[i], ob);
            }
        }
    }
    if (c == 0) {
#pragma unroll
        for (int i = 0; i < 4; ++i) {
            float4 p;
            p.x = best[i];
            p.y = sec[i];
            p.z = __int_as_float(bidx[i]);
            p.w = 0.f;
            part[(size_t)(m0 + r * 4 + i) * 2 + eh] = p;
        }
    }
}

// ---------------------------------------------------------------------------
// VQ merge + flag + latent head + state half of xz.  128 rows/block, grid mt.
// ---------------------------------------------------------------------------
__global__ __launch_bounds__(256) void vq_merge(
    const float4* __restrict__ part,
    const float* __restrict__ state_c,
    const float* __restrict__ codebook,
    const float* __restrict__ mean_w, const float* __restrict__ mean_b,
    const float* __restrict__ logstd_w, const float* __restrict__ logstd_b,
    const float* __restrict__ eps,
    float* __restrict__ mean_out, float* __restrict__ std_out,
    unsigned short* __restrict__ xz,
    int* __restrict__ ctr, int* __restrict__ list, int rowbase)
{
    __shared__ float mw[4160];
    __shared__ float lw[4160];
    __shared__ int sidx[128];

    const int tid = threadIdx.x;
    const int m0 = blockIdx.x * 128;

    if (tid < 128) {
        size_t row = (size_t)(m0 + tid);
        float4 p0 = part[row * 2 + 0];
        float4 p1 = part[row * 2 + 1];
        int i0 = __float_as_int(p0.z), i1 = __float_as_int(p1.z);
        float b, s;
        int ix;
        if (p0.x < p1.x || (p0.x == p1.x && i0 < i1)) {
            b = p0.x; ix = i0; s = fminf(p0.y, p1.x);
        } else {
            b = p1.x; ix = i1; s = fminf(p1.y, p0.x);
        }
        sidx[tid] = ix;
        if (s - b < TAU) {
            int p = atomicAdd(ctr, 1);
            list[p] = rowbase + m0 + tid;
        }
    }
#pragma unroll
    for (int it = 0; it < 4; ++it) {
        int idx = tid + it * 256;
        int k = idx >> 4, f = idx & 15;
        float4 v = *(const float4*)(mean_w + (size_t)k * 64 + f * 4);
        mw[k * 65 + f * 4 + 0] = v.x;
        mw[k * 65 + f * 4 + 1] = v.y;
        mw[k * 65 + f * 4 + 2] = v.z;
        mw[k * 65 + f * 4 + 3] = v.w;
        float4 w2 = *(const float4*)(logstd_w + (size_t)k * 64 + f * 4);
        lw[k * 65 + f * 4 + 0] = w2.x;
        lw[k * 65 + f * 4 + 1] = w2.y;
        lw[k * 65 + f * 4 + 2] = w2.z;
        lw[k * 65 + f * 4 + 3] = w2.w;
    }

    // state half -> xz cols 0..63 (independent of merge; no sync needed)
    {
        int row = tid >> 1;
        int d0 = (tid & 1) * 32;
        size_t so = (size_t)(m0 + row) * 64 + d0;
        size_t xo = (size_t)(m0 + row) * 128 + d0;
#pragma unroll
        for (int q = 0; q < 8; ++q) {
            f32x4 v = *(const f32x4*)&state_c[so + q * 4];
            unsigned short o[4];
            o[0] = f2bf(v[0]); o[1] = f2bf(v[1]);
            o[2] = f2bf(v[2]); o[3] = f2bf(v[3]);
            *(uint2*)&xz[xo + q * 4] = *(uint2*)o;
        }
    }
    __syncthreads();

    {
        int row = tid >> 1;
        int d0 = (tid & 1) * 32;
        int e = sidx[row];
        const float* cb = codebook + (size_t)e * 64;
        float mv[32], lv[32];
#pragma unroll
        for (int d = 0; d < 32; ++d) {
            mv[d] = mean_b[d0 + d];
            lv[d] = logstd_b[d0 + d];
        }
        for (int k = 0; k < 64; ++k) {
            float zk = cb[k];
#pragma unroll
            for (int d = 0; d < 32; ++d) {
                mv[d] = fmaf(zk, mw[k * 65 + d0 + d], mv[d]);
                lv[d] = fmaf(zk, lw[k * 65 + d0 + d], lv[d]);
            }
        }
        size_t ro = (size_t)(m0 + row) * 64 + d0;
        size_t xo = (size_t)(m0 + row) * 128 + 64 + d0;
#pragma unroll
        for (int d = 0; d < 32; ++d) {
            float mean = mv[d];
            float ls = fminf(fmaxf(lv[d], -4.f), 15.f);
            float sd = expf(ls);
            float z = fmaf(sd, eps[ro + d], mean);
            mean_out[ro + d] = mean;
            std_out[ro + d] = sd;
            xz[xo + d] = f2bf(z);
        }
    }
}

// ---------------------------------------------------------------------------
__global__ void gather_fix(const int* __restrict__ ctr, int* __restrict__ meta,
                           const int* __restrict__ list,
                           const float* __restrict__ state,
                           const float* __restrict__ action,
                           float* __restrict__ sa_fix)
{
    int cnt = *ctr; if (cnt > FMAX) cnt = FMAX;
    if (blockIdx.x == 0 && threadIdx.x == 0)
        meta[0] = (cnt + 31) & ~31;
    int t = blockIdx.x * 256 + threadIdx.x;
    if (t >= cnt * 24) return;
    int f = t / 24, q = t % 24;
    size_t g = (size_t)list[f];
    f32x4 v = (q < 16) ? *(const f32x4*)&state[g * 64 + q * 4]
                       : *(const f32x4*)&action[g * 32 + (q - 16) * 4];
    *(f32x4*)&sa_fix[(size_t)f * 96 + q * 4] = v;
}

// ---------------------------------------------------------------------------
__global__ __launch_bounds__(256) void vq_fix(
    const int* __restrict__ ctr, const int* __restrict__ list,
    const float* __restrict__ mz_fix,
    const float* __restrict__ codebook, const float* __restrict__ cbn,
    const float* __restrict__ mean_w, const float* __restrict__ mean_b,
    const float* __restrict__ logstd_w, const float* __restrict__ logstd_b,
    const float* __restrict__ eps,
    float* __restrict__ mean_out, float* __restrict__ std_out,
    unsigned short* __restrict__ xz)
{
    __shared__ float mzs[8][64];
    __shared__ float zns[8];
    __shared__ float sv[2048];
    __shared__ int si[2048];
    __shared__ int am_s[8];

    int cnt = *ctr; if (cnt > FMAX) cnt = FMAX;
    const int base = blockIdx.x * 8;
    if (base >= cnt) return;
    const int nr = min(8, cnt - base);
    const int tid = threadIdx.x;

    if (tid < 128) {
        int rr = tid >> 4, q = tid & 15;
        int src = base + ((rr < nr) ? rr : 0);
        *(f32x4*)&mzs[rr][q * 4] = *(const f32x4*)&mz_fix[(size_t)src * 64 + q * 4];
    }
    __syncthreads();
    if (tid < 8) {
        float s = 0.f;
#pragma unroll
        for (int k = 0; k < 64; ++k) s = fmaf(mzs[tid][k], mzs[tid][k], s);
        zns[tid] = s;
    }
    __syncthreads();

    float bb[8];
    int bi[8];
#pragma unroll
    for (int rr = 0; rr < 8; ++rr) { bb[rr] = 3.4e38f; bi[rr] = 0x7fffffff; }
    for (int j = 0; j < 4; ++j) {
        int code = tid + j * 256;
        const f32x4* cp = (const f32x4*)(codebook + (size_t)code * 64);
        float dot[8];
#pragma unroll
        for (int rr = 0; rr < 8; ++rr) dot[rr] = 0.f;
        for (int t = 0; t < 16; ++t) {
            f32x4 cv = cp[t];
#pragma unroll
            for (int e = 0; e < 4; ++e) {
                float cvv = cv[e];
#pragma unroll
                for (int rr = 0; rr < 8; ++rr)
                    dot[rr] = fmaf(mzs[rr][t * 4 + e], cvv, dot[rr]);
            }
        }
        float cnv = cbn[code];
#pragma unroll
        for (int rr = 0; rr < 8; ++rr) {
            float s = (zns[rr] + cnv) - 2.0f * dot[rr];
            if (s < bb[rr] || (s == bb[rr] && code < bi[rr])) {
                bb[rr] = s; bi[rr] = code;
            }
        }
    }
#pragma unroll
    for (int rr = 0; rr < 8; ++rr) {
        sv[rr * 256 + tid] = bb[rr];
        si[rr * 256 + tid] = bi[rr];
    }
    __syncthreads();
    if (tid < 8) {
        float b = 3.4e38f;
        int ix = 0x7fffffff;
        for (int t = 0; t < 256; ++t) {
            float v = sv[tid * 256 + t];
            int iv = si[tid * 256 + t];
            if (v < b || (v == b && iv < ix)) { b = v; ix = iv; }
        }
        am_s[tid] = ix;
    }
    __syncthreads();

    for (int jo = 0; jo < 2; ++jo) {
        int o = tid + jo * 256;
        int rr = o >> 6, d = o & 63;
        if (rr < nr) {
            int e = am_s[rr];
            size_t g = (size_t)list[base + rr];
            float mv = mean_b[d], lv = logstd_b[d];
            const float* cb = codebook + (size_t)e * 64;
            for (int k = 0; k < 64; ++k) {
                float zk = cb[k];
                mv = fmaf(zk, mean_w[(size_t)k * 64 + d], mv);
                lv = fmaf(zk, logstd_w[(size_t)k * 64 + d], lv);
            }
            float ls = fminf(fmaxf(lv, -4.f), 15.f);
            float sd = expf(ls);
            float z = fmaf(sd, eps[g * 64 + d], mv);
            mean_out[g * 64 + d] = mv;
            std_out[g * 64 + d] = sd;
            xz[g * 128 + 64 + d] = f2bf(z);
        }
    }
}

// ---------------------------------------------------------------------------
extern "C" void kernel_launch(void* const* d_in, const int* in_sizes, int n_in,
                              void* d_out, int out_size, void* d_ws, size_t ws_size,
                              hipStream_t stream)
{
    const float* state    = (const float*)d_in[0];
    const float* action   = (const float*)d_in[1];
    const float* eps      = (const float*)d_in[2];
    const float* enc_w1   = (const float*)d_in[3];
    const float* enc_b1   = (const float*)d_in[4];
    const float* enc_w2   = (const float*)d_in[5];
    const float* enc_b2   = (const float*)d_in[6];
    const float* enc_w3   = (const float*)d_in[7];
    const float* enc_b3   = (const float*)d_in[8];
    const float* mean_w   = (const float*)d_in[9];
    const float* mean_b   = (const float*)d_in[10];
    const float* logstd_w = (const float*)d_in[11];
    const float* logstd_b = (const float*)d_in[12];
    const float* codebook = (const float*)d_in[13];
    const float* dec_w1   = (const float*)d_in[14];
    const float* dec_b1   = (const float*)d_in[15];
    const float* dec_w2   = (const float*)d_in[16];
    const float* dec_b2   = (const float*)d_in[17];
    const float* dec_w3   = (const float*)d_in[18];
    const float* dec_b3   = (const float*)d_in[19];

    float* out = (float*)d_out;
    float* u_out = out;
    float* mean_out = out + (size_t)B_TOTAL * 32;
    float* std_out = mean_out + (size_t)B_TOTAL * 64;

    // ---- fixed ws region (~9.6 MB; fix buffers alias the dyn area) ----
    char* base = (char*)d_ws;
    float* cbn = (float*)base;                                   // 4096
    unsigned short* W1h = (unsigned short*)(base + 4096);        // fp16
    unsigned short* W2h = (unsigned short*)(base + 397312);      // fp16
    unsigned short* W3h = (unsigned short*)(base + 4591616);     // fp16
    unsigned short* W4h = (unsigned short*)(base + 4853760);     // bf16
    unsigned short* W5h = (unsigned short*)(base + 5115904);     // bf16
    unsigned short* W6h = (unsigned short*)(base + 7213056);     // bf16
    int* ctr            = (int*)(base + 7278592);                // 256
    int* flag_list      = (int*)(base + 7278848);                // 262144
    int* meta           = (int*)(base + 7540992);                // 256
    float4* part        = (float4*)(base + 7541248);             // 2097152
    const size_t FIXED  = 9638400;

    unsigned short* xz_g = (unsigned short*)(base + FIXED);      // 16 MB
    const size_t XZ_SZ = (size_t)B_TOTAL * 128 * 2;

    // dyn region: saH 192 + h1H 2048 + h2H 2048 + mz 256 = 4544 B per row
    const size_t per_row = 4544;
    size_t avail = (ws_size > FIXED + XZ_SZ) ? (ws_size - FIXED - XZ_SZ) : 0;
    long maxC = (long)(avail / per_row);
    int C = (int)(maxC / 1024) * 1024;
    if (C > B_TOTAL) C = B_TOTAL;
    if (C < 12288) C = 12288;   // >= fix-alias region (54.26 MB)

    char* dyn = base + FIXED + XZ_SZ;
    unsigned short* saH = (unsigned short*)dyn;                   // [C,96] fp16
    unsigned short* h1H = saH + (size_t)C * 96;                   // [C,1024] fp16
    unsigned short* h2H = h1H + (size_t)C * 1024;                 // [C,1024] fp16
    float* mz = (float*)(h2H + (size_t)C * 1024);                 // [C,64]
    unsigned short* hc = h1H;   // decoder reuse (bf16)
    unsigned short* hd = h2H;

    // fixup buffers alias dyn (phase B runs after all of phase A)
    float* sa_fix = (float*)dyn;                                  // 2359296
    float* h1_fix = (float*)(dyn + 2359296);                      // 25165824
    float* h2_fix = (float*)(dyn + 27525120);                     // 25165824
    float* mz_fix = (float*)(dyn + 52690944);                     // 1572864

    // dynamic-LDS attrs for the pipelined kernels (fallback to old if denied)
    bool deep = hipFuncSetAttribute(
        reinterpret_cast<const void*>(&mfma_gemm128<4, 3, 4, 0>),
        hipFuncAttributeMaxDynamicSharedMemorySize, 49152) == hipSuccess;
    deep = deep && hipFuncSetAttribute(
        reinterpret_cast<const void*>(&mfma_gemm128<1, 4, 1, 0>),
        hipFuncAttributeMaxDynamicSharedMemorySize, 65536) == hipSuccess;

    // ---- once per call ----
    cb_norms<<<dim3(4), dim3(256), 0, stream>>>(codebook, cbn);
    zero_ctr<<<dim3(1), dim3(64), 0, stream>>>(ctr);
    w_xform<2, 128><<<dim3(3, 8), dim3(256), 0, stream>>>(enc_w1, 96, 1024, W1h, nullptr);
    w_xform<2, 128><<<dim3(32, 8), dim3(256), 0, stream>>>(enc_w2, 1024, 1024, W2h, nullptr);
    w_xform<2, 64><<<dim3(32, 1), dim3(256), 0, stream>>>(enc_w3, 1024, 64, W3h, nullptr);
    w_xform<1, 128><<<dim3(4, 8), dim3(256), 0, stream>>>(dec_w1, 128, 1024, W4h, nullptr);
    w_xform<1, 128><<<dim3(32, 8), dim3(256), 0, stream>>>(dec_w2, 1024, 1024, W5h, nullptr);
    w_xform<1, 32><<<dim3(32, 1), dim3(256), 0, stream>>>(dec_w3, 1024, 32, W6h, nullptr);

    // ---- phase A: encoder (fp16 1-term, paired 3-deep, 3 blocks/CU) + VQ ----
    for (int r0 = 0; r0 < B_TOTAL; r0 += C) {
        int M = (r0 + C <= B_TOTAL) ? C : (B_TOTAL - r0);
        int mt = M / 128;

        sa_pre<<<dim3(M * 12 / 256), dim3(256), 0, stream>>>(
            state + (size_t)r0 * SDIM, action + (size_t)r0 * ADIM, saH);

        if (deep) {
            mfma_gemm128<4, 3, 4, 0><<<dim3(mt * 8), dim3(256), 49152, stream>>>(
                saH, nullptr, 96, W1h, nullptr, enc_b1, h1H, nullptr, 1024);
            mfma_gemm128<4, 3, 4, 0><<<dim3(mt * 8), dim3(256), 49152, stream>>>(
                h1H, nullptr, 1024, W2h, nullptr, enc_b2, h2H, nullptr, 1024);
        } else {
            mfma_gemm<4, 128, 4, 0><<<dim3(mt * 8), dim3(256), 0, stream>>>(
                saH, nullptr, 96, W1h, nullptr, enc_b1, h1H, nullptr, 1024);
            mfma_gemm<4, 128, 4, 0><<<dim3(mt * 8), dim3(256), 0, stream>>>(
                h1H, nullptr, 1024, W2h, nullptr, enc_b2, h2H, nullptr, 1024);
        }
        mfma_gemm64<4, 64, 0><<<dim3(M / 64), dim3(256), 0, stream>>>(
            h2H, nullptr, 1024, W3h, nullptr, enc_b3, mz, 64);

        vq_score<<<dim3(M / 64, 2), dim3(256), 0, stream>>>(
            mz, codebook, cbn, part + (size_t)r0 * 2);
        vq_merge<<<dim3(mt), dim3(256), 0, stream>>>(
            part + (size_t)r0 * 2, state + (size_t)r0 * SDIM, codebook,
            mean_w, mean_b, logstd_w, logstd_b,
            eps + (size_t)r0 * LDIM,
            mean_out + (size_t)r0 * LDIM, std_out + (size_t)r0 * LDIM,
            xz_g + (size_t)r0 * 128, ctr, flag_list, r0);
    }

    // ---- phase B: exact-fp32 fixup as 32-row-tile GEMMs on gathered rows ----
    gather_fix<<<dim3(FMAX * 24 / 256), dim3(256), 0, stream>>>(
        ctr, meta, flag_list, state, action, sa_fix);
    gemm_fix<128, 0><<<dim3(FMAX / 32, 8), dim3(256), 0, stream>>>(
        meta, sa_fix, 96, enc_w1, enc_b1, h1_fix, 1024);
    gemm_fix<128, 0><<<dim3(FMAX / 32, 8), dim3(256), 0, stream>>>(
        meta, h1_fix, 1024, enc_w2, enc_b2, h2_fix, 1024);
    gemm_fix<64, 0><<<dim3(FMAX / 32, 1), dim3(256), 0, stream>>>(
        meta, h2_fix, 1024, enc_w3, enc_b3, mz_fix, 64);
    vq_fix<<<dim3(FMAX / 8), dim3(256), 0, stream>>>(
        ctr, flag_list, mz_fix, codebook, cbn,
        mean_w, mean_b, logstd_w, logstd_b, eps,
        mean_out, std_out, xz_g);

    // ---- phase C: decoder (bf16 1-term, paired 4-deep) ----
    for (int r0 = 0; r0 < B_TOTAL; r0 += C) {
        int M = (r0 + C <= B_TOTAL) ? C : (B_TOTAL - r0);
        int mt = M / 128;

        if (deep) {
            mfma_gemm128<1, 4, 1, 0><<<dim3(mt * 8), dim3(256), 65536, stream>>>(
                xz_g + (size_t)r0 * 128, nullptr, 128, W4h, nullptr, dec_b1,
                hc, nullptr, 1024);
            mfma_gemm128<1, 4, 1, 0><<<dim3(mt * 8), dim3(256), 65536, stream>>>(
                hc, nullptr, 1024, W5h, nullptr, dec_b2, hd, nullptr, 1024);
        } else {
            mfma_gemm<1, 128, 1, 0><<<dim3(mt * 8), dim3(256), 0, stream>>>(
                xz_g + (size_t)r0 * 128, nullptr, 128, W4h, nullptr, dec_b1,
                hc, nullptr, 1024);
            mfma_gemm<1, 128, 1, 0><<<dim3(mt * 8), dim3(256), 0, stream>>>(
                hc, nullptr, 1024, W5h, nullptr, dec_b2, hd, nullptr, 1024);
        }
        mfma_gemm64<1, 32, 1><<<dim3(M / 64), dim3(256), 0, stream>>>(
            hd, nullptr, 1024, W6h, nullptr, dec_b3,
            u_out + (size_t)r0 * ADIM, 32);
    }
}

// Round 17
// 1171.428 us; speedup vs baseline: 1.2947x; 1.0241x over previous
//
#include <hip/hip_runtime.h>
#include <cstdint>
#include <cstddef>

#define B_TOTAL 65536
#define SDIM 64
#define ADIM 32
#define LDIM 64
#define HDIM 1024
#define NEMB 1024
#define TAU 0.125f
#define FMAX 6144

typedef __attribute__((ext_vector_type(8))) short short8;
typedef __attribute__((ext_vector_type(8))) _Float16 half8;
typedef __attribute__((ext_vector_type(4))) float f32x4;

__device__ inline unsigned short f2bf(float f) {
    unsigned int u = __float_as_uint(f);
    u += 0x7fffu + ((u >> 16) & 1u);
    return (unsigned short)(u >> 16);
}
__device__ inline float bf2f(unsigned short s) {
    return __uint_as_float(((unsigned int)s) << 16);
}
__device__ inline unsigned short f2h(float f) {
    _Float16 h = (_Float16)f;
    return __builtin_bit_cast(unsigned short, h);
}
__device__ inline float h2f(unsigned short s) {
    return (float)__builtin_bit_cast(_Float16, s);
}
__device__ inline half8 H8(short8 v) { return __builtin_bit_cast(half8, v); }

// async global->LDS, 16B per lane; LDS dest = wave-uniform base + lane*16.
__device__ inline void gload16(const unsigned short* g, unsigned short* l) {
    __builtin_amdgcn_global_load_lds(
        (__attribute__((address_space(1))) void*)(g),
        (__attribute__((address_space(3))) void*)(l), 16, 0, 0);
}

// exact counted vmcnt (wt always lands on an enumerated value)
__device__ inline void vm_wait(int wt) {
    if (wt >= 12)      asm volatile("s_waitcnt vmcnt(12)" ::: "memory");
    else if (wt >= 8)  asm volatile("s_waitcnt vmcnt(8)" ::: "memory");
    else if (wt >= 6)  asm volatile("s_waitcnt vmcnt(6)" ::: "memory");
    else if (wt >= 4)  asm volatile("s_waitcnt vmcnt(4)" ::: "memory");
    else               asm volatile("s_waitcnt vmcnt(0)" ::: "memory");
}

// ---------------------------------------------------------------------------
__global__ void cb_norms(const float* __restrict__ codebook, float* __restrict__ cbn)
{
    int i = blockIdx.x * 256 + threadIdx.x;
    if (i < NEMB) {
        float s = 0.f;
#pragma unroll
        for (int k = 0; k < LDIM; ++k) {
            float v = codebook[(size_t)i * LDIM + k];
            s = fmaf(v, v, s);
        }
        cbn[i] = s;
    }
}

__global__ void zero_ctr(int* ctr) { if (threadIdx.x == 0) *ctr = 0; }

// ---------------------------------------------------------------------------
// Weight pre-transform (old 32-k-block layout): NT==1 bf16, NT==2 fp16.
// ---------------------------------------------------------------------------
template <int NT, int BN>
__global__ __launch_bounds__(256) void w_xform(
    const float* __restrict__ W, int K, int N,
    unsigned short* __restrict__ Ph, unsigned short* __restrict__ Pl)
{
    __shared__ float Ws[32][BN + 4];
    const int tid = threadIdx.x;
    const int ks = blockIdx.x, nb = blockIdx.y;
    const int k0 = ks * 32, n0 = nb * BN;
    constexpr int LT = 32 * (BN / 4);
#pragma unroll
    for (int it = 0; it < (LT + 255) / 256; ++it) {
        int idx = tid + it * 256;
        if (LT % 256 == 0 || idx < LT) {
            int k = idx / (BN / 4);
            int nf = idx % (BN / 4);
            *(f32x4*)&Ws[k][nf * 4] =
                *(const f32x4*)&W[(size_t)(k0 + k) * N + n0 + nf * 4];
        }
    }
    __syncthreads();
    const int KS = K >> 5;
    size_t bo = ((size_t)nb * KS + ks) * (BN * 32);
    constexpr int WT = BN * 4;
#pragma unroll
    for (int it = 0; it < (WT + 255) / 256; ++it) {
        int idx = tid + it * 256;
        if (WT % 256 == 0 || idx < WT) {
            int kb = idx / BN;
            int n = idx % BN;
            short8 h;
#pragma unroll
            for (int j = 0; j < 8; ++j) {
                float x = Ws[kb * 8 + j][n];
                h[j] = (NT == 2) ? (short)f2h(x) : (short)f2bf(x);
            }
            *(short8*)&Ph[bo + (size_t)idx * 8] = h;
        }
    }
}

// ---------------------------------------------------------------------------
// NEW 256-tile pre-transform for the 8-phase kernel (N=1024 fixed).
// Block (kt64, colgrp128): grid (KT, 8); nb = y>>1, hb = y&1.
// Layout: P[ ((nb*KT+kt)*2+hb)*8192 + (kb*128+col)*8 + j ], k = kt*64+kb*8+j.
// ---------------------------------------------------------------------------
template <int FP16>
__global__ __launch_bounds__(256) void wx256(
    const float* __restrict__ W, int K, unsigned short* __restrict__ P)
{
    __shared__ float Ws[64][132];
    const int tid = threadIdx.x;
    const int kt = blockIdx.x;
    const int nb = blockIdx.y >> 1, hb = blockIdx.y & 1;
    const int n0 = nb * 256 + hb * 128;
    const int KT = K >> 6;
    // load 64 k x 128 cols
#pragma unroll
    for (int it = 0; it < 8; ++it) {
        int idx = tid + it * 256;          // 2048 f4 tasks
        int k = idx >> 5, nf = idx & 31;
        *(f32x4*)&Ws[k][nf * 4] =
            *(const f32x4*)&W[(size_t)(kt * 64 + k) * 1024 + n0 + nf * 4];
    }
    __syncthreads();
    size_t bo = (((size_t)nb * KT + kt) * 2 + hb) * 8192;
#pragma unroll
    for (int it = 0; it < 4; ++it) {
        int t = tid + it * 256;            // 1024 tasks: kb*128+col
        int kb = t >> 7, col = t & 127;
        short8 h;
#pragma unroll
        for (int j = 0; j < 8; ++j) {
            float x = Ws[kb * 8 + j][col];
            h[j] = FP16 ? (short)f2h(x) : (short)f2bf(x);
        }
        *(short8*)&P[bo + (size_t)t * 8] = h;
    }
}

// ---------------------------------------------------------------------------
// NEW: 256x256 8-phase MFMA GEMM (K=1024 layers), 512 threads, dyn LDS 128KB.
// Ledger (hand-verified r17): prologue stages ktiles 0,1; iter t: phases 1-4
// compute ktile 2t and issue halves of 2t+1 (A0,B0,B1,A1); phases 5-8 compute
// 2t+1 and issue 2t+2.  vmcnt(2) at p1/p5 (0 at p5-tail) retires the needed
// ktile exactly; barriers only at p1, end-p4, p5, end-p8.
// FP16: 1 = fp16 in/out, 0 = bf16 in/out.  ACT: 0 relu.
// ---------------------------------------------------------------------------
template <int FP16, int ACT>
__global__ __launch_bounds__(512, 1) void mfma_gemm256(
    const unsigned short* __restrict__ Ag, int K,
    const unsigned short* __restrict__ Wg,
    const float* __restrict__ bias,
    unsigned short* __restrict__ out0, int NTOT)
{
    extern __shared__ unsigned short smem[];
    const int tid = threadIdx.x;
    const int w = tid >> 6, lane = tid & 63;
    const int g = lane >> 4, lr = lane & 15;
    int per = gridDim.x >> 3;
    int xcd = blockIdx.x & 7;
    int lid = blockIdx.x >> 3;
    int tile = xcd * per + lid;
    const int m0 = (tile >> 2) * 256;
    const int nb = tile & 3;
    const int n0 = nb * 256;
    const int wrow0 = (w >> 2) * 128;      // 0 or 128
    const int wcol0 = (w & 3) * 64;        // 0,64,128,192
    const int hA = wrow0 >> 7;
    const int hB = wcol0 >> 7;
    const int cB0 = (wcol0 & 127);
    const int KT = K >> 6;
    const int T = KT >> 1;

    auto stageAh = [&](int kt, int h) {    // one A half-tile = 2 gloads
        unsigned short* dst = smem + (((kt & 1) * 2 + h) * 8192);
#pragma unroll
        for (int it = 0; it < 2; ++it) {
            int t0 = it * 512 + (w << 6);
            int tt = t0 + lane;
            int kb = tt >> 7, row = tt & 127;
            size_t go = (size_t)(m0 + h * 128 + row) * K + (size_t)kt * 64 + kb * 8;
            gload16(Ag + go, dst + (size_t)t0 * 8);
        }
    };
    auto stageBh = [&](int kt, int h) {    // one B half-tile = 2 gloads
        unsigned short* dst = smem + 32768 + (((kt & 1) * 2 + h) * 8192);
        size_t bo = (((size_t)nb * KT + kt) * 2 + h) * 8192;
#pragma unroll
        for (int it = 0; it < 2; ++it) {
            int t0 = it * 512 + (w << 6);
            gload16(Wg + bo + (size_t)(t0 + lane) * 8, dst + (size_t)t0 * 8);
        }
    };

    float bv[4];
#pragma unroll
    for (int n = 0; n < 4; ++n) bv[n] = bias[n0 + wcol0 + n * 16 + lr];
    asm volatile("s_waitcnt vmcnt(0)" ::: "memory");   // bias out of vm queue
    __builtin_amdgcn_sched_barrier(0);

    f32x4 acc[8][4];
#pragma unroll
    for (int m = 0; m < 8; ++m)
#pragma unroll
        for (int n = 0; n < 4; ++n) {
            acc[m][n][0] = 0.f; acc[m][n][1] = 0.f;
            acc[m][n][2] = 0.f; acc[m][n][3] = 0.f;
        }

    short8 bf[4][2];

    // compute phase macro: ktc = ktile, MP = m-pair index (compile-time), LB = load B frags
#define CPH(ktc, MP, LB) do {                                                   \
        unsigned short* Ab = smem + ((((ktc) & 1) * 2 + hA) * 8192);            \
        unsigned short* Bb = smem + 32768 + ((((ktc) & 1) * 2 + hB) * 8192);    \
        if (LB) {                                                               \
            _Pragma("unroll") for (int n = 0; n < 4; ++n)                       \
            _Pragma("unroll") for (int s = 0; s < 2; ++s)                       \
                bf[n][s] = *(const short8*)&Bb[((s * 4 + g) * 128 + cB0 + n * 16 + lr) * 8]; \
        }                                                                       \
        short8 af[2][2];                                                        \
        _Pragma("unroll") for (int mm = 0; mm < 2; ++mm)                        \
        _Pragma("unroll") for (int s = 0; s < 2; ++s)                           \
            af[mm][s] = *(const short8*)&Ab[((s * 4 + g) * 128 + ((MP) * 2 + mm) * 16 + lr) * 8]; \
        asm volatile("s_waitcnt lgkmcnt(0)" ::: "memory");                      \
        __builtin_amdgcn_sched_barrier(0);                                      \
        __builtin_amdgcn_s_setprio(1);                                          \
        _Pragma("unroll") for (int mm = 0; mm < 2; ++mm)                        \
        _Pragma("unroll") for (int n = 0; n < 4; ++n)                           \
        _Pragma("unroll") for (int s = 0; s < 2; ++s) {                         \
            if (FP16) acc[(MP) * 2 + mm][n] = __builtin_amdgcn_mfma_f32_16x16x32_f16( \
                H8(af[mm][s]), H8(bf[n][s]), acc[(MP) * 2 + mm][n], 0, 0, 0);   \
            else acc[(MP) * 2 + mm][n] = __builtin_amdgcn_mfma_f32_16x16x32_bf16( \
                af[mm][s], bf[n][s], acc[(MP) * 2 + mm][n], 0, 0, 0);           \
        }                                                                       \
        __builtin_amdgcn_s_setprio(0);                                          \
    } while (0)

    // prologue: ktiles 0,1 (order matters for the vmcnt ledger)
    stageAh(0, 0); stageBh(0, 0); stageBh(0, 1); stageAh(0, 1);
    stageAh(1, 0); stageBh(1, 0); stageBh(1, 1); stageAh(1, 1);

    for (int t = 0; t < T; ++t) {
        int k0t = 2 * t, k1t = 2 * t + 1;
        // ---- phase 1 ----
        if (t > 0) stageAh(k1t, 0);
        asm volatile("s_waitcnt vmcnt(2)" ::: "memory");   // ktile 2t fully landed
        __builtin_amdgcn_s_barrier();
        CPH(k0t, 0, 1);
        // ---- phase 2 ----
        if (t > 0) stageBh(k1t, 0);
        CPH(k0t, 1, 0);
        // ---- phase 3 ----
        if (t > 0) stageBh(k1t, 1);
        CPH(k0t, 2, 0);
        // ---- phase 4 ----
        if (t > 0) stageAh(k1t, 1);
        CPH(k0t, 3, 0);
        __builtin_amdgcn_s_barrier();                      // 2t slots now dead
        // ---- phase 5 ----
        if (k0t + 2 < KT) {
            stageAh(k0t + 2, 0);
            asm volatile("s_waitcnt vmcnt(2)" ::: "memory");
        } else {
            asm volatile("s_waitcnt vmcnt(0)" ::: "memory");
        }
        __builtin_amdgcn_s_barrier();
        CPH(k1t, 0, 1);
        // ---- phase 6 ----
        if (k0t + 2 < KT) stageBh(k0t + 2, 0);
        CPH(k1t, 1, 0);
        // ---- phase 7 ----
        if (k0t + 2 < KT) stageBh(k0t + 2, 1);
        CPH(k1t, 2, 0);
        // ---- phase 8 ----
        if (k0t + 2 < KT) stageAh(k0t + 2, 1);
        CPH(k1t, 3, 0);
        __builtin_amdgcn_s_barrier();                      // 2t+1 slots now dead
    }
#undef CPH

    // ---- epilogue: bias + act, LDS transpose (256x256 shorts = 128 KB) ----
    unsigned short* Sb = smem;
    __builtin_amdgcn_s_barrier();
#pragma unroll
    for (int m = 0; m < 8; ++m)
#pragma unroll
        for (int n = 0; n < 4; ++n)
#pragma unroll
            for (int q = 0; q < 4; ++q) {
                int rl = wrow0 + m * 16 + g * 4 + q;
                int cl = wcol0 + n * 16 + lr;
                float x = acc[m][n][q] + bv[n];
                if (ACT == 0) x = fmaxf(x, 0.f);
                else x = tanhf(x);
                Sb[rl * 256 + cl] = FP16 ? f2h(x) : f2bf(x);
            }
    __syncthreads();
#pragma unroll
    for (int it = 0; it < 16; ++it) {
        int idx = tid + it * 512;          // 8192 tasks: row x 32 short8-slots
        int row = idx >> 5, sl = idx & 31;
        *(short8*)&out0[(size_t)(m0 + row) * NTOT + n0 + sl * 8]
            = *(const short8*)&Sb[row * 256 + sl * 8];
    }
}

// ---------------------------------------------------------------------------
// Paired D-deep BN=128 kernel (proven r15/r16) for G1/G4.
// NT: 1=bf16 1-term (PAIR=4), 4=fp16 1-term (PAIR=4).  OUT: 1=bf16, 4=fp16.
// ---------------------------------------------------------------------------
template <int NT, int D, int OUT, int ACT>
__global__ __launch_bounds__(256, 2) void mfma_gemm128(
    const unsigned short* __restrict__ Ah_g, int K,
    const unsigned short* __restrict__ Wh,
    const float* __restrict__ bias,
    void* __restrict__ out0, int NTOT)
{
    constexpr int BN = 128;
    constexpr int WM = 4, WN = 4, NWC = 2;
    constexpr int ASTR = 4096;
    constexpr int BSTR = 4096;
    constexpr int BOFF = D * ASTR;
    constexpr int PAIR = 4;
    extern __shared__ unsigned short smem[];

    const int tid = threadIdx.x;
    int per = gridDim.x >> 3;
    int xcd = blockIdx.x & 7;
    int lid = blockIdx.x >> 3;
    int tile = xcd * per + lid;
    const int m0 = (tile >> 3) * 128;
    const int nb = tile & 7;
    const int n0 = nb * BN;
    const int w = tid >> 6, lane = tid & 63;
    const int g = lane >> 4, lr = lane & 15;
    const int wrow0 = (w / NWC) * (WM * 16);
    const int wcol0 = (w % NWC) * (WN * 16);
    const int KS = K >> 5;

    auto stageA = [&](int i, int ks) {
        unsigned short* Ah = smem + i * ASTR;
#pragma unroll
        for (int it = 0; it < 2; ++it) {
            int t0 = it * 256 + w * 64;
            int t = t0 + lane;
            int row = t & 127, kb = t >> 7;
            size_t go = (size_t)(m0 + row) * K + ks * 32 + kb * 8;
            gload16(Ah_g + go, Ah + (size_t)t0 * 8);
        }
    };
    auto stageB = [&](int j, int ks) {
        unsigned short* Bh = smem + BOFF + j * BSTR;
        size_t bo = ((size_t)nb * KS + ks) * (BN * 32);
#pragma unroll
        for (int it = 0; it < 2; ++it) {
            int t0 = it * 256 + w * 64;
            size_t go = bo + (size_t)(t0 + lane) * 8;
            gload16(Wh + go, Bh + (size_t)t0 * 8);
        }
    };

    float bv[WN];
#pragma unroll
    for (int n = 0; n < WN; ++n) bv[n] = bias[n0 + wcol0 + n * 16 + lr];
    __builtin_amdgcn_sched_barrier(0);

    f32x4 acc[WM][WN];
#pragma unroll
    for (int m = 0; m < WM; ++m)
#pragma unroll
        for (int n = 0; n < WN; ++n) {
            acc[m][n][0] = 0.f; acc[m][n][1] = 0.f;
            acc[m][n][2] = 0.f; acc[m][n][3] = 0.f;
        }

#pragma unroll
    for (int i = 0; i < D - 1; ++i)
        if (i < KS) { stageB(i, i); stageA(i, i); }

    for (int ks = 0; ks < KS; ++ks) {
        __builtin_amdgcn_s_barrier();
        if (ks + D - 1 < KS) {
            stageB((ks + D - 1) % D, ks + D - 1);
            stageA((ks + D - 1) % D, ks + D - 1);
        }
        int futP = KS - 1 - ks; if (futP > D - 1) futP = D - 1;
        vm_wait(futP * PAIR);
        __builtin_amdgcn_s_barrier();
        __builtin_amdgcn_sched_barrier(0);

        unsigned short* Ah = smem + (ks % D) * ASTR;
        unsigned short* Bh = smem + BOFF + (ks % D) * BSTR;

        short8 ah[WM], bh[WN];
#pragma unroll
        for (int m = 0; m < WM; ++m) {
            int ro = (g << 7) + wrow0 + m * 16 + lr;
            ah[m] = *(const short8*)&Ah[ro * 8];
        }
#pragma unroll
        for (int n = 0; n < WN; ++n) {
            int co = g * BN + wcol0 + n * 16 + lr;
            bh[n] = *(const short8*)&Bh[co * 8];
        }
#pragma unroll
        for (int m = 0; m < WM; ++m)
#pragma unroll
            for (int n = 0; n < WN; ++n) {
                if constexpr (NT == 4) {
                    acc[m][n] = __builtin_amdgcn_mfma_f32_16x16x32_f16(
                        H8(ah[m]), H8(bh[n]), acc[m][n], 0, 0, 0);
                } else {
                    acc[m][n] = __builtin_amdgcn_mfma_f32_16x16x32_bf16(
                        ah[m], bh[n], acc[m][n], 0, 0, 0);
                }
            }
    }

    unsigned short* Sb = smem;
    __syncthreads();
#pragma unroll
    for (int m = 0; m < WM; ++m)
#pragma unroll
        for (int n = 0; n < WN; ++n)
#pragma unroll
            for (int q = 0; q < 4; ++q) {
                int rl = wrow0 + m * 16 + g * 4 + q;
                int cl = wcol0 + n * 16 + lr;
                float x = acc[m][n][q] + bv[n];
                if (ACT == 0) x = fmaxf(x, 0.f);
                else x = tanhf(x);
                Sb[rl * BN + cl] = (OUT == 4) ? f2h(x) : f2bf(x);
            }
    __syncthreads();
    constexpr int SL = BN / 8;
    unsigned short* dst = (unsigned short*)out0;
#pragma unroll
    for (int it = 0; it < (128 * SL) / 256; ++it) {
        int idx = tid + it * 256;
        int row = idx / SL, sl = idx % SL;
        *(short8*)&dst[(size_t)(m0 + row) * NTOT + n0 + sl * 8]
            = *(const short8*)&Sb[row * BN + sl * 8];
    }
}

// ---------------------------------------------------------------------------
// BM=64 MFMA GEMM for small-N layers (G3: NT4/BN64 fp16, G6: NT1/BN32 bf16).
// ---------------------------------------------------------------------------
template <int NT, int BN, int ACT>
__global__ __launch_bounds__(256) void mfma_gemm64(
    const unsigned short* __restrict__ Ah_g, int K,
    const unsigned short* __restrict__ Wh,
    const float* __restrict__ bias,
    float* __restrict__ out, int NTOT)
{
    constexpr int WM = (BN == 64) ? 2 : 1;
    constexpr int WN = 2;
    constexpr int ABUF = 2048;
    constexpr int BBUF = BN * 32;
    constexpr int BUFSH = ABUF + BBUF;
    __shared__ unsigned short smem[2 * BUFSH];

    const int tid = threadIdx.x;
    const int m0 = blockIdx.x * 64;
    const int w = tid >> 6, lane = tid & 63;
    const int g = lane >> 4, lr = lane & 15;
    const int wrow0 = (BN == 64) ? ((w >> 1) * 32) : (w * 16);
    const int wcol0 = (BN == 64) ? ((w & 1) * 32) : 0;
    const int KS = K >> 5;

    auto stage = [&](unsigned short* buf, int ks) {
        unsigned short* Ah = buf;
        unsigned short* Bh = buf + ABUF;
        {
            int t0 = w * 64;
            int t = t0 + lane;
            int row = t & 63, kb = t >> 6;
            size_t go = (size_t)(m0 + row) * K + ks * 32 + kb * 8;
            gload16(Ah_g + go, Ah + (size_t)t0 * 8);
        }
        size_t bo = (size_t)ks * (BN * 32);
        constexpr int BT = BN * 4;
        if constexpr (BT == 256) {
            int t0 = w * 64;
            size_t go = bo + (size_t)(t0 + lane) * 8;
            gload16(Wh + go, Bh + (size_t)t0 * 8);
        } else {
            if (tid < BT) {
                int t0 = w * 64;
                size_t go = bo + (size_t)(t0 + lane) * 8;
                gload16(Wh + go, Bh + (size_t)t0 * 8);
            }
        }
    };

    f32x4 acc[WM][WN];
#pragma unroll
    for (int m = 0; m < WM; ++m)
#pragma unroll
        for (int n = 0; n < WN; ++n) {
            acc[m][n][0] = 0.f; acc[m][n][1] = 0.f;
            acc[m][n][2] = 0.f; acc[m][n][3] = 0.f;
        }

    stage(smem, 0);

    for (int ks = 0; ks < KS; ++ks) {
        __syncthreads();
        unsigned short* buf = smem + (size_t)(ks & 1) * BUFSH;
        if (ks + 1 < KS)
            stage(smem + (size_t)((ks + 1) & 1) * BUFSH, ks + 1);

        unsigned short* Ah = buf;
        unsigned short* Bh = buf + ABUF;

        short8 ah[WM], bh[WN];
#pragma unroll
        for (int m = 0; m < WM; ++m) {
            int ro = (g << 6) + wrow0 + m * 16 + lr;
            ah[m] = *(const short8*)&Ah[ro * 8];
        }
#pragma unroll
        for (int n = 0; n < WN; ++n) {
            int co = g * BN + wcol0 + n * 16 + lr;
            bh[n] = *(const short8*)&Bh[co * 8];
        }
#pragma unroll
        for (int m = 0; m < WM; ++m)
#pragma unroll
            for (int n = 0; n < WN; ++n) {
                if constexpr (NT == 4) {
                    acc[m][n] = __builtin_amdgcn_mfma_f32_16x16x32_f16(
                        H8(ah[m]), H8(bh[n]), acc[m][n], 0, 0, 0);
                } else {
                    acc[m][n] = __builtin_amdgcn_mfma_f32_16x16x32_bf16(
                        ah[m], bh[n], acc[m][n], 0, 0, 0);
                }
            }
    }

    float bv[WN];
#pragma unroll
    for (int n = 0; n < WN; ++n) bv[n] = bias[wcol0 + n * 16 + lr];

    float* Sf = (float*)smem;
    __syncthreads();
#pragma unroll
    for (int m = 0; m < WM; ++m)
#pragma unroll
        for (int n = 0; n < WN; ++n)
#pragma unroll
            for (int q = 0; q < 4; ++q) {
                int rl = wrow0 + m * 16 + g * 4 + q;
                int cl = wcol0 + n * 16 + lr;
                float x = acc[m][n][q] + bv[n];
                if (ACT == 0) x = fmaxf(x, 0.f);
                else x = tanhf(x);
                Sf[rl * BN + cl] = x;
            }
    __syncthreads();
    constexpr int SL = BN / 4;
#pragma unroll
    for (int it = 0; it < (64 * SL) / 256; ++it) {
        int idx = tid + it * 256;
        int row = idx / SL, sl = idx % SL;
        *(f32x4*)(out + (size_t)(m0 + row) * NTOT + sl * 4)
            = *(const f32x4*)&Sf[row * BN + sl * 4];
    }
}

// ---------------------------------------------------------------------------
// fp32 fixup GEMM, 32-row tiles (proven round 9).
// ---------------------------------------------------------------------------
template <int BN, int ACT>
__global__ __launch_bounds__(256) void gemm_fix(
    const int* __restrict__ mrows,
    const float* __restrict__ A, int K,
    const float* __restrict__ W, const float* __restrict__ bias,
    float* __restrict__ Co, int N)
{
    const int m0 = blockIdx.x * 32;
    if (m0 >= *mrows) return;

    constexpr int TN = BN / 16;
    __shared__ float At[16][36];
    __shared__ float Bt[16][BN + 4];

    const int tid = threadIdx.x;
    const int n0 = blockIdx.y * BN;
    const int r = tid >> 4;
    const int c = tid & 15;

    float acc[2][TN];
#pragma unroll
    for (int i = 0; i < 2; ++i)
#pragma unroll
        for (int j = 0; j < TN; ++j) acc[i][j] = 0.f;

    for (int k0 = 0; k0 < K; k0 += 16) {
        if (tid < 128) {
            int row = tid >> 2;
            int lf = tid & 3;
            float4 v = *(const float4*)(A + (size_t)(m0 + row) * K + k0 + lf * 4);
            At[lf * 4 + 0][row] = v.x;
            At[lf * 4 + 1][row] = v.y;
            At[lf * 4 + 2][row] = v.z;
            At[lf * 4 + 3][row] = v.w;
        }
        constexpr int NF4 = BN / 4;
        constexpr int NEL = 16 * NF4;
#pragma unroll
        for (int it = 0; it < NEL / 256; ++it) {
            int idx = tid + it * 256;
            int kk = idx / NF4;
            int f = idx % NF4;
            float4 v = *(const float4*)(W + (size_t)(k0 + kk) * N + n0 + f * 4);
            *(float4*)&Bt[kk][f * 4] = v;
        }
        __syncthreads();

#pragma unroll
        for (int kk = 0; kk < 16; ++kk) {
            float a0 = At[kk][r * 2];
            float a1 = At[kk][r * 2 + 1];
            float b[TN];
            if constexpr (BN == 128) {
                float4 b0 = *(const float4*)&Bt[kk][c * 4];
                float4 b1 = *(const float4*)&Bt[kk][64 + c * 4];
                b[0] = b0.x; b[1] = b0.y; b[2] = b0.z; b[3] = b0.w;
                b[4] = b1.x; b[5] = b1.y; b[6] = b1.z; b[7] = b1.w;
            } else {
                float4 b0 = *(const float4*)&Bt[kk][c * 4];
                b[0] = b0.x; b[1] = b0.y; b[2] = b0.z; b[3] = b0.w;
            }
#pragma unroll
            for (int j = 0; j < TN; ++j) {
                acc[0][j] = fmaf(a0, b[j], acc[0][j]);
                acc[1][j] = fmaf(a1, b[j], acc[1][j]);
            }
        }
        __syncthreads();
    }

#pragma unroll
    for (int i = 0; i < 2; ++i) {
        size_t row = (size_t)(m0 + r * 2 + i);
        if constexpr (BN == 128) {
            float e[8];
#pragma unroll
            for (int j = 0; j < 8; ++j) {
                int col = (j < 4) ? (c * 4 + j) : (64 + c * 4 + (j - 4));
                float v = acc[i][j] + bias[n0 + col];
                if (ACT == 0) v = fmaxf(v, 0.f);
                e[j] = v;
            }
            float4 v0, v1;
            v0.x = e[0]; v0.y = e[1]; v0.z = e[2]; v0.w = e[3];
            v1.x = e[4]; v1.y = e[5]; v1.z = e[6]; v1.w = e[7];
            *(float4*)&Co[row * N + n0 + c * 4] = v0;
            *(float4*)&Co[row * N + n0 + 64 + c * 4] = v1;
        } else {
            float e[4];
#pragma unroll
            for (int j = 0; j < 4; ++j) {
                float v = acc[i][j] + bias[n0 + c * 4 + j];
                if (ACT == 0) v = fmaxf(v, 0.f);
                e[j] = v;
            }
            float4 v0;
            v0.x = e[0]; v0.y = e[1]; v0.z = e[2]; v0.w = e[3];
            *(float4*)&Co[row * N + n0 + c * 4] = v0;
        }
    }
}

// ---------------------------------------------------------------------------
__global__ void sa_pre(const float* __restrict__ state, const float* __restrict__ action,
                       unsigned short* __restrict__ saH)
{
    int idx = blockIdx.x * 256 + threadIdx.x;
    int row = idx / 12, q = idx % 12;
    const float* src = (q < 8) ? (state + (size_t)row * 64 + q * 8)
                               : (action + (size_t)row * 32 + (q - 8) * 8);
    f32x4 v0 = *(const f32x4*)src;
    f32x4 v1 = *(const f32x4*)(src + 4);
    short8 h;
#pragma unroll
    for (int j = 0; j < 8; ++j) {
        float x = (j < 4) ? v0[j] : v1[j - 4];
        h[j] = (short)f2h(x);
    }
    *(short8*)&saH[(size_t)row * 96 + q * 8] = h;
}

// ---------------------------------------------------------------------------
// VQ score kernel: 64 rows x 512 codes per block, grid (M/64, 2).
// ---------------------------------------------------------------------------
__global__ __launch_bounds__(256) void vq_score(
    const float* __restrict__ midz,
    const float* __restrict__ codebook,
    const float* __restrict__ cbn,
    float4* __restrict__ part)
{
    __shared__ float Zt[64 * 68];
    __shared__ float Ct[64 * 68];
    __shared__ float cn[64];

    const int tid = threadIdx.x;
    const int m0 = blockIdx.x * 64;
    const int eh = blockIdx.y;
    const int r = tid >> 4;
    const int c = tid & 15;

#pragma unroll
    for (int it = 0; it < 4; ++it) {
        int idx = tid + it * 256;
        int row = idx >> 4, f = idx & 15;
        float4 v = *(const float4*)(midz + (size_t)(m0 + row) * 64 + f * 4);
        Zt[(f * 4 + 0) * 68 + row] = v.x;
        Zt[(f * 4 + 1) * 68 + row] = v.y;
        Zt[(f * 4 + 2) * 68 + row] = v.z;
        Zt[(f * 4 + 3) * 68 + row] = v.w;
    }

    float best[4], sec[4];
    int bidx[4];
#pragma unroll
    for (int i = 0; i < 4; ++i) { best[i] = 3.4e38f; sec[i] = 3.4e38f; bidx[i] = 0x7fffffff; }

    for (int ch = 0; ch < 8; ++ch) {
        int e0 = eh * 512 + ch * 64;
        __syncthreads();
#pragma unroll
        for (int it = 0; it < 4; ++it) {
            int idx = tid + it * 256;
            int e = idx >> 4, f = idx & 15;
            float4 v = *(const float4*)(codebook + (size_t)(e0 + e) * 64 + f * 4);
            Ct[(f * 4 + 0) * 68 + e] = v.x;
            Ct[(f * 4 + 1) * 68 + e] = v.y;
            Ct[(f * 4 + 2) * 68 + e] = v.z;
            Ct[(f * 4 + 3) * 68 + e] = v.w;
        }
        if (tid < 64) cn[tid] = cbn[e0 + tid];
        __syncthreads();

        float acc[4][4];
#pragma unroll
        for (int i = 0; i < 4; ++i)
#pragma unroll
            for (int j = 0; j < 4; ++j) acc[i][j] = 0.f;

#pragma unroll 8
        for (int kk = 0; kk < 64; ++kk) {
            float4 a = *(const float4*)&Zt[kk * 68 + r * 4];
            float4 b = *(const float4*)&Ct[kk * 68 + c * 4];
            acc[0][0] = fmaf(a.x, b.x, acc[0][0]);
            acc[0][1] = fmaf(a.x, b.y, acc[0][1]);
            acc[0][2] = fmaf(a.x, b.z, acc[0][2]);
            acc[0][3] = fmaf(a.x, b.w, acc[0][3]);
            acc[1][0] = fmaf(a.y, b.x, acc[1][0]);
            acc[1][1] = fmaf(a.y, b.y, acc[1][1]);
            acc[1][2] = fmaf(a.y, b.z, acc[1][2]);
            acc[1][3] = fmaf(a.y, b.w, acc[1][3]);
            acc[2][0] = fmaf(a.z, b.x, acc[2][0]);
            acc[2][1] = fmaf(a.z, b.y, acc[2][1]);
            acc[2][2] = fmaf(a.z, b.z, acc[2][2]);
            acc[2][3] = fmaf(a.z, b.w, acc[2][3]);
            acc[3][0] = fmaf(a.w, b.x, acc[3][0]);
            acc[3][1] = fmaf(a.w, b.y, acc[3][1]);
            acc[3][2] = fmaf(a.w, b.z, acc[3][2]);
            acc[3][3] = fmaf(a.w, b.w, acc[3][3]);
        }
#pragma unroll
        for (int i = 0; i < 4; ++i)
#pragma unroll
            for (int j = 0; j < 4; ++j) {
                int e = c * 4 + j;
                float s = cn[e] - 2.0f * acc[i][j];
                int gi = e0 + e;
                if (s < best[i] || (s == best[i] && gi < bidx[i])) {
                    sec[i] = best[i];
                    best[i] = s;
                    bidx[i] = gi;
                } else {
                    sec[i] = fminf(sec[i], s);
                }
            }
    }

#pragma unroll
    for (int i = 0; i < 4; ++i) {
#pragma unroll
        for (int m = 1; m < 16; m <<= 1) {
            float ob = __shfl_xor(best[i], m, 64);
            int oi = __shfl_xor(bidx[i], m, 64);
            float os = __shfl_xor(sec[i], m, 64);
            if (ob < best[i] || (ob == best[i] && oi < bidx[i])) {
                sec[i] = fminf(best[i], os);
                best[i] = ob;
                bidx[i] = oi;
            } else {
                sec[i] = fminf(sec[i], ob);
            }
        }
    }
    if (c == 0) {
#pragma unroll
        for (int i = 0; i < 4; ++i) {
            float4 p;
            p.x = best[i];
            p.y = sec[i];
            p.z = __int_as_float(bidx[i]);
            p.w = 0.f;
            part[(size_t)(m0 + r * 4 + i) * 2 + eh] = p;
        }
    }
}

// ---------------------------------------------------------------------------
// VQ merge + flag + latent head + state half of xz.  128 rows/block, grid mt.
// ---------------------------------------------------------------------------
__global__ __launch_bounds__(256) void vq_merge(
    const float4* __restrict__ part,
    const float* __restrict__ state_c,
    const float* __restrict__ codebook,
    const float* __restrict__ mean_w, const float* __restrict__ mean_b,
    const float* __restrict__ logstd_w, const float* __restrict__ logstd_b,
    const float* __restrict__ eps,
    float* __restrict__ mean_out, float* __restrict__ std_out,
    unsigned short* __restrict__ xz,
    int* __restrict__ ctr, int* __restrict__ list, int rowbase)
{
    __shared__ float mw[4160];
    __shared__ float lw[4160];
    __shared__ int sidx[128];

    const int tid = threadIdx.x;
    const int m0 = blockIdx.x * 128;

    if (tid < 128) {
        size_t row = (size_t)(m0 + tid);
        float4 p0 = part[row * 2 + 0];
        float4 p1 = part[row * 2 + 1];
        int i0 = __float_as_int(p0.z), i1 = __float_as_int(p1.z);
        float b, s;
        int ix;
        if (p0.x < p1.x || (p0.x == p1.x && i0 < i1)) {
            b = p0.x; ix = i0; s = fminf(p0.y, p1.x);
        } else {
            b = p1.x; ix = i1; s = fminf(p1.y, p0.x);
        }
        sidx[tid] = ix;
        if (s - b < TAU) {
            int p = atomicAdd(ctr, 1);
            list[p] = rowbase + m0 + tid;
        }
    }
#pragma unroll
    for (int it = 0; it < 4; ++it) {
        int idx = tid + it * 256;
        int k = idx >> 4, f = idx & 15;
        float4 v = *(const float4*)(mean_w + (size_t)k * 64 + f * 4);
        mw[k * 65 + f * 4 + 0] = v.x;
        mw[k * 65 + f * 4 + 1] = v.y;
        mw[k * 65 + f * 4 + 2] = v.z;
        mw[k * 65 + f * 4 + 3] = v.w;
        float4 w2 = *(const float4*)(logstd_w + (size_t)k * 64 + f * 4);
        lw[k * 65 + f * 4 + 0] = w2.x;
        lw[k * 65 + f * 4 + 1] = w2.y;
        lw[k * 65 + f * 4 + 2] = w2.z;
        lw[k * 65 + f * 4 + 3] = w2.w;
    }

    {
        int row = tid >> 1;
        int d0 = (tid & 1) * 32;
        size_t so = (size_t)(m0 + row) * 64 + d0;
        size_t xo = (size_t)(m0 + row) * 128 + d0;
#pragma unroll
        for (int q = 0; q < 8; ++q) {
            f32x4 v = *(const f32x4*)&state_c[so + q * 4];
            unsigned short o[4];
            o[0] = f2bf(v[0]); o[1] = f2bf(v[1]);
            o[2] = f2bf(v[2]); o[3] = f2bf(v[3]);
            *(uint2*)&xz[xo + q * 4] = *(uint2*)o;
        }
    }
    __syncthreads();

    {
        int row = tid >> 1;
        int d0 = (tid & 1) * 32;
        int e = sidx[row];
        const float* cb = codebook + (size_t)e * 64;
        float mv[32], lv[32];
#pragma unroll
        for (int d = 0; d < 32; ++d) {
            mv[d] = mean_b[d0 + d];
            lv[d] = logstd_b[d0 + d];
        }
        for (int k = 0; k < 64; ++k) {
            float zk = cb[k];
#pragma unroll
            for (int d = 0; d < 32; ++d) {
                mv[d] = fmaf(zk, mw[k * 65 + d0 + d], mv[d]);
                lv[d] = fmaf(zk, lw[k * 65 + d0 + d], lv[d]);
            }
        }
        size_t ro = (size_t)(m0 + row) * 64 + d0;
        size_t xo = (size_t)(m0 + row) * 128 + 64 + d0;
#pragma unroll
        for (int d = 0; d < 32; ++d) {
            float mean = mv[d];
            float ls = fminf(fmaxf(lv[d], -4.f), 15.f);
            float sd = expf(ls);
            float z = fmaf(sd, eps[ro + d], mean);
            mean_out[ro + d] = mean;
            std_out[ro + d] = sd;
            xz[xo + d] = f2bf(z);
        }
    }
}

// ---------------------------------------------------------------------------
__global__ void gather_fix(const int* __restrict__ ctr, int* __restrict__ meta,
                           const int* __restrict__ list,
                           const float* __restrict__ state,
                           const float* __restrict__ action,
                           float* __restrict__ sa_fix)
{
    int cnt = *ctr; if (cnt > FMAX) cnt = FMAX;
    if (blockIdx.x == 0 && threadIdx.x == 0)
        meta[0] = (cnt + 31) & ~31;
    int t = blockIdx.x * 256 + threadIdx.x;
    if (t >= cnt * 24) return;
    int f = t / 24, q = t % 24;
    size_t g = (size_t)list[f];
    f32x4 v = (q < 16) ? *(const f32x4*)&state[g * 64 + q * 4]
                       : *(const f32x4*)&action[g * 32 + (q - 16) * 4];
    *(f32x4*)&sa_fix[(size_t)f * 96 + q * 4] = v;
}

// ---------------------------------------------------------------------------
__global__ __launch_bounds__(256) void vq_fix(
    const int* __restrict__ ctr, const int* __restrict__ list,
    const float* __restrict__ mz_fix,
    const float* __restrict__ codebook, const float* __restrict__ cbn,
    const float* __restrict__ mean_w, const float* __restrict__ mean_b,
    const float* __restrict__ logstd_w, const float* __restrict__ logstd_b,
    const float* __restrict__ eps,
    float* __restrict__ mean_out, float* __restrict__ std_out,
    unsigned short* __restrict__ xz)
{
    __shared__ float mzs[8][64];
    __shared__ float zns[8];
    __shared__ float sv[2048];
    __shared__ int si[2048];
    __shared__ int am_s[8];

    int cnt = *ctr; if (cnt > FMAX) cnt = FMAX;
    const int base = blockIdx.x * 8;
    if (base >= cnt) return;
    const int nr = min(8, cnt - base);
    const int tid = threadIdx.x;

    if (tid < 128) {
        int rr = tid >> 4, q = tid & 15;
        int src = base + ((rr < nr) ? rr : 0);
        *(f32x4*)&mzs[rr][q * 4] = *(const f32x4*)&mz_fix[(size_t)src * 64 + q * 4];
    }
    __syncthreads();
    if (tid < 8) {
        float s = 0.f;
#pragma unroll
        for (int k = 0; k < 64; ++k) s = fmaf(mzs[tid][k], mzs[tid][k], s);
        zns[tid] = s;
    }
    __syncthreads();

    float bb[8];
    int bi[8];
#pragma unroll
    for (int rr = 0; rr < 8; ++rr) { bb[rr] = 3.4e38f; bi[rr] = 0x7fffffff; }
    for (int j = 0; j < 4; ++j) {
        int code = tid + j * 256;
        const f32x4* cp = (const f32x4*)(codebook + (size_t)code * 64);
        float dot[8];
#pragma unroll
        for (int rr = 0; rr < 8; ++rr) dot[rr] = 0.f;
        for (int t = 0; t < 16; ++t) {
            f32x4 cv = cp[t];
#pragma unroll
            for (int e = 0; e < 4; ++e) {
                float cvv = cv[e];
#pragma unroll
                for (int rr = 0; rr < 8; ++rr)
                    dot[rr] = fmaf(mzs[rr][t * 4 + e], cvv, dot[rr]);
            }
        }
        float cnv = cbn[code];
#pragma unroll
        for (int rr = 0; rr < 8; ++rr) {
            float s = (zns[rr] + cnv) - 2.0f * dot[rr];
            if (s < bb[rr] || (s == bb[rr] && code < bi[rr])) {
                bb[rr] = s; bi[rr] = code;
            }
        }
    }
#pragma unroll
    for (int rr = 0; rr < 8; ++rr) {
        sv[rr * 256 + tid] = bb[rr];
        si[rr * 256 + tid] = bi[rr];
    }
    __syncthreads();
    if (tid < 8) {
        float b = 3.4e38f;
        int ix = 0x7fffffff;
        for (int t = 0; t < 256; ++t) {
            float v = sv[tid * 256 + t];
            int iv = si[tid * 256 + t];
            if (v < b || (v == b && iv < ix)) { b = v; ix = iv; }
        }
        am_s[tid] = ix;
    }
    __syncthreads();

    for (int jo = 0; jo < 2; ++jo) {
        int o = tid + jo * 256;
        int rr = o >> 6, d = o & 63;
        if (rr < nr) {
            int e = am_s[rr];
            size_t g = (size_t)list[base + rr];
            float mv = mean_b[d], lv = logstd_b[d];
            const float* cb = codebook + (size_t)e * 64;
            for (int k = 0; k < 64; ++k) {
                float zk = cb[k];
                mv = fmaf(zk, mean_w[(size_t)k * 64 + d], mv);
                lv = fmaf(zk, logstd_w[(size_t)k * 64 + d], lv);
            }
            float ls = fminf(fmaxf(lv, -4.f), 15.f);
            float sd = expf(ls);
            float z = fmaf(sd, eps[g * 64 + d], mv);
            mean_out[g * 64 + d] = mv;
            std_out[g * 64 + d] = sd;
            xz[g * 128 + 64 + d] = f2bf(z);
        }
    }
}

// ---------------------------------------------------------------------------
extern "C" void kernel_launch(void* const* d_in, const int* in_sizes, int n_in,
                              void* d_out, int out_size, void* d_ws, size_t ws_size,
                              hipStream_t stream)
{
    const float* state    = (const float*)d_in[0];
    const float* action   = (const float*)d_in[1];
    const float* eps      = (const float*)d_in[2];
    const float* enc_w1   = (const float*)d_in[3];
    const float* enc_b1   = (const float*)d_in[4];
    const float* enc_w2   = (const float*)d_in[5];
    const float* enc_b2   = (const float*)d_in[6];
    const float* enc_w3   = (const float*)d_in[7];
    const float* enc_b3   = (const float*)d_in[8];
    const float* mean_w   = (const float*)d_in[9];
    const float* mean_b   = (const float*)d_in[10];
    const float* logstd_w = (const float*)d_in[11];
    const float* logstd_b = (const float*)d_in[12];
    const float* codebook = (const float*)d_in[13];
    const float* dec_w1   = (const float*)d_in[14];
    const float* dec_b1   = (const float*)d_in[15];
    const float* dec_w2   = (const float*)d_in[16];
    const float* dec_b2   = (const float*)d_in[17];
    const float* dec_w3   = (const float*)d_in[18];
    const float* dec_b3   = (const float*)d_in[19];

    float* out = (float*)d_out;
    float* u_out = out;
    float* mean_out = out + (size_t)B_TOTAL * 32;
    float* std_out = mean_out + (size_t)B_TOTAL * 64;

    // ---- fixed ws region (~9.6 MB; fix buffers alias the dyn area) ----
    char* base = (char*)d_ws;
    float* cbn = (float*)base;                                   // 4096
    unsigned short* W1h = (unsigned short*)(base + 4096);        // fp16
    unsigned short* W2h = (unsigned short*)(base + 397312);      // fp16 (256-layout)
    unsigned short* W3h = (unsigned short*)(base + 4591616);     // fp16
    unsigned short* W4h = (unsigned short*)(base + 4853760);     // bf16
    unsigned short* W5h = (unsigned short*)(base + 5115904);     // bf16 (256-layout)
    unsigned short* W6h = (unsigned short*)(base + 7213056);     // bf16
    int* ctr            = (int*)(base + 7278592);                // 256
    int* flag_list      = (int*)(base + 7278848);                // 262144
    int* meta           = (int*)(base + 7540992);                // 256
    float4* part        = (float4*)(base + 7541248);             // 2097152
    const size_t FIXED  = 9638400;

    unsigned short* xz_g = (unsigned short*)(base + FIXED);      // 16 MB
    const size_t XZ_SZ = (size_t)B_TOTAL * 128 * 2;

    // dyn region: saH 192 + h1H 2048 + h2H 2048 + mz 256 = 4544 B per row
    const size_t per_row = 4544;
    size_t avail = (ws_size > FIXED + XZ_SZ) ? (ws_size - FIXED - XZ_SZ) : 0;
    long maxC = (long)(avail / per_row);
    int C = (int)(maxC / 1024) * 1024;
    if (C > B_TOTAL) C = B_TOTAL;
    if (C < 12288) C = 12288;   // >= fix-alias region (54.26 MB)

    char* dyn = base + FIXED + XZ_SZ;
    unsigned short* saH = (unsigned short*)dyn;                   // [C,96] fp16
    unsigned short* h1H = saH + (size_t)C * 96;                   // [C,1024] fp16
    unsigned short* h2H = h1H + (size_t)C * 1024;                 // [C,1024] fp16
    float* mz = (float*)(h2H + (size_t)C * 1024);                 // [C,64]
    unsigned short* hc = h1H;   // decoder reuse (bf16)
    unsigned short* hd = h2H;

    float* sa_fix = (float*)dyn;                                  // 2359296
    float* h1_fix = (float*)(dyn + 2359296);                      // 25165824
    float* h2_fix = (float*)(dyn + 27525120);                     // 25165824
    float* mz_fix = (float*)(dyn + 52690944);                     // 1572864

    // dynamic-LDS attrs; fall back to proven kernels if denied
    bool deep = hipFuncSetAttribute(
        reinterpret_cast<const void*>(&mfma_gemm128<4, 3, 4, 0>),
        hipFuncAttributeMaxDynamicSharedMemorySize, 49152) == hipSuccess;
    deep = deep && hipFuncSetAttribute(
        reinterpret_cast<const void*>(&mfma_gemm128<1, 4, 1, 0>),
        hipFuncAttributeMaxDynamicSharedMemorySize, 65536) == hipSuccess;
    bool d256 = hipFuncSetAttribute(
        reinterpret_cast<const void*>(&mfma_gemm256<1, 0>),
        hipFuncAttributeMaxDynamicSharedMemorySize, 131072) == hipSuccess;
    d256 = d256 && hipFuncSetAttribute(
        reinterpret_cast<const void*>(&mfma_gemm256<0, 0>),
        hipFuncAttributeMaxDynamicSharedMemorySize, 131072) == hipSuccess;
    d256 = d256 && deep;

    // ---- once per call ----
    cb_norms<<<dim3(4), dim3(256), 0, stream>>>(codebook, cbn);
    zero_ctr<<<dim3(1), dim3(64), 0, stream>>>(ctr);
    w_xform<2, 128><<<dim3(3, 8), dim3(256), 0, stream>>>(enc_w1, 96, 1024, W1h, nullptr);
    if (d256) wx256<1><<<dim3(16, 8), dim3(256), 0, stream>>>(enc_w2, 1024, W2h);
    else w_xform<2, 128><<<dim3(32, 8), dim3(256), 0, stream>>>(enc_w2, 1024, 1024, W2h, nullptr);
    w_xform<2, 64><<<dim3(32, 1), dim3(256), 0, stream>>>(enc_w3, 1024, 64, W3h, nullptr);
    w_xform<1, 128><<<dim3(4, 8), dim3(256), 0, stream>>>(dec_w1, 128, 1024, W4h, nullptr);
    if (d256) wx256<0><<<dim3(16, 8), dim3(256), 0, stream>>>(dec_w2, 1024, W5h);
    else w_xform<1, 128><<<dim3(32, 8), dim3(256), 0, stream>>>(dec_w2, 1024, 1024, W5h, nullptr);
    w_xform<1, 32><<<dim3(32, 1), dim3(256), 0, stream>>>(dec_w3, 1024, 32, W6h, nullptr);

    // ---- phase A: encoder + VQ ----
    for (int r0 = 0; r0 < B_TOTAL; r0 += C) {
        int M = (r0 + C <= B_TOTAL) ? C : (B_TOTAL - r0);
        int mt = M / 128;

        sa_pre<<<dim3(M * 12 / 256), dim3(256), 0, stream>>>(
            state + (size_t)r0 * SDIM, action + (size_t)r0 * ADIM, saH);

        if (deep)
            mfma_gemm128<4, 3, 4, 0><<<dim3(mt * 8), dim3(256), 49152, stream>>>(
                saH, 96, W1h, enc_b1, h1H, 1024);
        else
            mfma_gemm128<4, 3, 4, 0><<<dim3(mt * 8), dim3(256), 49152, stream>>>(
                saH, 96, W1h, enc_b1, h1H, 1024);
        if (d256)
            mfma_gemm256<1, 0><<<dim3((M / 256) * 4), dim3(512), 131072, stream>>>(
                h1H, 1024, W2h, enc_b2, h2H, 1024);
        else
            mfma_gemm128<4, 3, 4, 0><<<dim3(mt * 8), dim3(256), 49152, stream>>>(
                h1H, 1024, W2h, enc_b2, h2H, 1024);
        mfma_gemm64<4, 64, 0><<<dim3(M / 64), dim3(256), 0, stream>>>(
            h2H, 1024, W3h, enc_b3, mz, 64);

        vq_score<<<dim3(M / 64, 2), dim3(256), 0, stream>>>(
            mz, codebook, cbn, part + (size_t)r0 * 2);
        vq_merge<<<dim3(mt), dim3(256), 0, stream>>>(
            part + (size_t)r0 * 2, state + (size_t)r0 * SDIM, codebook,
            mean_w, mean_b, logstd_w, logstd_b,
            eps + (size_t)r0 * LDIM,
            mean_out + (size_t)r0 * LDIM, std_out + (size_t)r0 * LDIM,
            xz_g + (size_t)r0 * 128, ctr, flag_list, r0);
    }

    // ---- phase B: exact-fp32 fixup ----
    gather_fix<<<dim3(FMAX * 24 / 256), dim3(256), 0, stream>>>(
        ctr, meta, flag_list, state, action, sa_fix);
    gemm_fix<128, 0><<<dim3(FMAX / 32, 8), dim3(256), 0, stream>>>(
        meta, sa_fix, 96, enc_w1, enc_b1, h1_fix, 1024);
    gemm_fix<128, 0><<<dim3(FMAX / 32, 8), dim3(256), 0, stream>>>(
        meta, h1_fix, 1024, enc_w2, enc_b2, h2_fix, 1024);
    gemm_fix<64, 0><<<dim3(FMAX / 32, 1), dim3(256), 0, stream>>>(
        meta, h2_fix, 1024, enc_w3, enc_b3, mz_fix, 64);
    vq_fix<<<dim3(FMAX / 8), dim3(256), 0, stream>>>(
        ctr, flag_list, mz_fix, codebook, cbn,
        mean_w, mean_b, logstd_w, logstd_b, eps,
        mean_out, std_out, xz_g);

    // ---- phase C: decoder ----
    for (int r0 = 0; r0 < B_TOTAL; r0 += C) {
        int M = (r0 + C <= B_TOTAL) ? C : (B_TOTAL - r0);
        int mt = M / 128;

        mfma_gemm128<1, 4, 1, 0><<<dim3(mt * 8), dim3(256), 65536, stream>>>(
            xz_g + (size_t)r0 * 128, 128, W4h, dec_b1, hc, 1024);
        if (d256)
            mfma_gemm256<0, 0><<<dim3((M / 256) * 4), dim3(512), 131072, stream>>>(
                hc, 1024, W5h, dec_b2, hd, 1024);
        else
            mfma_gemm128<1, 4, 1, 0><<<dim3(mt * 8), dim3(256), 65536, stream>>>(
                hc, 1024, W5h, dec_b2, hd, 1024);
        mfma_gemm64<1, 32, 1><<<dim3(M / 64), dim3(256), 0, stream>>>(
            hd, 1024, W6h, dec_b3, u_out + (size_t)r0 * ADIM, 32);
    }
}

// Round 18
// 1076.682 us; speedup vs baseline: 1.4086x; 1.0880x over previous
//
#include <hip/hip_runtime.h>
#include <cstdint>
#include <cstddef>

#define B_TOTAL 65536
#define SDIM 64
#define ADIM 32
#define LDIM 64
#define HDIM 1024
#define NEMB 1024
#define TAU 0.125f
#define FMAX 6144

typedef __attribute__((ext_vector_type(8))) short short8;
typedef __attribute__((ext_vector_type(8))) _Float16 half8;
typedef __attribute__((ext_vector_type(4))) float f32x4;

__device__ inline unsigned short f2bf(float f) {
    unsigned int u = __float_as_uint(f);
    u += 0x7fffu + ((u >> 16) & 1u);
    return (unsigned short)(u >> 16);
}
__device__ inline float bf2f(unsigned short s) {
    return __uint_as_float(((unsigned int)s) << 16);
}
__device__ inline unsigned short f2h(float f) {
    _Float16 h = (_Float16)f;
    return __builtin_bit_cast(unsigned short, h);
}
__device__ inline float h2f(unsigned short s) {
    return (float)__builtin_bit_cast(_Float16, s);
}
__device__ inline half8 H8(short8 v) { return __builtin_bit_cast(half8, v); }

// async global->LDS, 16B per lane; LDS dest = wave-uniform base + lane*16.
__device__ inline void gload16(const unsigned short* g, unsigned short* l) {
    __builtin_amdgcn_global_load_lds(
        (__attribute__((address_space(1))) void*)(g),
        (__attribute__((address_space(3))) void*)(l), 16, 0, 0);
}

// exact counted vmcnt (wt always lands on an enumerated value)
__device__ inline void vm_wait(int wt) {
    if (wt >= 12)      asm volatile("s_waitcnt vmcnt(12)" ::: "memory");
    else if (wt >= 8)  asm volatile("s_waitcnt vmcnt(8)" ::: "memory");
    else if (wt >= 6)  asm volatile("s_waitcnt vmcnt(6)" ::: "memory");
    else if (wt >= 4)  asm volatile("s_waitcnt vmcnt(4)" ::: "memory");
    else               asm volatile("s_waitcnt vmcnt(0)" ::: "memory");
}

// ---------------------------------------------------------------------------
// codebook norms + fp16 plane (row-major [1024][64])
// ---------------------------------------------------------------------------
__global__ void cb_norms(const float* __restrict__ codebook, float* __restrict__ cbn,
                         unsigned short* __restrict__ cbH)
{
    int i = blockIdx.x * 256 + threadIdx.x;
    if (i < NEMB) {
        float s = 0.f;
#pragma unroll
        for (int k = 0; k < LDIM; ++k) {
            float v = codebook[(size_t)i * LDIM + k];
            s = fmaf(v, v, s);
            cbH[(size_t)i * LDIM + k] = f2h(v);
        }
        cbn[i] = s;
    }
}

__global__ void zero_ctr(int* ctr) { if (threadIdx.x == 0) *ctr = 0; }

// ---------------------------------------------------------------------------
// Weight pre-transform (old 32-k-block layout): NT==1 bf16, NT==2 fp16.
// ---------------------------------------------------------------------------
template <int NT, int BN>
__global__ __launch_bounds__(256) void w_xform(
    const float* __restrict__ W, int K, int N,
    unsigned short* __restrict__ Ph, unsigned short* __restrict__ Pl)
{
    __shared__ float Ws[32][BN + 4];
    const int tid = threadIdx.x;
    const int ks = blockIdx.x, nb = blockIdx.y;
    const int k0 = ks * 32, n0 = nb * BN;
    constexpr int LT = 32 * (BN / 4);
#pragma unroll
    for (int it = 0; it < (LT + 255) / 256; ++it) {
        int idx = tid + it * 256;
        if (LT % 256 == 0 || idx < LT) {
            int k = idx / (BN / 4);
            int nf = idx % (BN / 4);
            *(f32x4*)&Ws[k][nf * 4] =
                *(const f32x4*)&W[(size_t)(k0 + k) * N + n0 + nf * 4];
        }
    }
    __syncthreads();
    const int KS = K >> 5;
    size_t bo = ((size_t)nb * KS + ks) * (BN * 32);
    constexpr int WT = BN * 4;
#pragma unroll
    for (int it = 0; it < (WT + 255) / 256; ++it) {
        int idx = tid + it * 256;
        if (WT % 256 == 0 || idx < WT) {
            int kb = idx / BN;
            int n = idx % BN;
            short8 h;
#pragma unroll
            for (int j = 0; j < 8; ++j) {
                float x = Ws[kb * 8 + j][n];
                h[j] = (NT == 2) ? (short)f2h(x) : (short)f2bf(x);
            }
            *(short8*)&Ph[bo + (size_t)idx * 8] = h;
        }
    }
}

// ---------------------------------------------------------------------------
// 256-tile pre-transform for the 8-phase kernel (N=1024 fixed).
// ---------------------------------------------------------------------------
template <int FP16>
__global__ __launch_bounds__(256) void wx256(
    const float* __restrict__ W, int K, unsigned short* __restrict__ P)
{
    __shared__ float Ws[64][132];
    const int tid = threadIdx.x;
    const int kt = blockIdx.x;
    const int nb = blockIdx.y >> 1, hb = blockIdx.y & 1;
    const int n0 = nb * 256 + hb * 128;
    const int KT = K >> 6;
#pragma unroll
    for (int it = 0; it < 8; ++it) {
        int idx = tid + it * 256;
        int k = idx >> 5, nf = idx & 31;
        *(f32x4*)&Ws[k][nf * 4] =
            *(const f32x4*)&W[(size_t)(kt * 64 + k) * 1024 + n0 + nf * 4];
    }
    __syncthreads();
    size_t bo = (((size_t)nb * KT + kt) * 2 + hb) * 8192;
#pragma unroll
    for (int it = 0; it < 4; ++it) {
        int t = tid + it * 256;
        int kb = t >> 7, col = t & 127;
        short8 h;
#pragma unroll
        for (int j = 0; j < 8; ++j) {
            float x = Ws[kb * 8 + j][col];
            h[j] = FP16 ? (short)f2h(x) : (short)f2bf(x);
        }
        *(short8*)&P[bo + (size_t)t * 8] = h;
    }
}

// ---------------------------------------------------------------------------
// 256x256 8-phase MFMA GEMM (K=1024 layers), proven round 17.
// ---------------------------------------------------------------------------
template <int FP16, int ACT>
__global__ __launch_bounds__(512, 1) void mfma_gemm256(
    const unsigned short* __restrict__ Ag, int K,
    const unsigned short* __restrict__ Wg,
    const float* __restrict__ bias,
    unsigned short* __restrict__ out0, int NTOT)
{
    extern __shared__ unsigned short smem[];
    const int tid = threadIdx.x;
    const int w = tid >> 6, lane = tid & 63;
    const int g = lane >> 4, lr = lane & 15;
    int per = gridDim.x >> 3;
    int xcd = blockIdx.x & 7;
    int lid = blockIdx.x >> 3;
    int tile = xcd * per + lid;
    const int m0 = (tile >> 2) * 256;
    const int nb = tile & 3;
    const int n0 = nb * 256;
    const int wrow0 = (w >> 2) * 128;
    const int wcol0 = (w & 3) * 64;
    const int hA = wrow0 >> 7;
    const int hB = wcol0 >> 7;
    const int cB0 = (wcol0 & 127);
    const int KT = K >> 6;
    const int T = KT >> 1;

    auto stageAh = [&](int kt, int h) {
        unsigned short* dst = smem + (((kt & 1) * 2 + h) * 8192);
#pragma unroll
        for (int it = 0; it < 2; ++it) {
            int t0 = it * 512 + (w << 6);
            int tt = t0 + lane;
            int kb = tt >> 7, row = tt & 127;
            size_t go = (size_t)(m0 + h * 128 + row) * K + (size_t)kt * 64 + kb * 8;
            gload16(Ag + go, dst + (size_t)t0 * 8);
        }
    };
    auto stageBh = [&](int kt, int h) {
        unsigned short* dst = smem + 32768 + (((kt & 1) * 2 + h) * 8192);
        size_t bo = (((size_t)nb * KT + kt) * 2 + h) * 8192;
#pragma unroll
        for (int it = 0; it < 2; ++it) {
            int t0 = it * 512 + (w << 6);
            gload16(Wg + bo + (size_t)(t0 + lane) * 8, dst + (size_t)t0 * 8);
        }
    };

    float bv[4];
#pragma unroll
    for (int n = 0; n < 4; ++n) bv[n] = bias[n0 + wcol0 + n * 16 + lr];
    asm volatile("s_waitcnt vmcnt(0)" ::: "memory");
    __builtin_amdgcn_sched_barrier(0);

    f32x4 acc[8][4];
#pragma unroll
    for (int m = 0; m < 8; ++m)
#pragma unroll
        for (int n = 0; n < 4; ++n) {
            acc[m][n][0] = 0.f; acc[m][n][1] = 0.f;
            acc[m][n][2] = 0.f; acc[m][n][3] = 0.f;
        }

    short8 bf[4][2];

#define CPH(ktc, MP, LB) do {                                                   \
        unsigned short* Ab = smem + ((((ktc) & 1) * 2 + hA) * 8192);            \
        unsigned short* Bb = smem + 32768 + ((((ktc) & 1) * 2 + hB) * 8192);    \
        if (LB) {                                                               \
            _Pragma("unroll") for (int n = 0; n < 4; ++n)                       \
            _Pragma("unroll") for (int s = 0; s < 2; ++s)                       \
                bf[n][s] = *(const short8*)&Bb[((s * 4 + g) * 128 + cB0 + n * 16 + lr) * 8]; \
        }                                                                       \
        short8 af[2][2];                                                        \
        _Pragma("unroll") for (int mm = 0; mm < 2; ++mm)                        \
        _Pragma("unroll") for (int s = 0; s < 2; ++s)                           \
            af[mm][s] = *(const short8*)&Ab[((s * 4 + g) * 128 + ((MP) * 2 + mm) * 16 + lr) * 8]; \
        asm volatile("s_waitcnt lgkmcnt(0)" ::: "memory");                      \
        __builtin_amdgcn_sched_barrier(0);                                      \
        __builtin_amdgcn_s_setprio(1);                                          \
        _Pragma("unroll") for (int mm = 0; mm < 2; ++mm)                        \
        _Pragma("unroll") for (int n = 0; n < 4; ++n)                           \
        _Pragma("unroll") for (int s = 0; s < 2; ++s) {                         \
            if (FP16) acc[(MP) * 2 + mm][n] = __builtin_amdgcn_mfma_f32_16x16x32_f16( \
                H8(af[mm][s]), H8(bf[n][s]), acc[(MP) * 2 + mm][n], 0, 0, 0);   \
            else acc[(MP) * 2 + mm][n] = __builtin_amdgcn_mfma_f32_16x16x32_bf16( \
                af[mm][s], bf[n][s], acc[(MP) * 2 + mm][n], 0, 0, 0);           \
        }                                                                       \
        __builtin_amdgcn_s_setprio(0);                                          \
    } while (0)

    stageAh(0, 0); stageBh(0, 0); stageBh(0, 1); stageAh(0, 1);
    stageAh(1, 0); stageBh(1, 0); stageBh(1, 1); stageAh(1, 1);

    for (int t = 0; t < T; ++t) {
        int k0t = 2 * t, k1t = 2 * t + 1;
        if (t > 0) stageAh(k1t, 0);
        asm volatile("s_waitcnt vmcnt(2)" ::: "memory");
        __builtin_amdgcn_s_barrier();
        CPH(k0t, 0, 1);
        if (t > 0) stageBh(k1t, 0);
        CPH(k0t, 1, 0);
        if (t > 0) stageBh(k1t, 1);
        CPH(k0t, 2, 0);
        if (t > 0) stageAh(k1t, 1);
        CPH(k0t, 3, 0);
        __builtin_amdgcn_s_barrier();
        if (k0t + 2 < KT) {
            stageAh(k0t + 2, 0);
            asm volatile("s_waitcnt vmcnt(2)" ::: "memory");
        } else {
            asm volatile("s_waitcnt vmcnt(0)" ::: "memory");
        }
        __builtin_amdgcn_s_barrier();
        CPH(k1t, 0, 1);
        if (k0t + 2 < KT) stageBh(k0t + 2, 0);
        CPH(k1t, 1, 0);
        if (k0t + 2 < KT) stageBh(k0t + 2, 1);
        CPH(k1t, 2, 0);
        if (k0t + 2 < KT) stageAh(k0t + 2, 1);
        CPH(k1t, 3, 0);
        __builtin_amdgcn_s_barrier();
    }
#undef CPH

    unsigned short* Sb = smem;
    __builtin_amdgcn_s_barrier();
#pragma unroll
    for (int m = 0; m < 8; ++m)
#pragma unroll
        for (int n = 0; n < 4; ++n)
#pragma unroll
            for (int q = 0; q < 4; ++q) {
                int rl = wrow0 + m * 16 + g * 4 + q;
                int cl = wcol0 + n * 16 + lr;
                float x = acc[m][n][q] + bv[n];
                if (ACT == 0) x = fmaxf(x, 0.f);
                else x = tanhf(x);
                Sb[rl * 256 + cl] = FP16 ? f2h(x) : f2bf(x);
            }
    __syncthreads();
#pragma unroll
    for (int it = 0; it < 16; ++it) {
        int idx = tid + it * 512;
        int row = idx >> 5, sl = idx & 31;
        *(short8*)&out0[(size_t)(m0 + row) * NTOT + n0 + sl * 8]
            = *(const short8*)&Sb[row * 256 + sl * 8];
    }
}

// ---------------------------------------------------------------------------
// Paired D-deep BN=128 kernel (proven r15/r16) for G1/G4.
// ---------------------------------------------------------------------------
template <int NT, int D, int OUT, int ACT>
__global__ __launch_bounds__(256, 2) void mfma_gemm128(
    const unsigned short* __restrict__ Ah_g, int K,
    const unsigned short* __restrict__ Wh,
    const float* __restrict__ bias,
    void* __restrict__ out0, int NTOT)
{
    constexpr int BN = 128;
    constexpr int WM = 4, WN = 4, NWC = 2;
    constexpr int ASTR = 4096;
    constexpr int BSTR = 4096;
    constexpr int BOFF = D * ASTR;
    constexpr int PAIR = 4;
    extern __shared__ unsigned short smem[];

    const int tid = threadIdx.x;
    int per = gridDim.x >> 3;
    int xcd = blockIdx.x & 7;
    int lid = blockIdx.x >> 3;
    int tile = xcd * per + lid;
    const int m0 = (tile >> 3) * 128;
    const int nb = tile & 7;
    const int n0 = nb * BN;
    const int w = tid >> 6, lane = tid & 63;
    const int g = lane >> 4, lr = lane & 15;
    const int wrow0 = (w / NWC) * (WM * 16);
    const int wcol0 = (w % NWC) * (WN * 16);
    const int KS = K >> 5;

    auto stageA = [&](int i, int ks) {
        unsigned short* Ah = smem + i * ASTR;
#pragma unroll
        for (int it = 0; it < 2; ++it) {
            int t0 = it * 256 + w * 64;
            int t = t0 + lane;
            int row = t & 127, kb = t >> 7;
            size_t go = (size_t)(m0 + row) * K + ks * 32 + kb * 8;
            gload16(Ah_g + go, Ah + (size_t)t0 * 8);
        }
    };
    auto stageB = [&](int j, int ks) {
        unsigned short* Bh = smem + BOFF + j * BSTR;
        size_t bo = ((size_t)nb * KS + ks) * (BN * 32);
#pragma unroll
        for (int it = 0; it < 2; ++it) {
            int t0 = it * 256 + w * 64;
            size_t go = bo + (size_t)(t0 + lane) * 8;
            gload16(Wh + go, Bh + (size_t)t0 * 8);
        }
    };

    float bv[WN];
#pragma unroll
    for (int n = 0; n < WN; ++n) bv[n] = bias[n0 + wcol0 + n * 16 + lr];
    __builtin_amdgcn_sched_barrier(0);

    f32x4 acc[WM][WN];
#pragma unroll
    for (int m = 0; m < WM; ++m)
#pragma unroll
        for (int n = 0; n < WN; ++n) {
            acc[m][n][0] = 0.f; acc[m][n][1] = 0.f;
            acc[m][n][2] = 0.f; acc[m][n][3] = 0.f;
        }

#pragma unroll
    for (int i = 0; i < D - 1; ++i)
        if (i < KS) { stageB(i, i); stageA(i, i); }

    for (int ks = 0; ks < KS; ++ks) {
        __builtin_amdgcn_s_barrier();
        if (ks + D - 1 < KS) {
            stageB((ks + D - 1) % D, ks + D - 1);
            stageA((ks + D - 1) % D, ks + D - 1);
        }
        int futP = KS - 1 - ks; if (futP > D - 1) futP = D - 1;
        vm_wait(futP * PAIR);
        __builtin_amdgcn_s_barrier();
        __builtin_amdgcn_sched_barrier(0);

        unsigned short* Ah = smem + (ks % D) * ASTR;
        unsigned short* Bh = smem + BOFF + (ks % D) * BSTR;

        short8 ah[WM], bh[WN];
#pragma unroll
        for (int m = 0; m < WM; ++m) {
            int ro = (g << 7) + wrow0 + m * 16 + lr;
            ah[m] = *(const short8*)&Ah[ro * 8];
        }
#pragma unroll
        for (int n = 0; n < WN; ++n) {
            int co = g * BN + wcol0 + n * 16 + lr;
            bh[n] = *(const short8*)&Bh[co * 8];
        }
#pragma unroll
        for (int m = 0; m < WM; ++m)
#pragma unroll
            for (int n = 0; n < WN; ++n) {
                if constexpr (NT == 4) {
                    acc[m][n] = __builtin_amdgcn_mfma_f32_16x16x32_f16(
                        H8(ah[m]), H8(bh[n]), acc[m][n], 0, 0, 0);
                } else {
                    acc[m][n] = __builtin_amdgcn_mfma_f32_16x16x32_bf16(
                        ah[m], bh[n], acc[m][n], 0, 0, 0);
                }
            }
    }

    unsigned short* Sb = smem;
    __syncthreads();
#pragma unroll
    for (int m = 0; m < WM; ++m)
#pragma unroll
        for (int n = 0; n < WN; ++n)
#pragma unroll
            for (int q = 0; q < 4; ++q) {
                int rl = wrow0 + m * 16 + g * 4 + q;
                int cl = wcol0 + n * 16 + lr;
                float x = acc[m][n][q] + bv[n];
                if (ACT == 0) x = fmaxf(x, 0.f);
                else x = tanhf(x);
                Sb[rl * BN + cl] = (OUT == 4) ? f2h(x) : f2bf(x);
            }
    __syncthreads();
    constexpr int SL = BN / 8;
    unsigned short* dst = (unsigned short*)out0;
#pragma unroll
    for (int it = 0; it < (128 * SL) / 256; ++it) {
        int idx = tid + it * 256;
        int row = idx / SL, sl = idx % SL;
        *(short8*)&dst[(size_t)(m0 + row) * NTOT + n0 + sl * 8]
            = *(const short8*)&Sb[row * BN + sl * 8];
    }
}

// ---------------------------------------------------------------------------
// BM=64 MFMA GEMM (G3: NT4/BN64 fp16->fp16, G6: NT1/BN32 bf16->fp32).
// OUT: 2 = fp32, 4 = fp16.
// ---------------------------------------------------------------------------
template <int NT, int BN, int OUT, int ACT>
__global__ __launch_bounds__(256) void mfma_gemm64(
    const unsigned short* __restrict__ Ah_g, int K,
    const unsigned short* __restrict__ Wh,
    const float* __restrict__ bias,
    void* __restrict__ out, int NTOT)
{
    constexpr int WM = (BN == 64) ? 2 : 1;
    constexpr int WN = 2;
    constexpr int ABUF = 2048;
    constexpr int BBUF = BN * 32;
    constexpr int BUFSH = ABUF + BBUF;
    __shared__ unsigned short smem[2 * BUFSH];

    const int tid = threadIdx.x;
    const int m0 = blockIdx.x * 64;
    const int w = tid >> 6, lane = tid & 63;
    const int g = lane >> 4, lr = lane & 15;
    const int wrow0 = (BN == 64) ? ((w >> 1) * 32) : (w * 16);
    const int wcol0 = (BN == 64) ? ((w & 1) * 32) : 0;
    const int KS = K >> 5;

    auto stage = [&](unsigned short* buf, int ks) {
        unsigned short* Ah = buf;
        unsigned short* Bh = buf + ABUF;
        {
            int t0 = w * 64;
            int t = t0 + lane;
            int row = t & 63, kb = t >> 6;
            size_t go = (size_t)(m0 + row) * K + ks * 32 + kb * 8;
            gload16(Ah_g + go, Ah + (size_t)t0 * 8);
        }
        size_t bo = (size_t)ks * (BN * 32);
        constexpr int BT = BN * 4;
        if constexpr (BT == 256) {
            int t0 = w * 64;
            size_t go = bo + (size_t)(t0 + lane) * 8;
            gload16(Wh + go, Bh + (size_t)t0 * 8);
        } else {
            if (tid < BT) {
                int t0 = w * 64;
                size_t go = bo + (size_t)(t0 + lane) * 8;
                gload16(Wh + go, Bh + (size_t)t0 * 8);
            }
        }
    };

    f32x4 acc[WM][WN];
#pragma unroll
    for (int m = 0; m < WM; ++m)
#pragma unroll
        for (int n = 0; n < WN; ++n) {
            acc[m][n][0] = 0.f; acc[m][n][1] = 0.f;
            acc[m][n][2] = 0.f; acc[m][n][3] = 0.f;
        }

    stage(smem, 0);

    for (int ks = 0; ks < KS; ++ks) {
        __syncthreads();
        unsigned short* buf = smem + (size_t)(ks & 1) * BUFSH;
        if (ks + 1 < KS)
            stage(smem + (size_t)((ks + 1) & 1) * BUFSH, ks + 1);

        unsigned short* Ah = buf;
        unsigned short* Bh = buf + ABUF;

        short8 ah[WM], bh[WN];
#pragma unroll
        for (int m = 0; m < WM; ++m) {
            int ro = (g << 6) + wrow0 + m * 16 + lr;
            ah[m] = *(const short8*)&Ah[ro * 8];
        }
#pragma unroll
        for (int n = 0; n < WN; ++n) {
            int co = g * BN + wcol0 + n * 16 + lr;
            bh[n] = *(const short8*)&Bh[co * 8];
        }
#pragma unroll
        for (int m = 0; m < WM; ++m)
#pragma unroll
            for (int n = 0; n < WN; ++n) {
                if constexpr (NT == 4) {
                    acc[m][n] = __builtin_amdgcn_mfma_f32_16x16x32_f16(
                        H8(ah[m]), H8(bh[n]), acc[m][n], 0, 0, 0);
                } else {
                    acc[m][n] = __builtin_amdgcn_mfma_f32_16x16x32_bf16(
                        ah[m], bh[n], acc[m][n], 0, 0, 0);
                }
            }
    }

    float bv[WN];
#pragma unroll
    for (int n = 0; n < WN; ++n) bv[n] = bias[wcol0 + n * 16 + lr];

    __syncthreads();
    if constexpr (OUT == 2) {
        float* Sf = (float*)smem;
#pragma unroll
        for (int m = 0; m < WM; ++m)
#pragma unroll
            for (int n = 0; n < WN; ++n)
#pragma unroll
                for (int q = 0; q < 4; ++q) {
                    int rl = wrow0 + m * 16 + g * 4 + q;
                    int cl = wcol0 + n * 16 + lr;
                    float x = acc[m][n][q] + bv[n];
                    if (ACT == 0) x = fmaxf(x, 0.f);
                    else x = tanhf(x);
                    Sf[rl * BN + cl] = x;
                }
        __syncthreads();
        constexpr int SL = BN / 4;
#pragma unroll
        for (int it = 0; it < (64 * SL) / 256; ++it) {
            int idx = tid + it * 256;
            int row = idx / SL, sl = idx % SL;
            *(f32x4*)((float*)out + (size_t)(m0 + row) * NTOT + sl * 4)
                = *(const f32x4*)&Sf[row * BN + sl * 4];
        }
    } else {
        unsigned short* Sb = smem;
#pragma unroll
        for (int m = 0; m < WM; ++m)
#pragma unroll
            for (int n = 0; n < WN; ++n)
#pragma unroll
                for (int q = 0; q < 4; ++q) {
                    int rl = wrow0 + m * 16 + g * 4 + q;
                    int cl = wcol0 + n * 16 + lr;
                    float x = acc[m][n][q] + bv[n];
                    if (ACT == 0) x = fmaxf(x, 0.f);
                    else x = tanhf(x);
                    Sb[rl * BN + cl] = f2h(x);
                }
        __syncthreads();
        constexpr int SL = BN / 8;
        unsigned short* dst = (unsigned short*)out;
#pragma unroll
        for (int it = 0; it < (64 * SL) / 256; ++it) {
            int idx = tid + it * 256;
            int row = idx / SL, sl = idx % SL;
            *(short8*)&dst[(size_t)(m0 + row) * NTOT + sl * 8]
                = *(const short8*)&Sb[row * BN + sl * 8];
        }
    }
}

// ---------------------------------------------------------------------------
// fp32 fixup GEMM, 32-row tiles (proven round 9).
// ---------------------------------------------------------------------------
template <int BN, int ACT>
__global__ __launch_bounds__(256) void gemm_fix(
    const int* __restrict__ mrows,
    const float* __restrict__ A, int K,
    const float* __restrict__ W, const float* __restrict__ bias,
    float* __restrict__ Co, int N)
{
    const int m0 = blockIdx.x * 32;
    if (m0 >= *mrows) return;

    constexpr int TN = BN / 16;
    __shared__ float At[16][36];
    __shared__ float Bt[16][BN + 4];

    const int tid = threadIdx.x;
    const int n0 = blockIdx.y * BN;
    const int r = tid >> 4;
    const int c = tid & 15;

    float acc[2][TN];
#pragma unroll
    for (int i = 0; i < 2; ++i)
#pragma unroll
        for (int j = 0; j < TN; ++j) acc[i][j] = 0.f;

    for (int k0 = 0; k0 < K; k0 += 16) {
        if (tid < 128) {
            int row = tid >> 2;
            int lf = tid & 3;
            float4 v = *(const float4*)(A + (size_t)(m0 + row) * K + k0 + lf * 4);
            At[lf * 4 + 0][row] = v.x;
            At[lf * 4 + 1][row] = v.y;
            At[lf * 4 + 2][row] = v.z;
            At[lf * 4 + 3][row] = v.w;
        }
        constexpr int NF4 = BN / 4;
        constexpr int NEL = 16 * NF4;
#pragma unroll
        for (int it = 0; it < NEL / 256; ++it) {
            int idx = tid + it * 256;
            int kk = idx / NF4;
            int f = idx % NF4;
            float4 v = *(const float4*)(W + (size_t)(k0 + kk) * N + n0 + f * 4);
            *(float4*)&Bt[kk][f * 4] = v;
        }
        __syncthreads();

#pragma unroll
        for (int kk = 0; kk < 16; ++kk) {
            float a0 = At[kk][r * 2];
            float a1 = At[kk][r * 2 + 1];
            float b[TN];
            if constexpr (BN == 128) {
                float4 b0 = *(const float4*)&Bt[kk][c * 4];
                float4 b1 = *(const float4*)&Bt[kk][64 + c * 4];
                b[0] = b0.x; b[1] = b0.y; b[2] = b0.z; b[3] = b0.w;
                b[4] = b1.x; b[5] = b1.y; b[6] = b1.z; b[7] = b1.w;
            } else {
                float4 b0 = *(const float4*)&Bt[kk][c * 4];
                b[0] = b0.x; b[1] = b0.y; b[2] = b0.z; b[3] = b0.w;
            }
#pragma unroll
            for (int j = 0; j < TN; ++j) {
                acc[0][j] = fmaf(a0, b[j], acc[0][j]);
                acc[1][j] = fmaf(a1, b[j], acc[1][j]);
            }
        }
        __syncthreads();
    }

#pragma unroll
    for (int i = 0; i < 2; ++i) {
        size_t row = (size_t)(m0 + r * 2 + i);
        if constexpr (BN == 128) {
            float e[8];
#pragma unroll
            for (int j = 0; j < 8; ++j) {
                int col = (j < 4) ? (c * 4 + j) : (64 + c * 4 + (j - 4));
                float v = acc[i][j] + bias[n0 + col];
                if (ACT == 0) v = fmaxf(v, 0.f);
                e[j] = v;
            }
            float4 v0, v1;
            v0.x = e[0]; v0.y = e[1]; v0.z = e[2]; v0.w = e[3];
            v1.x = e[4]; v1.y = e[5]; v1.z = e[6]; v1.w = e[7];
            *(float4*)&Co[row * N + n0 + c * 4] = v0;
            *(float4*)&Co[row * N + n0 + 64 + c * 4] = v1;
        } else {
            float e[4];
#pragma unroll
            for (int j = 0; j < 4; ++j) {
                float v = acc[i][j] + bias[n0 + c * 4 + j];
                if (ACT == 0) v = fmaxf(v, 0.f);
                e[j] = v;
            }
            float4 v0;
            v0.x = e[0]; v0.y = e[1]; v0.z = e[2]; v0.w = e[3];
            *(float4*)&Co[row * N + n0 + c * 4] = v0;
        }
    }
}

// ---------------------------------------------------------------------------
__global__ void sa_pre(const float* __restrict__ state, const float* __restrict__ action,
                       unsigned short* __restrict__ saH)
{
    int idx = blockIdx.x * 256 + threadIdx.x;
    int row = idx / 12, q = idx % 12;
    const float* src = (q < 8) ? (state + (size_t)row * 64 + q * 8)
                               : (action + (size_t)row * 32 + (q - 8) * 8);
    f32x4 v0 = *(const f32x4*)src;
    f32x4 v1 = *(const f32x4*)(src + 4);
    short8 h;
#pragma unroll
    for (int j = 0; j < 8; ++j) {
        float x = (j < 4) ? v0[j] : v1[j - 4];
        h[j] = (short)f2h(x);
    }
    *(short8*)&saH[(size_t)row * 96 + q * 8] = h;
}

// ---------------------------------------------------------------------------
// NEW: MFMA VQ score.  64 rows/block (4 waves x 16 rows), all 1024 codes.
// A-frag: row=lane&15, k=(lane>>4)*8+j (fp16 mz direct from global).
// B-frag: col=lane&15 -> code; fp16 codebook plane (L2-resident).
// C/D: col=lane&15 (code), row=(lane>>4)*4+q.  Per-lane top-2 over frags,
// shuffle-merge over the 16 col-lanes.  part[row] = {best, sec, idx}.
// ---------------------------------------------------------------------------
__global__ __launch_bounds__(256) void vq_score(
    const unsigned short* __restrict__ mzH,
    const unsigned short* __restrict__ cbH,
    const float* __restrict__ cbn,
    float4* __restrict__ part)
{
    __shared__ float cn[1024];
    const int tid = threadIdx.x;
    const int w = tid >> 6, lane = tid & 63;
    const int g = lane >> 4, lr = lane & 15;
    const int rowbase = blockIdx.x * 64 + w * 16;

#pragma unroll
    for (int it = 0; it < 4; ++it) cn[tid + it * 256] = cbn[tid + it * 256];

    short8 af[2];
#pragma unroll
    for (int s = 0; s < 2; ++s)
        af[s] = *(const short8*)&mzH[(size_t)(rowbase + lr) * 64 + s * 32 + g * 8];
    __syncthreads();

    float best[4], sec[4];
    int bidx[4];
#pragma unroll
    for (int q = 0; q < 4; ++q) { best[q] = 3.4e38f; sec[q] = 3.4e38f; bidx[q] = 0x7fffffff; }

#pragma unroll 4
    for (int nf = 0; nf < 64; ++nf) {
        int code = nf * 16 + lr;
        short8 bf0 = *(const short8*)&cbH[(size_t)code * 64 + g * 8];
        short8 bf1 = *(const short8*)&cbH[(size_t)code * 64 + 32 + g * 8];
        f32x4 acc;
        acc[0] = 0.f; acc[1] = 0.f; acc[2] = 0.f; acc[3] = 0.f;
        acc = __builtin_amdgcn_mfma_f32_16x16x32_f16(H8(af[0]), H8(bf0), acc, 0, 0, 0);
        acc = __builtin_amdgcn_mfma_f32_16x16x32_f16(H8(af[1]), H8(bf1), acc, 0, 0, 0);
        float cnv = cn[code];
#pragma unroll
        for (int q = 0; q < 4; ++q) {
            float s = cnv - 2.0f * acc[q];
            if (s < best[q] || (s == best[q] && code < bidx[q])) {
                sec[q] = best[q];
                best[q] = s;
                bidx[q] = code;
            } else {
                sec[q] = fminf(sec[q], s);
            }
        }
    }

#pragma unroll
    for (int q = 0; q < 4; ++q) {
#pragma unroll
        for (int m = 1; m < 16; m <<= 1) {
            float ob = __shfl_xor(best[q], m, 64);
            int oi = __shfl_xor(bidx[q], m, 64);
            float os = __shfl_xor(sec[q], m, 64);
            if (ob < best[q] || (ob == best[q] && oi < bidx[q])) {
                sec[q] = fminf(best[q], os);
                best[q] = ob;
                bidx[q] = oi;
            } else {
                sec[q] = fminf(sec[q], ob);
            }
        }
    }
    if (lr == 0) {
#pragma unroll
        for (int q = 0; q < 4; ++q) {
            float4 p;
            p.x = best[q];
            p.y = sec[q];
            p.z = __int_as_float(bidx[q]);
            p.w = 0.f;
            part[(size_t)(rowbase + g * 4 + q)] = p;
        }
    }
}

// ---------------------------------------------------------------------------
// VQ merge + flag + latent head + state half of xz.  128 rows/block, grid mt.
// part is now one float4 per row.
// ---------------------------------------------------------------------------
__global__ __launch_bounds__(256) void vq_merge(
    const float4* __restrict__ part,
    const float* __restrict__ state_c,
    const float* __restrict__ codebook,
    const float* __restrict__ mean_w, const float* __restrict__ mean_b,
    const float* __restrict__ logstd_w, const float* __restrict__ logstd_b,
    const float* __restrict__ eps,
    float* __restrict__ mean_out, float* __restrict__ std_out,
    unsigned short* __restrict__ xz,
    int* __restrict__ ctr, int* __restrict__ list, int rowbase)
{
    __shared__ float mw[4160];
    __shared__ float lw[4160];
    __shared__ int sidx[128];

    const int tid = threadIdx.x;
    const int m0 = blockIdx.x * 128;

    if (tid < 128) {
        float4 p0 = part[(size_t)(m0 + tid)];
        int ix = __float_as_int(p0.z);
        sidx[tid] = ix;
        if (p0.y - p0.x < TAU) {
            int p = atomicAdd(ctr, 1);
            list[p] = rowbase + m0 + tid;
        }
    }
#pragma unroll
    for (int it = 0; it < 4; ++it) {
        int idx = tid + it * 256;
        int k = idx >> 4, f = idx & 15;
        float4 v = *(const float4*)(mean_w + (size_t)k * 64 + f * 4);
        mw[k * 65 + f * 4 + 0] = v.x;
        mw[k * 65 + f * 4 + 1] = v.y;
        mw[k * 65 + f * 4 + 2] = v.z;
        mw[k * 65 + f * 4 + 3] = v.w;
        float4 w2 = *(const float4*)(logstd_w + (size_t)k * 64 + f * 4);
        lw[k * 65 + f * 4 + 0] = w2.x;
        lw[k * 65 + f * 4 + 1] = w2.y;
        lw[k * 65 + f * 4 + 2] = w2.z;
        lw[k * 65 + f * 4 + 3] = w2.w;
    }

    {
        int row = tid >> 1;
        int d0 = (tid & 1) * 32;
        size_t so = (size_t)(m0 + row) * 64 + d0;
        size_t xo = (size_t)(m0 + row) * 128 + d0;
#pragma unroll
        for (int q = 0; q < 8; ++q) {
            f32x4 v = *(const f32x4*)&state_c[so + q * 4];
            unsigned short o[4];
            o[0] = f2bf(v[0]); o[1] = f2bf(v[1]);
            o[2] = f2bf(v[2]); o[3] = f2bf(v[3]);
            *(uint2*)&xz[xo + q * 4] = *(uint2*)o;
        }
    }
    __syncthreads();

    {
        int row = tid >> 1;
        int d0 = (tid & 1) * 32;
        int e = sidx[row];
        const float* cb = codebook + (size_t)e * 64;
        float mv[32], lv[32];
#pragma unroll
        for (int d = 0; d < 32; ++d) {
            mv[d] = mean_b[d0 + d];
            lv[d] = logstd_b[d0 + d];
        }
        for (int k = 0; k < 64; ++k) {
            float zk = cb[k];
#pragma unroll
            for (int d = 0; d < 32; ++d) {
                mv[d] = fmaf(zk, mw[k * 65 + d0 + d], mv[d]);
                lv[d] = fmaf(zk, lw[k * 65 + d0 + d], lv[d]);
            }
        }
        size_t ro = (size_t)(m0 + row) * 64 + d0;
        size_t xo = (size_t)(m0 + row) * 128 + 64 + d0;
#pragma unroll
        for (int d = 0; d < 32; ++d) {
            float mean = mv[d];
            float ls = fminf(fmaxf(lv[d], -4.f), 15.f);
            float sd = expf(ls);
            float z = fmaf(sd, eps[ro + d], mean);
            mean_out[ro + d] = mean;
            std_out[ro + d] = sd;
            xz[xo + d] = f2bf(z);
        }
    }
}

// ---------------------------------------------------------------------------
__global__ void gather_fix(const int* __restrict__ ctr, int* __restrict__ meta,
                           const int* __restrict__ list,
                           const float* __restrict__ state,
                           const float* __restrict__ action,
                           float* __restrict__ sa_fix)
{
    int cnt = *ctr; if (cnt > FMAX) cnt = FMAX;
    if (blockIdx.x == 0 && threadIdx.x == 0)
        meta[0] = (cnt + 31) & ~31;
    int t = blockIdx.x * 256 + threadIdx.x;
    if (t >= cnt * 24) return;
    int f = t / 24, q = t % 24;
    size_t g = (size_t)list[f];
    f32x4 v = (q < 16) ? *(const f32x4*)&state[g * 64 + q * 4]
                       : *(const f32x4*)&action[g * 32 + (q - 16) * 4];
    *(f32x4*)&sa_fix[(size_t)f * 96 + q * 4] = v;
}

// ---------------------------------------------------------------------------
__global__ __launch_bounds__(256) void vq_fix(
    const int* __restrict__ ctr, const int* __restrict__ list,
    const float* __restrict__ mz_fix,
    const float* __restrict__ codebook, const float* __restrict__ cbn,
    const float* __restrict__ mean_w, const float* __restrict__ mean_b,
    const float* __restrict__ logstd_w, const float* __restrict__ logstd_b,
    const float* __restrict__ eps,
    float* __restrict__ mean_out, float* __restrict__ std_out,
    unsigned short* __restrict__ xz)
{
    __shared__ float mzs[8][64];
    __shared__ float zns[8];
    __shared__ float sv[2048];
    __shared__ int si[2048];
    __shared__ int am_s[8];

    int cnt = *ctr; if (cnt > FMAX) cnt = FMAX;
    const int base = blockIdx.x * 8;
    if (base >= cnt) return;
    const int nr = min(8, cnt - base);
    const int tid = threadIdx.x;

    if (tid < 128) {
        int rr = tid >> 4, q = tid & 15;
        int src = base + ((rr < nr) ? rr : 0);
        *(f32x4*)&mzs[rr][q * 4] = *(const f32x4*)&mz_fix[(size_t)src * 64 + q * 4];
    }
    __syncthreads();
    if (tid < 8) {
        float s = 0.f;
#pragma unroll
        for (int k = 0; k < 64; ++k) s = fmaf(mzs[tid][k], mzs[tid][k], s);
        zns[tid] = s;
    }
    __syncthreads();

    float bb[8];
    int bi[8];
#pragma unroll
    for (int rr = 0; rr < 8; ++rr) { bb[rr] = 3.4e38f; bi[rr] = 0x7fffffff; }
    for (int j = 0; j < 4; ++j) {
        int code = tid + j * 256;
        const f32x4* cp = (const f32x4*)(codebook + (size_t)code * 64);
        float dot[8];
#pragma unroll
        for (int rr = 0; rr < 8; ++rr) dot[rr] = 0.f;
        for (int t = 0; t < 16; ++t) {
            f32x4 cv = cp[t];
#pragma unroll
            for (int e = 0; e < 4; ++e) {
                float cvv = cv[e];
#pragma unroll
                for (int rr = 0; rr < 8; ++rr)
                    dot[rr] = fmaf(mzs[rr][t * 4 + e], cvv, dot[rr]);
            }
        }
        float cnv = cbn[code];
#pragma unroll
        for (int rr = 0; rr < 8; ++rr) {
            float s = (zns[rr] + cnv) - 2.0f * dot[rr];
            if (s < bb[rr] || (s == bb[rr] && code < bi[rr])) {
                bb[rr] = s; bi[rr] = code;
            }
        }
    }
#pragma unroll
    for (int rr = 0; rr < 8; ++rr) {
        sv[rr * 256 + tid] = bb[rr];
        si[rr * 256 + tid] = bi[rr];
    }
    __syncthreads();
    if (tid < 8) {
        float b = 3.4e38f;
        int ix = 0x7fffffff;
        for (int t = 0; t < 256; ++t) {
            float v = sv[tid * 256 + t];
            int iv = si[tid * 256 + t];
            if (v < b || (v == b && iv < ix)) { b = v; ix = iv; }
        }
        am_s[tid] = ix;
    }
    __syncthreads();

    for (int jo = 0; jo < 2; ++jo) {
        int o = tid + jo * 256;
        int rr = o >> 6, d = o & 63;
        if (rr < nr) {
            int e = am_s[rr];
            size_t g = (size_t)list[base + rr];
            float mv = mean_b[d], lv = logstd_b[d];
            const float* cb = codebook + (size_t)e * 64;
            for (int k = 0; k < 64; ++k) {
                float zk = cb[k];
                mv = fmaf(zk, mean_w[(size_t)k * 64 + d], mv);
                lv = fmaf(zk, logstd_w[(size_t)k * 64 + d], lv);
            }
            float ls = fminf(fmaxf(lv, -4.f), 15.f);
            float sd = expf(ls);
            float z = fmaf(sd, eps[g * 64 + d], mv);
            mean_out[g * 64 + d] = mv;
            std_out[g * 64 + d] = sd;
            xz[g * 128 + 64 + d] = f2bf(z);
        }
    }
}

// ---------------------------------------------------------------------------
extern "C" void kernel_launch(void* const* d_in, const int* in_sizes, int n_in,
                              void* d_out, int out_size, void* d_ws, size_t ws_size,
                              hipStream_t stream)
{
    const float* state    = (const float*)d_in[0];
    const float* action   = (const float*)d_in[1];
    const float* eps      = (const float*)d_in[2];
    const float* enc_w1   = (const float*)d_in[3];
    const float* enc_b1   = (const float*)d_in[4];
    const float* enc_w2   = (const float*)d_in[5];
    const float* enc_b2   = (const float*)d_in[6];
    const float* enc_w3   = (const float*)d_in[7];
    const float* enc_b3   = (const float*)d_in[8];
    const float* mean_w   = (const float*)d_in[9];
    const float* mean_b   = (const float*)d_in[10];
    const float* logstd_w = (const float*)d_in[11];
    const float* logstd_b = (const float*)d_in[12];
    const float* codebook = (const float*)d_in[13];
    const float* dec_w1   = (const float*)d_in[14];
    const float* dec_b1   = (const float*)d_in[15];
    const float* dec_w2   = (const float*)d_in[16];
    const float* dec_b2   = (const float*)d_in[17];
    const float* dec_w3   = (const float*)d_in[18];
    const float* dec_b3   = (const float*)d_in[19];

    float* out = (float*)d_out;
    float* u_out = out;
    float* mean_out = out + (size_t)B_TOTAL * 32;
    float* std_out = mean_out + (size_t)B_TOTAL * 64;

    // ---- fixed ws region ----
    char* base = (char*)d_ws;
    float* cbn = (float*)base;                                   // 4096
    unsigned short* W1h = (unsigned short*)(base + 4096);        // fp16
    unsigned short* W2h = (unsigned short*)(base + 397312);      // fp16 (256-layout)
    unsigned short* W3h = (unsigned short*)(base + 4591616);     // fp16
    unsigned short* W4h = (unsigned short*)(base + 4853760);     // bf16
    unsigned short* W5h = (unsigned short*)(base + 5115904);     // bf16 (256-layout)
    unsigned short* W6h = (unsigned short*)(base + 7213056);     // bf16
    int* ctr            = (int*)(base + 7278592);                // 256
    int* flag_list      = (int*)(base + 7278848);                // 262144
    int* meta           = (int*)(base + 7540992);                // 256
    float4* part        = (float4*)(base + 7541248);             // B*16 = 1048576
    unsigned short* cbH = (unsigned short*)(base + 8589824);     // 131072
    const size_t FIXED  = 8720896;

    unsigned short* xz_g = (unsigned short*)(base + FIXED);      // 16 MB
    const size_t XZ_SZ = (size_t)B_TOTAL * 128 * 2;

    // dyn region: saH 192 + h1H 2048 + h2H 2048 + mz 256 = 4544 B per row
    const size_t per_row = 4544;
    size_t avail = (ws_size > FIXED + XZ_SZ) ? (ws_size - FIXED - XZ_SZ) : 0;
    long maxC = (long)(avail / per_row);
    int C = (int)(maxC / 1024) * 1024;
    if (C > B_TOTAL) C = B_TOTAL;
    if (C < 12288) C = 12288;   // >= fix-alias region

    char* dyn = base + FIXED + XZ_SZ;
    unsigned short* saH = (unsigned short*)dyn;                   // [C,96] fp16
    unsigned short* h1H = saH + (size_t)C * 96;                   // [C,1024] fp16
    unsigned short* h2H = h1H + (size_t)C * 1024;                 // [C,1024] fp16
    unsigned short* mzH = h2H + (size_t)C * 1024;                 // [C,64] fp16
    unsigned short* hc = h1H;   // decoder reuse (bf16)
    unsigned short* hd = h2H;

    float* sa_fix = (float*)dyn;                                  // 2359296
    float* h1_fix = (float*)(dyn + 2359296);                      // 25165824
    float* h2_fix = (float*)(dyn + 27525120);                     // 25165824
    float* mz_fix = (float*)(dyn + 52690944);                     // 1572864

    // dynamic-LDS attrs; fall back to proven kernels if denied
    bool deep = hipFuncSetAttribute(
        reinterpret_cast<const void*>(&mfma_gemm128<4, 3, 4, 0>),
        hipFuncAttributeMaxDynamicSharedMemorySize, 49152) == hipSuccess;
    deep = deep && hipFuncSetAttribute(
        reinterpret_cast<const void*>(&mfma_gemm128<1, 4, 1, 0>),
        hipFuncAttributeMaxDynamicSharedMemorySize, 65536) == hipSuccess;
    bool d256 = hipFuncSetAttribute(
        reinterpret_cast<const void*>(&mfma_gemm256<1, 0>),
        hipFuncAttributeMaxDynamicSharedMemorySize, 131072) == hipSuccess;
    d256 = d256 && hipFuncSetAttribute(
        reinterpret_cast<const void*>(&mfma_gemm256<0, 0>),
        hipFuncAttributeMaxDynamicSharedMemorySize, 131072) == hipSuccess;
    d256 = d256 && deep;

    // ---- once per call ----
    cb_norms<<<dim3(4), dim3(256), 0, stream>>>(codebook, cbn, cbH);
    zero_ctr<<<dim3(1), dim3(64), 0, stream>>>(ctr);
    w_xform<2, 128><<<dim3(3, 8), dim3(256), 0, stream>>>(enc_w1, 96, 1024, W1h, nullptr);
    if (d256) wx256<1><<<dim3(16, 8), dim3(256), 0, stream>>>(enc_w2, 1024, W2h);
    else w_xform<2, 128><<<dim3(32, 8), dim3(256), 0, stream>>>(enc_w2, 1024, 1024, W2h, nullptr);
    w_xform<2, 64><<<dim3(32, 1), dim3(256), 0, stream>>>(enc_w3, 1024, 64, W3h, nullptr);
    w_xform<1, 128><<<dim3(4, 8), dim3(256), 0, stream>>>(dec_w1, 128, 1024, W4h, nullptr);
    if (d256) wx256<0><<<dim3(16, 8), dim3(256), 0, stream>>>(dec_w2, 1024, W5h);
    else w_xform<1, 128><<<dim3(32, 8), dim3(256), 0, stream>>>(dec_w2, 1024, 1024, W5h, nullptr);
    w_xform<1, 32><<<dim3(32, 1), dim3(256), 0, stream>>>(dec_w3, 1024, 32, W6h, nullptr);

    // ---- phase A: encoder + VQ ----
    for (int r0 = 0; r0 < B_TOTAL; r0 += C) {
        int M = (r0 + C <= B_TOTAL) ? C : (B_TOTAL - r0);
        int mt = M / 128;

        sa_pre<<<dim3(M * 12 / 256), dim3(256), 0, stream>>>(
            state + (size_t)r0 * SDIM, action + (size_t)r0 * ADIM, saH);

        mfma_gemm128<4, 3, 4, 0><<<dim3(mt * 8), dim3(256), 49152, stream>>>(
            saH, 96, W1h, enc_b1, h1H, 1024);
        if (d256)
            mfma_gemm256<1, 0><<<dim3((M / 256) * 4), dim3(512), 131072, stream>>>(
                h1H, 1024, W2h, enc_b2, h2H, 1024);
        else
            mfma_gemm128<4, 3, 4, 0><<<dim3(mt * 8), dim3(256), 49152, stream>>>(
                h1H, 1024, W2h, enc_b2, h2H, 1024);
        mfma_gemm64<4, 64, 4, 0><<<dim3(M / 64), dim3(256), 0, stream>>>(
            h2H, 1024, W3h, enc_b3, mzH, 64);

        vq_score<<<dim3(M / 64), dim3(256), 0, stream>>>(
            mzH, cbH, cbn, part + r0);
        vq_merge<<<dim3(mt), dim3(256), 0, stream>>>(
            part + r0, state + (size_t)r0 * SDIM, codebook,
            mean_w, mean_b, logstd_w, logstd_b,
            eps + (size_t)r0 * LDIM,
            mean_out + (size_t)r0 * LDIM, std_out + (size_t)r0 * LDIM,
            xz_g + (size_t)r0 * 128, ctr, flag_list, r0);
    }

    // ---- phase B: exact-fp32 fixup ----
    gather_fix<<<dim3(FMAX * 24 / 256), dim3(256), 0, stream>>>(
        ctr, meta, flag_list, state, action, sa_fix);
    gemm_fix<128, 0><<<dim3(FMAX / 32, 8), dim3(256), 0, stream>>>(
        meta, sa_fix, 96, enc_w1, enc_b1, h1_fix, 1024);
    gemm_fix<128, 0><<<dim3(FMAX / 32, 8), dim3(256), 0, stream>>>(
        meta, h1_fix, 1024, enc_w2, enc_b2, h2_fix, 1024);
    gemm_fix<64, 0><<<dim3(FMAX / 32, 1), dim3(256), 0, stream>>>(
        meta, h2_fix, 1024, enc_w3, enc_b3, mz_fix, 64);
    vq_fix<<<dim3(FMAX / 8), dim3(256), 0, stream>>>(
        ctr, flag_list, mz_fix, codebook, cbn,
        mean_w, mean_b, logstd_w, logstd_b, eps,
        mean_out, std_out, xz_g);

    // ---- phase C: decoder ----
    for (int r0 = 0; r0 < B_TOTAL; r0 += C) {
        int M = (r0 + C <= B_TOTAL) ? C : (B_TOTAL - r0);
        int mt = M / 128;

        mfma_gemm128<1, 4, 1, 0><<<dim3(mt * 8), dim3(256), 65536, stream>>>(
            xz_g + (size_t)r0 * 128, 128, W4h, dec_b1, hc, 1024);
        if (d256)
            mfma_gemm256<0, 0><<<dim3((M / 256) * 4), dim3(512), 131072, stream>>>(
                hc, 1024, W5h, dec_b2, hd, 1024);
        else
            mfma_gemm128<1, 4, 1, 0><<<dim3(mt * 8), dim3(256), 65536, stream>>>(
                hc, 1024, W5h, dec_b2, hd, 1024);
        mfma_gemm64<1, 32, 2, 1><<<dim3(M / 64), dim3(256), 0, stream>>>(
            hd, 1024, W6h, dec_b3, u_out + (size_t)r0 * ADIM, 32);
    }
}

// Round 19
// 1051.449 us; speedup vs baseline: 1.4424x; 1.0240x over previous
//
#include <hip/hip_runtime.h>
#include <cstdint>
#include <cstddef>

#define B_TOTAL 65536
#define SDIM 64
#define ADIM 32
#define LDIM 64
#define HDIM 1024
#define NEMB 1024
#define TAU 0.125f
#define FMAX 6144

typedef __attribute__((ext_vector_type(8))) short short8;
typedef __attribute__((ext_vector_type(8))) _Float16 half8;
typedef __attribute__((ext_vector_type(4))) float f32x4;

__device__ inline unsigned short f2bf(float f) {
    unsigned int u = __float_as_uint(f);
    u += 0x7fffu + ((u >> 16) & 1u);
    return (unsigned short)(u >> 16);
}
__device__ inline float bf2f(unsigned short s) {
    return __uint_as_float(((unsigned int)s) << 16);
}
__device__ inline unsigned short f2h(float f) {
    _Float16 h = (_Float16)f;
    return __builtin_bit_cast(unsigned short, h);
}
__device__ inline float h2f(unsigned short s) {
    return (float)__builtin_bit_cast(_Float16, s);
}
__device__ inline half8 H8(short8 v) { return __builtin_bit_cast(half8, v); }

// async global->LDS, 16B per lane; LDS dest = wave-uniform base + lane*16.
__device__ inline void gload16(const unsigned short* g, unsigned short* l) {
    __builtin_amdgcn_global_load_lds(
        (__attribute__((address_space(1))) void*)(g),
        (__attribute__((address_space(3))) void*)(l), 16, 0, 0);
}

// exact counted vmcnt (wt always lands on an enumerated value)
__device__ inline void vm_wait(int wt) {
    if (wt >= 12)      asm volatile("s_waitcnt vmcnt(12)" ::: "memory");
    else if (wt >= 8)  asm volatile("s_waitcnt vmcnt(8)" ::: "memory");
    else if (wt >= 6)  asm volatile("s_waitcnt vmcnt(6)" ::: "memory");
    else if (wt >= 4)  asm volatile("s_waitcnt vmcnt(4)" ::: "memory");
    else               asm volatile("s_waitcnt vmcnt(0)" ::: "memory");
}

// ---------------------------------------------------------------------------
// codebook norms + fp16 plane (row-major [1024][64])
// ---------------------------------------------------------------------------
__global__ void cb_norms(const float* __restrict__ codebook, float* __restrict__ cbn,
                         unsigned short* __restrict__ cbH)
{
    int i = blockIdx.x * 256 + threadIdx.x;
    if (i < NEMB) {
        float s = 0.f;
#pragma unroll
        for (int k = 0; k < LDIM; ++k) {
            float v = codebook[(size_t)i * LDIM + k];
            s = fmaf(v, v, s);
            cbH[(size_t)i * LDIM + k] = f2h(v);
        }
        cbn[i] = s;
    }
}

__global__ void zero_ctr(int* ctr) { if (threadIdx.x == 0) *ctr = 0; }

// ---------------------------------------------------------------------------
// Weight pre-transform (old 32-k-block layout): NT==1 bf16, NT==2 fp16.
// ---------------------------------------------------------------------------
template <int NT, int BN>
__global__ __launch_bounds__(256) void w_xform(
    const float* __restrict__ W, int K, int N,
    unsigned short* __restrict__ Ph, unsigned short* __restrict__ Pl)
{
    __shared__ float Ws[32][BN + 4];
    const int tid = threadIdx.x;
    const int ks = blockIdx.x, nb = blockIdx.y;
    const int k0 = ks * 32, n0 = nb * BN;
    constexpr int LT = 32 * (BN / 4);
#pragma unroll
    for (int it = 0; it < (LT + 255) / 256; ++it) {
        int idx = tid + it * 256;
        if (LT % 256 == 0 || idx < LT) {
            int k = idx / (BN / 4);
            int nf = idx % (BN / 4);
            *(f32x4*)&Ws[k][nf * 4] =
                *(const f32x4*)&W[(size_t)(k0 + k) * N + n0 + nf * 4];
        }
    }
    __syncthreads();
    const int KS = K >> 5;
    size_t bo = ((size_t)nb * KS + ks) * (BN * 32);
    constexpr int WT = BN * 4;
#pragma unroll
    for (int it = 0; it < (WT + 255) / 256; ++it) {
        int idx = tid + it * 256;
        if (WT % 256 == 0 || idx < WT) {
            int kb = idx / BN;
            int n = idx % BN;
            short8 h;
#pragma unroll
            for (int j = 0; j < 8; ++j) {
                float x = Ws[kb * 8 + j][n];
                h[j] = (NT == 2) ? (short)f2h(x) : (short)f2bf(x);
            }
            *(short8*)&Ph[bo + (size_t)idx * 8] = h;
        }
    }
}

// ---------------------------------------------------------------------------
// 256-tile pre-transform for the 8-phase kernel (N=1024 fixed).
// ---------------------------------------------------------------------------
template <int FP16>
__global__ __launch_bounds__(256) void wx256(
    const float* __restrict__ W, int K, unsigned short* __restrict__ P)
{
    __shared__ float Ws[64][132];
    const int tid = threadIdx.x;
    const int kt = blockIdx.x;
    const int nb = blockIdx.y >> 1, hb = blockIdx.y & 1;
    const int n0 = nb * 256 + hb * 128;
    const int KT = K >> 6;
#pragma unroll
    for (int it = 0; it < 8; ++it) {
        int idx = tid + it * 256;
        int k = idx >> 5, nf = idx & 31;
        *(f32x4*)&Ws[k][nf * 4] =
            *(const f32x4*)&W[(size_t)(kt * 64 + k) * 1024 + n0 + nf * 4];
    }
    __syncthreads();
    size_t bo = (((size_t)nb * KT + kt) * 2 + hb) * 8192;
#pragma unroll
    for (int it = 0; it < 4; ++it) {
        int t = tid + it * 256;
        int kb = t >> 7, col = t & 127;
        short8 h;
#pragma unroll
        for (int j = 0; j < 8; ++j) {
            float x = Ws[kb * 8 + j][col];
            h[j] = FP16 ? (short)f2h(x) : (short)f2bf(x);
        }
        *(short8*)&P[bo + (size_t)t * 8] = h;
    }
}

// ---------------------------------------------------------------------------
// 256x256 8-phase MFMA GEMM (K=1024 layers), proven round 17.
// ---------------------------------------------------------------------------
template <int FP16, int ACT>
__global__ __launch_bounds__(512, 1) void mfma_gemm256(
    const unsigned short* __restrict__ Ag, int K,
    const unsigned short* __restrict__ Wg,
    const float* __restrict__ bias,
    unsigned short* __restrict__ out0, int NTOT)
{
    extern __shared__ unsigned short smem[];
    const int tid = threadIdx.x;
    const int w = tid >> 6, lane = tid & 63;
    const int g = lane >> 4, lr = lane & 15;
    int per = gridDim.x >> 3;
    int xcd = blockIdx.x & 7;
    int lid = blockIdx.x >> 3;
    int tile = xcd * per + lid;
    const int m0 = (tile >> 2) * 256;
    const int nb = tile & 3;
    const int n0 = nb * 256;
    const int wrow0 = (w >> 2) * 128;
    const int wcol0 = (w & 3) * 64;
    const int hA = wrow0 >> 7;
    const int hB = wcol0 >> 7;
    const int cB0 = (wcol0 & 127);
    const int KT = K >> 6;
    const int T = KT >> 1;

    auto stageAh = [&](int kt, int h) {
        unsigned short* dst = smem + (((kt & 1) * 2 + h) * 8192);
#pragma unroll
        for (int it = 0; it < 2; ++it) {
            int t0 = it * 512 + (w << 6);
            int tt = t0 + lane;
            int kb = tt >> 7, row = tt & 127;
            size_t go = (size_t)(m0 + h * 128 + row) * K + (size_t)kt * 64 + kb * 8;
            gload16(Ag + go, dst + (size_t)t0 * 8);
        }
    };
    auto stageBh = [&](int kt, int h) {
        unsigned short* dst = smem + 32768 + (((kt & 1) * 2 + h) * 8192);
        size_t bo = (((size_t)nb * KT + kt) * 2 + h) * 8192;
#pragma unroll
        for (int it = 0; it < 2; ++it) {
            int t0 = it * 512 + (w << 6);
            gload16(Wg + bo + (size_t)(t0 + lane) * 8, dst + (size_t)t0 * 8);
        }
    };

    float bv[4];
#pragma unroll
    for (int n = 0; n < 4; ++n) bv[n] = bias[n0 + wcol0 + n * 16 + lr];
    asm volatile("s_waitcnt vmcnt(0)" ::: "memory");
    __builtin_amdgcn_sched_barrier(0);

    f32x4 acc[8][4];
#pragma unroll
    for (int m = 0; m < 8; ++m)
#pragma unroll
        for (int n = 0; n < 4; ++n) {
            acc[m][n][0] = 0.f; acc[m][n][1] = 0.f;
            acc[m][n][2] = 0.f; acc[m][n][3] = 0.f;
        }

    short8 bf[4][2];

#define CPH(ktc, MP, LB) do {                                                   \
        unsigned short* Ab = smem + ((((ktc) & 1) * 2 + hA) * 8192);            \
        unsigned short* Bb = smem + 32768 + ((((ktc) & 1) * 2 + hB) * 8192);    \
        if (LB) {                                                               \
            _Pragma("unroll") for (int n = 0; n < 4; ++n)                       \
            _Pragma("unroll") for (int s = 0; s < 2; ++s)                       \
                bf[n][s] = *(const short8*)&Bb[((s * 4 + g) * 128 + cB0 + n * 16 + lr) * 8]; \
        }                                                                       \
        short8 af[2][2];                                                        \
        _Pragma("unroll") for (int mm = 0; mm < 2; ++mm)                        \
        _Pragma("unroll") for (int s = 0; s < 2; ++s)                           \
            af[mm][s] = *(const short8*)&Ab[((s * 4 + g) * 128 + ((MP) * 2 + mm) * 16 + lr) * 8]; \
        asm volatile("s_waitcnt lgkmcnt(0)" ::: "memory");                      \
        __builtin_amdgcn_sched_barrier(0);                                      \
        __builtin_amdgcn_s_setprio(1);                                          \
        _Pragma("unroll") for (int mm = 0; mm < 2; ++mm)                        \
        _Pragma("unroll") for (int n = 0; n < 4; ++n)                           \
        _Pragma("unroll") for (int s = 0; s < 2; ++s) {                         \
            if (FP16) acc[(MP) * 2 + mm][n] = __builtin_amdgcn_mfma_f32_16x16x32_f16( \
                H8(af[mm][s]), H8(bf[n][s]), acc[(MP) * 2 + mm][n], 0, 0, 0);   \
            else acc[(MP) * 2 + mm][n] = __builtin_amdgcn_mfma_f32_16x16x32_bf16( \
                af[mm][s], bf[n][s], acc[(MP) * 2 + mm][n], 0, 0, 0);           \
        }                                                                       \
        __builtin_amdgcn_s_setprio(0);                                          \
    } while (0)

    stageAh(0, 0); stageBh(0, 0); stageBh(0, 1); stageAh(0, 1);
    stageAh(1, 0); stageBh(1, 0); stageBh(1, 1); stageAh(1, 1);

    for (int t = 0; t < T; ++t) {
        int k0t = 2 * t, k1t = 2 * t + 1;
        if (t > 0) stageAh(k1t, 0);
        asm volatile("s_waitcnt vmcnt(2)" ::: "memory");
        __builtin_amdgcn_s_barrier();
        CPH(k0t, 0, 1);
        if (t > 0) stageBh(k1t, 0);
        CPH(k0t, 1, 0);
        if (t > 0) stageBh(k1t, 1);
        CPH(k0t, 2, 0);
        if (t > 0) stageAh(k1t, 1);
        CPH(k0t, 3, 0);
        __builtin_amdgcn_s_barrier();
        if (k0t + 2 < KT) {
            stageAh(k0t + 2, 0);
            asm volatile("s_waitcnt vmcnt(2)" ::: "memory");
        } else {
            asm volatile("s_waitcnt vmcnt(0)" ::: "memory");
        }
        __builtin_amdgcn_s_barrier();
        CPH(k1t, 0, 1);
        if (k0t + 2 < KT) stageBh(k0t + 2, 0);
        CPH(k1t, 1, 0);
        if (k0t + 2 < KT) stageBh(k0t + 2, 1);
        CPH(k1t, 2, 0);
        if (k0t + 2 < KT) stageAh(k0t + 2, 1);
        CPH(k1t, 3, 0);
        __builtin_amdgcn_s_barrier();
    }
#undef CPH

    unsigned short* Sb = smem;
    __builtin_amdgcn_s_barrier();
#pragma unroll
    for (int m = 0; m < 8; ++m)
#pragma unroll
        for (int n = 0; n < 4; ++n)
#pragma unroll
            for (int q = 0; q < 4; ++q) {
                int rl = wrow0 + m * 16 + g * 4 + q;
                int cl = wcol0 + n * 16 + lr;
                float x = acc[m][n][q] + bv[n];
                if (ACT == 0) x = fmaxf(x, 0.f);
                else x = tanhf(x);
                Sb[rl * 256 + cl] = FP16 ? f2h(x) : f2bf(x);
            }
    __syncthreads();
#pragma unroll
    for (int it = 0; it < 16; ++it) {
        int idx = tid + it * 512;
        int row = idx >> 5, sl = idx & 31;
        *(short8*)&out0[(size_t)(m0 + row) * NTOT + n0 + sl * 8]
            = *(const short8*)&Sb[row * 256 + sl * 8];
    }
}

// ---------------------------------------------------------------------------
// Paired D-deep BN=128 kernel (proven r15/r16) for G1/G4.
// ---------------------------------------------------------------------------
template <int NT, int D, int OUT, int ACT>
__global__ __launch_bounds__(256, 2) void mfma_gemm128(
    const unsigned short* __restrict__ Ah_g, int K,
    const unsigned short* __restrict__ Wh,
    const float* __restrict__ bias,
    void* __restrict__ out0, int NTOT)
{
    constexpr int BN = 128;
    constexpr int WM = 4, WN = 4, NWC = 2;
    constexpr int ASTR = 4096;
    constexpr int BSTR = 4096;
    constexpr int BOFF = D * ASTR;
    constexpr int PAIR = 4;
    extern __shared__ unsigned short smem[];

    const int tid = threadIdx.x;
    int per = gridDim.x >> 3;
    int xcd = blockIdx.x & 7;
    int lid = blockIdx.x >> 3;
    int tile = xcd * per + lid;
    const int m0 = (tile >> 3) * 128;
    const int nb = tile & 7;
    const int n0 = nb * BN;
    const int w = tid >> 6, lane = tid & 63;
    const int g = lane >> 4, lr = lane & 15;
    const int wrow0 = (w / NWC) * (WM * 16);
    const int wcol0 = (w % NWC) * (WN * 16);
    const int KS = K >> 5;

    auto stageA = [&](int i, int ks) {
        unsigned short* Ah = smem + i * ASTR;
#pragma unroll
        for (int it = 0; it < 2; ++it) {
            int t0 = it * 256 + w * 64;
            int t = t0 + lane;
            int row = t & 127, kb = t >> 7;
            size_t go = (size_t)(m0 + row) * K + ks * 32 + kb * 8;
            gload16(Ah_g + go, Ah + (size_t)t0 * 8);
        }
    };
    auto stageB = [&](int j, int ks) {
        unsigned short* Bh = smem + BOFF + j * BSTR;
        size_t bo = ((size_t)nb * KS + ks) * (BN * 32);
#pragma unroll
        for (int it = 0; it < 2; ++it) {
            int t0 = it * 256 + w * 64;
            size_t go = bo + (size_t)(t0 + lane) * 8;
            gload16(Wh + go, Bh + (size_t)t0 * 8);
        }
    };

    float bv[WN];
#pragma unroll
    for (int n = 0; n < WN; ++n) bv[n] = bias[n0 + wcol0 + n * 16 + lr];
    __builtin_amdgcn_sched_barrier(0);

    f32x4 acc[WM][WN];
#pragma unroll
    for (int m = 0; m < WM; ++m)
#pragma unroll
        for (int n = 0; n < WN; ++n) {
            acc[m][n][0] = 0.f; acc[m][n][1] = 0.f;
            acc[m][n][2] = 0.f; acc[m][n][3] = 0.f;
        }

#pragma unroll
    for (int i = 0; i < D - 1; ++i)
        if (i < KS) { stageB(i, i); stageA(i, i); }

    for (int ks = 0; ks < KS; ++ks) {
        __builtin_amdgcn_s_barrier();
        if (ks + D - 1 < KS) {
            stageB((ks + D - 1) % D, ks + D - 1);
            stageA((ks + D - 1) % D, ks + D - 1);
        }
        int futP = KS - 1 - ks; if (futP > D - 1) futP = D - 1;
        vm_wait(futP * PAIR);
        __builtin_amdgcn_s_barrier();
        __builtin_amdgcn_sched_barrier(0);

        unsigned short* Ah = smem + (ks % D) * ASTR;
        unsigned short* Bh = smem + BOFF + (ks % D) * BSTR;

        short8 ah[WM], bh[WN];
#pragma unroll
        for (int m = 0; m < WM; ++m) {
            int ro = (g << 7) + wrow0 + m * 16 + lr;
            ah[m] = *(const short8*)&Ah[ro * 8];
        }
#pragma unroll
        for (int n = 0; n < WN; ++n) {
            int co = g * BN + wcol0 + n * 16 + lr;
            bh[n] = *(const short8*)&Bh[co * 8];
        }
#pragma unroll
        for (int m = 0; m < WM; ++m)
#pragma unroll
            for (int n = 0; n < WN; ++n) {
                if constexpr (NT == 4) {
                    acc[m][n] = __builtin_amdgcn_mfma_f32_16x16x32_f16(
                        H8(ah[m]), H8(bh[n]), acc[m][n], 0, 0, 0);
                } else {
                    acc[m][n] = __builtin_amdgcn_mfma_f32_16x16x32_bf16(
                        ah[m], bh[n], acc[m][n], 0, 0, 0);
                }
            }
    }

    unsigned short* Sb = smem;
    __syncthreads();
#pragma unroll
    for (int m = 0; m < WM; ++m)
#pragma unroll
        for (int n = 0; n < WN; ++n)
#pragma unroll
            for (int q = 0; q < 4; ++q) {
                int rl = wrow0 + m * 16 + g * 4 + q;
                int cl = wcol0 + n * 16 + lr;
                float x = acc[m][n][q] + bv[n];
                if (ACT == 0) x = fmaxf(x, 0.f);
                else x = tanhf(x);
                Sb[rl * BN + cl] = (OUT == 4) ? f2h(x) : f2bf(x);
            }
    __syncthreads();
    constexpr int SL = BN / 8;
    unsigned short* dst = (unsigned short*)out0;
#pragma unroll
    for (int it = 0; it < (128 * SL) / 256; ++it) {
        int idx = tid + it * 256;
        int row = idx / SL, sl = idx % SL;
        *(short8*)&dst[(size_t)(m0 + row) * NTOT + n0 + sl * 8]
            = *(const short8*)&Sb[row * BN + sl * 8];
    }
}

// ---------------------------------------------------------------------------
// BM=64 MFMA GEMM (G3: NT4/BN64 fp16->fp16, G6: NT1/BN32 bf16->fp32).
// OUT: 2 = fp32, 4 = fp16.
// ---------------------------------------------------------------------------
template <int NT, int BN, int OUT, int ACT>
__global__ __launch_bounds__(256) void mfma_gemm64(
    const unsigned short* __restrict__ Ah_g, int K,
    const unsigned short* __restrict__ Wh,
    const float* __restrict__ bias,
    void* __restrict__ out, int NTOT)
{
    constexpr int WM = (BN == 64) ? 2 : 1;
    constexpr int WN = 2;
    constexpr int ABUF = 2048;
    constexpr int BBUF = BN * 32;
    constexpr int BUFSH = ABUF + BBUF;
    __shared__ unsigned short smem[2 * BUFSH];

    const int tid = threadIdx.x;
    const int m0 = blockIdx.x * 64;
    const int w = tid >> 6, lane = tid & 63;
    const int g = lane >> 4, lr = lane & 15;
    const int wrow0 = (BN == 64) ? ((w >> 1) * 32) : (w * 16);
    const int wcol0 = (BN == 64) ? ((w & 1) * 32) : 0;
    const int KS = K >> 5;

    auto stage = [&](unsigned short* buf, int ks) {
        unsigned short* Ah = buf;
        unsigned short* Bh = buf + ABUF;
        {
            int t0 = w * 64;
            int t = t0 + lane;
            int row = t & 63, kb = t >> 6;
            size_t go = (size_t)(m0 + row) * K + ks * 32 + kb * 8;
            gload16(Ah_g + go, Ah + (size_t)t0 * 8);
        }
        size_t bo = (size_t)ks * (BN * 32);
        constexpr int BT = BN * 4;
        if constexpr (BT == 256) {
            int t0 = w * 64;
            size_t go = bo + (size_t)(t0 + lane) * 8;
            gload16(Wh + go, Bh + (size_t)t0 * 8);
        } else {
            if (tid < BT) {
                int t0 = w * 64;
                size_t go = bo + (size_t)(t0 + lane) * 8;
                gload16(Wh + go, Bh + (size_t)t0 * 8);
            }
        }
    };

    f32x4 acc[WM][WN];
#pragma unroll
    for (int m = 0; m < WM; ++m)
#pragma unroll
        for (int n = 0; n < WN; ++n) {
            acc[m][n][0] = 0.f; acc[m][n][1] = 0.f;
            acc[m][n][2] = 0.f; acc[m][n][3] = 0.f;
        }

    stage(smem, 0);

    for (int ks = 0; ks < KS; ++ks) {
        __syncthreads();
        unsigned short* buf = smem + (size_t)(ks & 1) * BUFSH;
        if (ks + 1 < KS)
            stage(smem + (size_t)((ks + 1) & 1) * BUFSH, ks + 1);

        unsigned short* Ah = buf;
        unsigned short* Bh = buf + ABUF;

        short8 ah[WM], bh[WN];
#pragma unroll
        for (int m = 0; m < WM; ++m) {
            int ro = (g << 6) + wrow0 + m * 16 + lr;
            ah[m] = *(const short8*)&Ah[ro * 8];
        }
#pragma unroll
        for (int n = 0; n < WN; ++n) {
            int co = g * BN + wcol0 + n * 16 + lr;
            bh[n] = *(const short8*)&Bh[co * 8];
        }
#pragma unroll
        for (int m = 0; m < WM; ++m)
#pragma unroll
            for (int n = 0; n < WN; ++n) {
                if constexpr (NT == 4) {
                    acc[m][n] = __builtin_amdgcn_mfma_f32_16x16x32_f16(
                        H8(ah[m]), H8(bh[n]), acc[m][n], 0, 0, 0);
                } else {
                    acc[m][n] = __builtin_amdgcn_mfma_f32_16x16x32_bf16(
                        ah[m], bh[n], acc[m][n], 0, 0, 0);
                }
            }
    }

    float bv[WN];
#pragma unroll
    for (int n = 0; n < WN; ++n) bv[n] = bias[wcol0 + n * 16 + lr];

    __syncthreads();
    if constexpr (OUT == 2) {
        float* Sf = (float*)smem;
#pragma unroll
        for (int m = 0; m < WM; ++m)
#pragma unroll
            for (int n = 0; n < WN; ++n)
#pragma unroll
                for (int q = 0; q < 4; ++q) {
                    int rl = wrow0 + m * 16 + g * 4 + q;
                    int cl = wcol0 + n * 16 + lr;
                    float x = acc[m][n][q] + bv[n];
                    if (ACT == 0) x = fmaxf(x, 0.f);
                    else x = tanhf(x);
                    Sf[rl * BN + cl] = x;
                }
        __syncthreads();
        constexpr int SL = BN / 4;
#pragma unroll
        for (int it = 0; it < (64 * SL) / 256; ++it) {
            int idx = tid + it * 256;
            int row = idx / SL, sl = idx % SL;
            *(f32x4*)((float*)out + (size_t)(m0 + row) * NTOT + sl * 4)
                = *(const f32x4*)&Sf[row * BN + sl * 4];
        }
    } else {
        unsigned short* Sb = smem;
#pragma unroll
        for (int m = 0; m < WM; ++m)
#pragma unroll
            for (int n = 0; n < WN; ++n)
#pragma unroll
                for (int q = 0; q < 4; ++q) {
                    int rl = wrow0 + m * 16 + g * 4 + q;
                    int cl = wcol0 + n * 16 + lr;
                    float x = acc[m][n][q] + bv[n];
                    if (ACT == 0) x = fmaxf(x, 0.f);
                    else x = tanhf(x);
                    Sb[rl * BN + cl] = f2h(x);
                }
        __syncthreads();
        constexpr int SL = BN / 8;
        unsigned short* dst = (unsigned short*)out;
#pragma unroll
        for (int it = 0; it < (64 * SL) / 256; ++it) {
            int idx = tid + it * 256;
            int row = idx / SL, sl = idx % SL;
            *(short8*)&dst[(size_t)(m0 + row) * NTOT + sl * 8]
                = *(const short8*)&Sb[row * BN + sl * 8];
        }
    }
}

// ---------------------------------------------------------------------------
// fp32 fixup GEMM v3: 64-row tiles, K-step 32 (4x compute per barrier vs v2;
// round-18 counters showed VALUBusy 38% = barrier-stall dominated).
// 256 threads = 16 rowgrp x 16 colgrp; each thread 4 rows x TN cols.
// ---------------------------------------------------------------------------
template <int BN, int ACT>
__global__ __launch_bounds__(256) void gemm_fix(
    const int* __restrict__ mrows,
    const float* __restrict__ A, int K,
    const float* __restrict__ W, const float* __restrict__ bias,
    float* __restrict__ Co, int N)
{
    const int m0 = blockIdx.x * 64;
    if (m0 >= *mrows) return;

    constexpr int TN = BN / 16;          // 8 or 4
    __shared__ float At[32][68];
    __shared__ float Bt[32][BN + 4];

    const int tid = threadIdx.x;
    const int n0 = blockIdx.y * BN;
    const int rg = tid >> 4;
    const int cg = tid & 15;

    float acc[4][TN];
#pragma unroll
    for (int i = 0; i < 4; ++i)
#pragma unroll
        for (int j = 0; j < TN; ++j) acc[i][j] = 0.f;

    for (int k0 = 0; k0 < K; k0 += 32) {
        // stage A: 64 rows x 32 k, transposed; 512 f4 tasks (2/thread)
#pragma unroll
        for (int it = 0; it < 2; ++it) {
            int idx = tid + it * 256;
            int row = idx >> 3, lf = idx & 7;
            float4 v = *(const float4*)(A + (size_t)(m0 + row) * K + k0 + lf * 4);
            At[lf * 4 + 0][row] = v.x;
            At[lf * 4 + 1][row] = v.y;
            At[lf * 4 + 2][row] = v.z;
            At[lf * 4 + 3][row] = v.w;
        }
        // stage B: 32 k x BN; 32*BN/4 f4 tasks
        constexpr int NF4 = BN / 4;
        constexpr int NEL = 32 * NF4;
#pragma unroll
        for (int it = 0; it < NEL / 256; ++it) {
            int idx = tid + it * 256;
            int kk = idx / NF4;
            int f = idx % NF4;
            float4 v = *(const float4*)(W + (size_t)(k0 + kk) * N + n0 + f * 4);
            *(float4*)&Bt[kk][f * 4] = v;
        }
        __syncthreads();

#pragma unroll
        for (int kk = 0; kk < 32; ++kk) {
            float a[4];
            float4 av = *(const float4*)&At[kk][rg * 4];
            a[0] = av.x; a[1] = av.y; a[2] = av.z; a[3] = av.w;
            float b[TN];
            if constexpr (BN == 128) {
                float4 b0 = *(const float4*)&Bt[kk][cg * 8];
                float4 b1 = *(const float4*)&Bt[kk][cg * 8 + 4];
                b[0] = b0.x; b[1] = b0.y; b[2] = b0.z; b[3] = b0.w;
                b[4] = b1.x; b[5] = b1.y; b[6] = b1.z; b[7] = b1.w;
            } else {
                float4 b0 = *(const float4*)&Bt[kk][cg * 4];
                b[0] = b0.x; b[1] = b0.y; b[2] = b0.z; b[3] = b0.w;
            }
#pragma unroll
            for (int i = 0; i < 4; ++i)
#pragma unroll
                for (int j = 0; j < TN; ++j)
                    acc[i][j] = fmaf(a[i], b[j], acc[i][j]);
        }
        __syncthreads();
    }

#pragma unroll
    for (int i = 0; i < 4; ++i) {
        size_t row = (size_t)(m0 + rg * 4 + i);
        if constexpr (BN == 128) {
            float e[8];
#pragma unroll
            for (int j = 0; j < 8; ++j) {
                float v = acc[i][j] + bias[n0 + cg * 8 + j];
                if (ACT == 0) v = fmaxf(v, 0.f);
                e[j] = v;
            }
            float4 v0, v1;
            v0.x = e[0]; v0.y = e[1]; v0.z = e[2]; v0.w = e[3];
            v1.x = e[4]; v1.y = e[5]; v1.z = e[6]; v1.w = e[7];
            *(float4*)&Co[row * N + n0 + cg * 8] = v0;
            *(float4*)&Co[row * N + n0 + cg * 8 + 4] = v1;
        } else {
            float e[4];
#pragma unroll
            for (int j = 0; j < 4; ++j) {
                float v = acc[i][j] + bias[n0 + cg * 4 + j];
                if (ACT == 0) v = fmaxf(v, 0.f);
                e[j] = v;
            }
            float4 v0;
            v0.x = e[0]; v0.y = e[1]; v0.z = e[2]; v0.w = e[3];
            *(float4*)&Co[row * N + n0 + cg * 4] = v0;
        }
    }
}

// ---------------------------------------------------------------------------
__global__ void sa_pre(const float* __restrict__ state, const float* __restrict__ action,
                       unsigned short* __restrict__ saH)
{
    int idx = blockIdx.x * 256 + threadIdx.x;
    int row = idx / 12, q = idx % 12;
    const float* src = (q < 8) ? (state + (size_t)row * 64 + q * 8)
                               : (action + (size_t)row * 32 + (q - 8) * 8);
    f32x4 v0 = *(const f32x4*)src;
    f32x4 v1 = *(const f32x4*)(src + 4);
    short8 h;
#pragma unroll
    for (int j = 0; j < 8; ++j) {
        float x = (j < 4) ? v0[j] : v1[j - 4];
        h[j] = (short)f2h(x);
    }
    *(short8*)&saH[(size_t)row * 96 + q * 8] = h;
}

// ---------------------------------------------------------------------------
// MFMA VQ score (proven round 18).
// ---------------------------------------------------------------------------
__global__ __launch_bounds__(256) void vq_score(
    const unsigned short* __restrict__ mzH,
    const unsigned short* __restrict__ cbH,
    const float* __restrict__ cbn,
    float4* __restrict__ part)
{
    __shared__ float cn[1024];
    const int tid = threadIdx.x;
    const int w = tid >> 6, lane = tid & 63;
    const int g = lane >> 4, lr = lane & 15;
    const int rowbase = blockIdx.x * 64 + w * 16;

#pragma unroll
    for (int it = 0; it < 4; ++it) cn[tid + it * 256] = cbn[tid + it * 256];

    short8 af[2];
#pragma unroll
    for (int s = 0; s < 2; ++s)
        af[s] = *(const short8*)&mzH[(size_t)(rowbase + lr) * 64 + s * 32 + g * 8];
    __syncthreads();

    float best[4], sec[4];
    int bidx[4];
#pragma unroll
    for (int q = 0; q < 4; ++q) { best[q] = 3.4e38f; sec[q] = 3.4e38f; bidx[q] = 0x7fffffff; }

#pragma unroll 4
    for (int nf = 0; nf < 64; ++nf) {
        int code = nf * 16 + lr;
        short8 bf0 = *(const short8*)&cbH[(size_t)code * 64 + g * 8];
        short8 bf1 = *(const short8*)&cbH[(size_t)code * 64 + 32 + g * 8];
        f32x4 acc;
        acc[0] = 0.f; acc[1] = 0.f; acc[2] = 0.f; acc[3] = 0.f;
        acc = __builtin_amdgcn_mfma_f32_16x16x32_f16(H8(af[0]), H8(bf0), acc, 0, 0, 0);
        acc = __builtin_amdgcn_mfma_f32_16x16x32_f16(H8(af[1]), H8(bf1), acc, 0, 0, 0);
        float cnv = cn[code];
#pragma unroll
        for (int q = 0; q < 4; ++q) {
            float s = cnv - 2.0f * acc[q];
            if (s < best[q] || (s == best[q] && code < bidx[q])) {
                sec[q] = best[q];
                best[q] = s;
                bidx[q] = code;
            } else {
                sec[q] = fminf(sec[q], s);
            }
        }
    }

#pragma unroll
    for (int q = 0; q < 4; ++q) {
#pragma unroll
        for (int m = 1; m < 16; m <<= 1) {
            float ob = __shfl_xor(best[q], m, 64);
            int oi = __shfl_xor(bidx[q], m, 64);
            float os = __shfl_xor(sec[q], m, 64);
            if (ob < best[q] || (ob == best[q] && oi < bidx[q])) {
                sec[q] = fminf(best[q], os);
                best[q] = ob;
                bidx[q] = oi;
            } else {
                sec[q] = fminf(sec[q], ob);
            }
        }
    }
    if (lr == 0) {
#pragma unroll
        for (int q = 0; q < 4; ++q) {
            float4 p;
            p.x = best[q];
            p.y = sec[q];
            p.z = __int_as_float(bidx[q]);
            p.w = 0.f;
            part[(size_t)(rowbase + g * 4 + q)] = p;
        }
    }
}

// ---------------------------------------------------------------------------
// VQ merge + flag + latent head + state half of xz.  128 rows/block, grid mt.
// ---------------------------------------------------------------------------
__global__ __launch_bounds__(256) void vq_merge(
    const float4* __restrict__ part,
    const float* __restrict__ state_c,
    const float* __restrict__ codebook,
    const float* __restrict__ mean_w, const float* __restrict__ mean_b,
    const float* __restrict__ logstd_w, const float* __restrict__ logstd_b,
    const float* __restrict__ eps,
    float* __restrict__ mean_out, float* __restrict__ std_out,
    unsigned short* __restrict__ xz,
    int* __restrict__ ctr, int* __restrict__ list, int rowbase)
{
    __shared__ float mw[4160];
    __shared__ float lw[4160];
    __shared__ int sidx[128];

    const int tid = threadIdx.x;
    const int m0 = blockIdx.x * 128;

    if (tid < 128) {
        float4 p0 = part[(size_t)(m0 + tid)];
        int ix = __float_as_int(p0.z);
        sidx[tid] = ix;
        if (p0.y - p0.x < TAU) {
            int p = atomicAdd(ctr, 1);
            list[p] = rowbase + m0 + tid;
        }
    }
#pragma unroll
    for (int it = 0; it < 4; ++it) {
        int idx = tid + it * 256;
        int k = idx >> 4, f = idx & 15;
        float4 v = *(const float4*)(mean_w + (size_t)k * 64 + f * 4);
        mw[k * 65 + f * 4 + 0] = v.x;
        mw[k * 65 + f * 4 + 1] = v.y;
        mw[k * 65 + f * 4 + 2] = v.z;
        mw[k * 65 + f * 4 + 3] = v.w;
        float4 w2 = *(const float4*)(logstd_w + (size_t)k * 64 + f * 4);
        lw[k * 65 + f * 4 + 0] = w2.x;
        lw[k * 65 + f * 4 + 1] = w2.y;
        lw[k * 65 + f * 4 + 2] = w2.z;
        lw[k * 65 + f * 4 + 3] = w2.w;
    }

    {
        int row = tid >> 1;
        int d0 = (tid & 1) * 32;
        size_t so = (size_t)(m0 + row) * 64 + d0;
        size_t xo = (size_t)(m0 + row) * 128 + d0;
#pragma unroll
        for (int q = 0; q < 8; ++q) {
            f32x4 v = *(const f32x4*)&state_c[so + q * 4];
            unsigned short o[4];
            o[0] = f2bf(v[0]); o[1] = f2bf(v[1]);
            o[2] = f2bf(v[2]); o[3] = f2bf(v[3]);
            *(uint2*)&xz[xo + q * 4] = *(uint2*)o;
        }
    }
    __syncthreads();

    {
        int row = tid >> 1;
        int d0 = (tid & 1) * 32;
        int e = sidx[row];
        const float* cb = codebook + (size_t)e * 64;
        float mv[32], lv[32];
#pragma unroll
        for (int d = 0; d < 32; ++d) {
            mv[d] = mean_b[d0 + d];
            lv[d] = logstd_b[d0 + d];
        }
        for (int k = 0; k < 64; ++k) {
            float zk = cb[k];
#pragma unroll
            for (int d = 0; d < 32; ++d) {
                mv[d] = fmaf(zk, mw[k * 65 + d0 + d], mv[d]);
                lv[d] = fmaf(zk, lw[k * 65 + d0 + d], lv[d]);
            }
        }
        size_t ro = (size_t)(m0 + row) * 64 + d0;
        size_t xo = (size_t)(m0 + row) * 128 + 64 + d0;
#pragma unroll
        for (int d = 0; d < 32; ++d) {
            float mean = mv[d];
            float ls = fminf(fmaxf(lv[d], -4.f), 15.f);
            float sd = expf(ls);
            float z = fmaf(sd, eps[ro + d], mean);
            mean_out[ro + d] = mean;
            std_out[ro + d] = sd;
            xz[xo + d] = f2bf(z);
        }
    }
}

// ---------------------------------------------------------------------------
__global__ void gather_fix(const int* __restrict__ ctr, int* __restrict__ meta,
                           const int* __restrict__ list,
                           const float* __restrict__ state,
                           const float* __restrict__ action,
                           float* __restrict__ sa_fix)
{
    int cnt = *ctr; if (cnt > FMAX) cnt = FMAX;
    if (blockIdx.x == 0 && threadIdx.x == 0)
        meta[0] = (cnt + 63) & ~63;
    int t = blockIdx.x * 256 + threadIdx.x;
    if (t >= cnt * 24) return;
    int f = t / 24, q = t % 24;
    size_t g = (size_t)list[f];
    f32x4 v = (q < 16) ? *(const f32x4*)&state[g * 64 + q * 4]
                       : *(const f32x4*)&action[g * 32 + (q - 16) * 4];
    *(f32x4*)&sa_fix[(size_t)f * 96 + q * 4] = v;
}

// ---------------------------------------------------------------------------
__global__ __launch_bounds__(256) void vq_fix(
    const int* __restrict__ ctr, const int* __restrict__ list,
    const float* __restrict__ mz_fix,
    const float* __restrict__ codebook, const float* __restrict__ cbn,
    const float* __restrict__ mean_w, const float* __restrict__ mean_b,
    const float* __restrict__ logstd_w, const float* __restrict__ logstd_b,
    const float* __restrict__ eps,
    float* __restrict__ mean_out, float* __restrict__ std_out,
    unsigned short* __restrict__ xz)
{
    __shared__ float mzs[8][64];
    __shared__ float zns[8];
    __shared__ float sv[2048];
    __shared__ int si[2048];
    __shared__ int am_s[8];

    int cnt = *ctr; if (cnt > FMAX) cnt = FMAX;
    const int base = blockIdx.x * 8;
    if (base >= cnt) return;
    const int nr = min(8, cnt - base);
    const int tid = threadIdx.x;

    if (tid < 128) {
        int rr = tid >> 4, q = tid & 15;
        int src = base + ((rr < nr) ? rr : 0);
        *(f32x4*)&mzs[rr][q * 4] = *(const f32x4*)&mz_fix[(size_t)src * 64 + q * 4];
    }
    __syncthreads();
    if (tid < 8) {
        float s = 0.f;
#pragma unroll
        for (int k = 0; k < 64; ++k) s = fmaf(mzs[tid][k], mzs[tid][k], s);
        zns[tid] = s;
    }
    __syncthreads();

    float bb[8];
    int bi[8];
#pragma unroll
    for (int rr = 0; rr < 8; ++rr) { bb[rr] = 3.4e38f; bi[rr] = 0x7fffffff; }
    for (int j = 0; j < 4; ++j) {
        int code = tid + j * 256;
        const f32x4* cp = (const f32x4*)(codebook + (size_t)code * 64);
        float dot[8];
#pragma unroll
        for (int rr = 0; rr < 8; ++rr) dot[rr] = 0.f;
        for (int t = 0; t < 16; ++t) {
            f32x4 cv = cp[t];
#pragma unroll
            for (int e = 0; e < 4; ++e) {
                float cvv = cv[e];
#pragma unroll
                for (int rr = 0; rr < 8; ++rr)
                    dot[rr] = fmaf(mzs[rr][t * 4 + e], cvv, dot[rr]);
            }
        }
        float cnv = cbn[code];
#pragma unroll
        for (int rr = 0; rr < 8; ++rr) {
            float s = (zns[rr] + cnv) - 2.0f * dot[rr];
            if (s < bb[rr] || (s == bb[rr] && code < bi[rr])) {
                bb[rr] = s; bi[rr] = code;
            }
        }
    }
#pragma unroll
    for (int rr = 0; rr < 8; ++rr) {
        sv[rr * 256 + tid] = bb[rr];
        si[rr * 256 + tid] = bi[rr];
    }
    __syncthreads();
    if (tid < 8) {
        float b = 3.4e38f;
        int ix = 0x7fffffff;
        for (int t = 0; t < 256; ++t) {
            float v = sv[tid * 256 + t];
            int iv = si[tid * 256 + t];
            if (v < b || (v == b && iv < ix)) { b = v; ix = iv; }
        }
        am_s[tid] = ix;
    }
    __syncthreads();

    for (int jo = 0; jo < 2; ++jo) {
        int o = tid + jo * 256;
        int rr = o >> 6, d = o & 63;
        if (rr < nr) {
            int e = am_s[rr];
            size_t g = (size_t)list[base + rr];
            float mv = mean_b[d], lv = logstd_b[d];
            const float* cb = codebook + (size_t)e * 64;
            for (int k = 0; k < 64; ++k) {
                float zk = cb[k];
                mv = fmaf(zk, mean_w[(size_t)k * 64 + d], mv);
                lv = fmaf(zk, logstd_w[(size_t)k * 64 + d], lv);
            }
            float ls = fminf(fmaxf(lv, -4.f), 15.f);
            float sd = expf(ls);
            float z = fmaf(sd, eps[g * 64 + d], mv);
            mean_out[g * 64 + d] = mv;
            std_out[g * 64 + d] = sd;
            xz[g * 128 + 64 + d] = f2bf(z);
        }
    }
}

// ---------------------------------------------------------------------------
extern "C" void kernel_launch(void* const* d_in, const int* in_sizes, int n_in,
                              void* d_out, int out_size, void* d_ws, size_t ws_size,
                              hipStream_t stream)
{
    const float* state    = (const float*)d_in[0];
    const float* action   = (const float*)d_in[1];
    const float* eps      = (const float*)d_in[2];
    const float* enc_w1   = (const float*)d_in[3];
    const float* enc_b1   = (const float*)d_in[4];
    const float* enc_w2   = (const float*)d_in[5];
    const float* enc_b2   = (const float*)d_in[6];
    const float* enc_w3   = (const float*)d_in[7];
    const float* enc_b3   = (const float*)d_in[8];
    const float* mean_w   = (const float*)d_in[9];
    const float* mean_b   = (const float*)d_in[10];
    const float* logstd_w = (const float*)d_in[11];
    const float* logstd_b = (const float*)d_in[12];
    const float* codebook = (const float*)d_in[13];
    const float* dec_w1   = (const float*)d_in[14];
    const float* dec_b1   = (const float*)d_in[15];
    const float* dec_w2   = (const float*)d_in[16];
    const float* dec_b2   = (const float*)d_in[17];
    const float* dec_w3   = (const float*)d_in[18];
    const float* dec_b3   = (const float*)d_in[19];

    float* out = (float*)d_out;
    float* u_out = out;
    float* mean_out = out + (size_t)B_TOTAL * 32;
    float* std_out = mean_out + (size_t)B_TOTAL * 64;

    // ---- fixed ws region ----
    char* base = (char*)d_ws;
    float* cbn = (float*)base;                                   // 4096
    unsigned short* W1h = (unsigned short*)(base + 4096);        // fp16
    unsigned short* W2h = (unsigned short*)(base + 397312);      // fp16 (256-layout)
    unsigned short* W3h = (unsigned short*)(base + 4591616);     // fp16
    unsigned short* W4h = (unsigned short*)(base + 4853760);     // bf16
    unsigned short* W5h = (unsigned short*)(base + 5115904);     // bf16 (256-layout)
    unsigned short* W6h = (unsigned short*)(base + 7213056);     // bf16
    int* ctr            = (int*)(base + 7278592);                // 256
    int* flag_list      = (int*)(base + 7278848);                // 262144
    int* meta           = (int*)(base + 7540992);                // 256
    float4* part        = (float4*)(base + 7541248);             // B*16 = 1048576
    unsigned short* cbH = (unsigned short*)(base + 8589824);     // 131072
    const size_t FIXED  = 8720896;

    unsigned short* xz_g = (unsigned short*)(base + FIXED);      // 16 MB
    const size_t XZ_SZ = (size_t)B_TOTAL * 128 * 2;

    // dyn region: saH 192 + h1H 2048 + h2H 2048 + mz 256 = 4544 B per row
    const size_t per_row = 4544;
    size_t avail = (ws_size > FIXED + XZ_SZ) ? (ws_size - FIXED - XZ_SZ) : 0;
    long maxC = (long)(avail / per_row);
    int C = (int)(maxC / 1024) * 1024;
    if (C > B_TOTAL) C = B_TOTAL;
    if (C < 12288) C = 12288;   // >= fix-alias region

    char* dyn = base + FIXED + XZ_SZ;
    unsigned short* saH = (unsigned short*)dyn;                   // [C,96] fp16
    unsigned short* h1H = saH + (size_t)C * 96;                   // [C,1024] fp16
    unsigned short* h2H = h1H + (size_t)C * 1024;                 // [C,1024] fp16
    unsigned short* mzH = h2H + (size_t)C * 1024;                 // [C,64] fp16
    unsigned short* hc = h1H;   // decoder reuse (bf16)
    unsigned short* hd = h2H;

    float* sa_fix = (float*)dyn;                                  // 2359296
    float* h1_fix = (float*)(dyn + 2359296);                      // 25165824
    float* h2_fix = (float*)(dyn + 27525120);                     // 25165824
    float* mz_fix = (float*)(dyn + 52690944);                     // 1572864

    // dynamic-LDS attrs; fall back to proven kernels if denied
    bool deep = hipFuncSetAttribute(
        reinterpret_cast<const void*>(&mfma_gemm128<4, 3, 4, 0>),
        hipFuncAttributeMaxDynamicSharedMemorySize, 49152) == hipSuccess;
    deep = deep && hipFuncSetAttribute(
        reinterpret_cast<const void*>(&mfma_gemm128<1, 4, 1, 0>),
        hipFuncAttributeMaxDynamicSharedMemorySize, 65536) == hipSuccess;
    bool d256 = hipFuncSetAttribute(
        reinterpret_cast<const void*>(&mfma_gemm256<1, 0>),
        hipFuncAttributeMaxDynamicSharedMemorySize, 131072) == hipSuccess;
    d256 = d256 && hipFuncSetAttribute(
        reinterpret_cast<const void*>(&mfma_gemm256<0, 0>),
        hipFuncAttributeMaxDynamicSharedMemorySize, 131072) == hipSuccess;
    d256 = d256 && deep;

    // ---- once per call ----
    cb_norms<<<dim3(4), dim3(256), 0, stream>>>(codebook, cbn, cbH);
    zero_ctr<<<dim3(1), dim3(64), 0, stream>>>(ctr);
    w_xform<2, 128><<<dim3(3, 8), dim3(256), 0, stream>>>(enc_w1, 96, 1024, W1h, nullptr);
    if (d256) wx256<1><<<dim3(16, 8), dim3(256), 0, stream>>>(enc_w2, 1024, W2h);
    else w_xform<2, 128><<<dim3(32, 8), dim3(256), 0, stream>>>(enc_w2, 1024, 1024, W2h, nullptr);
    w_xform<2, 64><<<dim3(32, 1), dim3(256), 0, stream>>>(enc_w3, 1024, 64, W3h, nullptr);
    w_xform<1, 128><<<dim3(4, 8), dim3(256), 0, stream>>>(dec_w1, 128, 1024, W4h, nullptr);
    if (d256) wx256<0><<<dim3(16, 8), dim3(256), 0, stream>>>(dec_w2, 1024, W5h);
    else w_xform<1, 128><<<dim3(32, 8), dim3(256), 0, stream>>>(dec_w2, 1024, 1024, W5h, nullptr);
    w_xform<1, 32><<<dim3(32, 1), dim3(256), 0, stream>>>(dec_w3, 1024, 32, W6h, nullptr);

    // ---- phase A: encoder + VQ ----
    for (int r0 = 0; r0 < B_TOTAL; r0 += C) {
        int M = (r0 + C <= B_TOTAL) ? C : (B_TOTAL - r0);
        int mt = M / 128;

        sa_pre<<<dim3(M * 12 / 256), dim3(256), 0, stream>>>(
            state + (size_t)r0 * SDIM, action + (size_t)r0 * ADIM, saH);

        mfma_gemm128<4, 3, 4, 0><<<dim3(mt * 8), dim3(256), 49152, stream>>>(
            saH, 96, W1h, enc_b1, h1H, 1024);
        if (d256)
            mfma_gemm256<1, 0><<<dim3((M / 256) * 4), dim3(512), 131072, stream>>>(
                h1H, 1024, W2h, enc_b2, h2H, 1024);
        else
            mfma_gemm128<4, 3, 4, 0><<<dim3(mt * 8), dim3(256), 49152, stream>>>(
                h1H, 1024, W2h, enc_b2, h2H, 1024);
        mfma_gemm64<4, 64, 4, 0><<<dim3(M / 64), dim3(256), 0, stream>>>(
            h2H, 1024, W3h, enc_b3, mzH, 64);

        vq_score<<<dim3(M / 64), dim3(256), 0, stream>>>(
            mzH, cbH, cbn, part + r0);
        vq_merge<<<dim3(mt), dim3(256), 0, stream>>>(
            part + r0, state + (size_t)r0 * SDIM, codebook,
            mean_w, mean_b, logstd_w, logstd_b,
            eps + (size_t)r0 * LDIM,
            mean_out + (size_t)r0 * LDIM, std_out + (size_t)r0 * LDIM,
            xz_g + (size_t)r0 * 128, ctr, flag_list, r0);
    }

    // ---- phase B: exact-fp32 fixup (64-row tiles, K-step 32) ----
    gather_fix<<<dim3(FMAX * 24 / 256), dim3(256), 0, stream>>>(
        ctr, meta, flag_list, state, action, sa_fix);
    gemm_fix<128, 0><<<dim3(FMAX / 64, 8), dim3(256), 0, stream>>>(
        meta, sa_fix, 96, enc_w1, enc_b1, h1_fix, 1024);
    gemm_fix<128, 0><<<dim3(FMAX / 64, 8), dim3(256), 0, stream>>>(
        meta, h1_fix, 1024, enc_w2, enc_b2, h2_fix, 1024);
    gemm_fix<64, 0><<<dim3(FMAX / 64, 1), dim3(256), 0, stream>>>(
        meta, h2_fix, 1024, enc_w3, enc_b3, mz_fix, 64);
    vq_fix<<<dim3(FMAX / 8), dim3(256), 0, stream>>>(
        ctr, flag_list, mz_fix, codebook, cbn,
        mean_w, mean_b, logstd_w, logstd_b, eps,
        mean_out, std_out, xz_g);

    // ---- phase C: decoder ----
    for (int r0 = 0; r0 < B_TOTAL; r0 += C) {
        int M = (r0 + C <= B_TOTAL) ? C : (B_TOTAL - r0);
        int mt = M / 128;

        mfma_gemm128<1, 4, 1, 0><<<dim3(mt * 8), dim3(256), 65536, stream>>>(
            xz_g + (size_t)r0 * 128, 128, W4h, dec_b1, hc, 1024);
        if (d256)
            mfma_gemm256<0, 0><<<dim3((M / 256) * 4), dim3(512), 131072, stream>>>(
                hc, 1024, W5h, dec_b2, hd, 1024);
        else
            mfma_gemm128<1, 4, 1, 0><<<dim3(mt * 8), dim3(256), 65536, stream>>>(
                hc, 1024, W5h, dec_b2, hd, 1024);
        mfma_gemm64<1, 32, 2, 1><<<dim3(M / 64), dim3(256), 0, stream>>>(
            hd, 1024, W6h, dec_b3, u_out + (size_t)r0 * ADIM, 32);
    }
}

// Round 20
// 983.394 us; speedup vs baseline: 1.5422x; 1.0692x over previous
//
#include <hip/hip_runtime.h>
#include <cstdint>
#include <cstddef>

#define B_TOTAL 65536
#define SDIM 64
#define ADIM 32
#define LDIM 64
#define HDIM 1024
#define NEMB 1024
#define TAU 0.125f
#define FMAX 6144

typedef __attribute__((ext_vector_type(8))) short short8;
typedef __attribute__((ext_vector_type(8))) _Float16 half8;
typedef __attribute__((ext_vector_type(4))) float f32x4;

__device__ inline unsigned short f2bf(float f) {
    unsigned int u = __float_as_uint(f);
    u += 0x7fffu + ((u >> 16) & 1u);
    return (unsigned short)(u >> 16);
}
__device__ inline float bf2f(unsigned short s) {
    return __uint_as_float(((unsigned int)s) << 16);
}
__device__ inline unsigned short f2h(float f) {
    _Float16 h = (_Float16)f;
    return __builtin_bit_cast(unsigned short, h);
}
__device__ inline float h2f(unsigned short s) {
    return (float)__builtin_bit_cast(_Float16, s);
}
__device__ inline half8 H8(short8 v) { return __builtin_bit_cast(half8, v); }

// async global->LDS, 16B per lane; LDS dest = wave-uniform base + lane*16.
__device__ inline void gload16(const unsigned short* g, unsigned short* l) {
    __builtin_amdgcn_global_load_lds(
        (__attribute__((address_space(1))) void*)(g),
        (__attribute__((address_space(3))) void*)(l), 16, 0, 0);
}

// exact counted vmcnt (wt always lands on an enumerated value)
__device__ inline void vm_wait(int wt) {
    if (wt >= 12)      asm volatile("s_waitcnt vmcnt(12)" ::: "memory");
    else if (wt >= 8)  asm volatile("s_waitcnt vmcnt(8)" ::: "memory");
    else if (wt >= 6)  asm volatile("s_waitcnt vmcnt(6)" ::: "memory");
    else if (wt >= 4)  asm volatile("s_waitcnt vmcnt(4)" ::: "memory");
    else               asm volatile("s_waitcnt vmcnt(0)" ::: "memory");
}

// ---------------------------------------------------------------------------
// codebook norms + fp16 plane (row-major [1024][64])
// ---------------------------------------------------------------------------
__global__ void cb_norms(const float* __restrict__ codebook, float* __restrict__ cbn,
                         unsigned short* __restrict__ cbH)
{
    int i = blockIdx.x * 256 + threadIdx.x;
    if (i < NEMB) {
        float s = 0.f;
#pragma unroll
        for (int k = 0; k < LDIM; ++k) {
            float v = codebook[(size_t)i * LDIM + k];
            s = fmaf(v, v, s);
            cbH[(size_t)i * LDIM + k] = f2h(v);
        }
        cbn[i] = s;
    }
}

// ---------------------------------------------------------------------------
// NEW round-20: per-code latent-head tables.  mean/std depend only on the
// code index -> precompute CBm[1024][64], CBs[1024][64] once.  k-major fmaf
// order matches the old vq_merge/vq_fix matvec bitwise.
// ---------------------------------------------------------------------------
__global__ __launch_bounds__(256) void cb_head(
    const float* __restrict__ codebook,
    const float* __restrict__ mean_w, const float* __restrict__ mean_b,
    const float* __restrict__ logstd_w, const float* __restrict__ logstd_b,
    float* __restrict__ CBm, float* __restrict__ CBs)
{
    int idx = blockIdx.x * 256 + threadIdx.x;   // grid 256 -> 1024 codes x 64 d
    int e = idx >> 6, d = idx & 63;
    const float* cb = codebook + (size_t)e * 64;
    float mv = mean_b[d], lv = logstd_b[d];
#pragma unroll 8
    for (int k = 0; k < 64; ++k) {
        float zk = cb[k];
        mv = fmaf(zk, mean_w[(size_t)k * 64 + d], mv);
        lv = fmaf(zk, logstd_w[(size_t)k * 64 + d], lv);
    }
    CBm[idx] = mv;
    float ls = fminf(fmaxf(lv, -4.f), 15.f);
    CBs[idx] = expf(ls);
}

__global__ void zero_ctr(int* ctr) { if (threadIdx.x == 0) *ctr = 0; }

// ---------------------------------------------------------------------------
// Weight pre-transform (old 32-k-block layout): NT==1 bf16, NT==2 fp16.
// ---------------------------------------------------------------------------
template <int NT, int BN>
__global__ __launch_bounds__(256) void w_xform(
    const float* __restrict__ W, int K, int N,
    unsigned short* __restrict__ Ph, unsigned short* __restrict__ Pl)
{
    __shared__ float Ws[32][BN + 4];
    const int tid = threadIdx.x;
    const int ks = blockIdx.x, nb = blockIdx.y;
    const int k0 = ks * 32, n0 = nb * BN;
    constexpr int LT = 32 * (BN / 4);
#pragma unroll
    for (int it = 0; it < (LT + 255) / 256; ++it) {
        int idx = tid + it * 256;
        if (LT % 256 == 0 || idx < LT) {
            int k = idx / (BN / 4);
            int nf = idx % (BN / 4);
            *(f32x4*)&Ws[k][nf * 4] =
                *(const f32x4*)&W[(size_t)(k0 + k) * N + n0 + nf * 4];
        }
    }
    __syncthreads();
    const int KS = K >> 5;
    size_t bo = ((size_t)nb * KS + ks) * (BN * 32);
    constexpr int WT = BN * 4;
#pragma unroll
    for (int it = 0; it < (WT + 255) / 256; ++it) {
        int idx = tid + it * 256;
        if (WT % 256 == 0 || idx < WT) {
            int kb = idx / BN;
            int n = idx % BN;
            short8 h;
#pragma unroll
            for (int j = 0; j < 8; ++j) {
                float x = Ws[kb * 8 + j][n];
                h[j] = (NT == 2) ? (short)f2h(x) : (short)f2bf(x);
            }
            *(short8*)&Ph[bo + (size_t)idx * 8] = h;
        }
    }
}

// ---------------------------------------------------------------------------
// 256-tile pre-transform for the 8-phase kernel (N=1024 fixed).
// ---------------------------------------------------------------------------
template <int FP16>
__global__ __launch_bounds__(256) void wx256(
    const float* __restrict__ W, int K, unsigned short* __restrict__ P)
{
    __shared__ float Ws[64][132];
    const int tid = threadIdx.x;
    const int kt = blockIdx.x;
    const int nb = blockIdx.y >> 1, hb = blockIdx.y & 1;
    const int n0 = nb * 256 + hb * 128;
    const int KT = K >> 6;
#pragma unroll
    for (int it = 0; it < 8; ++it) {
        int idx = tid + it * 256;
        int k = idx >> 5, nf = idx & 31;
        *(f32x4*)&Ws[k][nf * 4] =
            *(const f32x4*)&W[(size_t)(kt * 64 + k) * 1024 + n0 + nf * 4];
    }
    __syncthreads();
    size_t bo = (((size_t)nb * KT + kt) * 2 + hb) * 8192;
#pragma unroll
    for (int it = 0; it < 4; ++it) {
        int t = tid + it * 256;
        int kb = t >> 7, col = t & 127;
        short8 h;
#pragma unroll
        for (int j = 0; j < 8; ++j) {
            float x = Ws[kb * 8 + j][col];
            h[j] = FP16 ? (short)f2h(x) : (short)f2bf(x);
        }
        *(short8*)&P[bo + (size_t)t * 8] = h;
    }
}

// ---------------------------------------------------------------------------
// 256x256 8-phase MFMA GEMM (K=1024 layers), proven round 17.
// ---------------------------------------------------------------------------
template <int FP16, int ACT>
__global__ __launch_bounds__(512, 1) void mfma_gemm256(
    const unsigned short* __restrict__ Ag, int K,
    const unsigned short* __restrict__ Wg,
    const float* __restrict__ bias,
    unsigned short* __restrict__ out0, int NTOT)
{
    extern __shared__ unsigned short smem[];
    const int tid = threadIdx.x;
    const int w = tid >> 6, lane = tid & 63;
    const int g = lane >> 4, lr = lane & 15;
    int per = gridDim.x >> 3;
    int xcd = blockIdx.x & 7;
    int lid = blockIdx.x >> 3;
    int tile = xcd * per + lid;
    const int m0 = (tile >> 2) * 256;
    const int nb = tile & 3;
    const int n0 = nb * 256;
    const int wrow0 = (w >> 2) * 128;
    const int wcol0 = (w & 3) * 64;
    const int hA = wrow0 >> 7;
    const int hB = wcol0 >> 7;
    const int cB0 = (wcol0 & 127);
    const int KT = K >> 6;
    const int T = KT >> 1;

    auto stageAh = [&](int kt, int h) {
        unsigned short* dst = smem + (((kt & 1) * 2 + h) * 8192);
#pragma unroll
        for (int it = 0; it < 2; ++it) {
            int t0 = it * 512 + (w << 6);
            int tt = t0 + lane;
            int kb = tt >> 7, row = tt & 127;
            size_t go = (size_t)(m0 + h * 128 + row) * K + (size_t)kt * 64 + kb * 8;
            gload16(Ag + go, dst + (size_t)t0 * 8);
        }
    };
    auto stageBh = [&](int kt, int h) {
        unsigned short* dst = smem + 32768 + (((kt & 1) * 2 + h) * 8192);
        size_t bo = (((size_t)nb * KT + kt) * 2 + h) * 8192;
#pragma unroll
        for (int it = 0; it < 2; ++it) {
            int t0 = it * 512 + (w << 6);
            gload16(Wg + bo + (size_t)(t0 + lane) * 8, dst + (size_t)t0 * 8);
        }
    };

    float bv[4];
#pragma unroll
    for (int n = 0; n < 4; ++n) bv[n] = bias[n0 + wcol0 + n * 16 + lr];
    asm volatile("s_waitcnt vmcnt(0)" ::: "memory");
    __builtin_amdgcn_sched_barrier(0);

    f32x4 acc[8][4];
#pragma unroll
    for (int m = 0; m < 8; ++m)
#pragma unroll
        for (int n = 0; n < 4; ++n) {
            acc[m][n][0] = 0.f; acc[m][n][1] = 0.f;
            acc[m][n][2] = 0.f; acc[m][n][3] = 0.f;
        }

    short8 bf[4][2];

#define CPH(ktc, MP, LB) do {                                                   \
        unsigned short* Ab = smem + ((((ktc) & 1) * 2 + hA) * 8192);            \
        unsigned short* Bb = smem + 32768 + ((((ktc) & 1) * 2 + hB) * 8192);    \
        if (LB) {                                                               \
            _Pragma("unroll") for (int n = 0; n < 4; ++n)                       \
            _Pragma("unroll") for (int s = 0; s < 2; ++s)                       \
                bf[n][s] = *(const short8*)&Bb[((s * 4 + g) * 128 + cB0 + n * 16 + lr) * 8]; \
        }                                                                       \
        short8 af[2][2];                                                        \
        _Pragma("unroll") for (int mm = 0; mm < 2; ++mm)                        \
        _Pragma("unroll") for (int s = 0; s < 2; ++s)                           \
            af[mm][s] = *(const short8*)&Ab[((s * 4 + g) * 128 + ((MP) * 2 + mm) * 16 + lr) * 8]; \
        asm volatile("s_waitcnt lgkmcnt(0)" ::: "memory");                      \
        __builtin_amdgcn_sched_barrier(0);                                      \
        __builtin_amdgcn_s_setprio(1);                                          \
        _Pragma("unroll") for (int mm = 0; mm < 2; ++mm)                        \
        _Pragma("unroll") for (int n = 0; n < 4; ++n)                           \
        _Pragma("unroll") for (int s = 0; s < 2; ++s) {                         \
            if (FP16) acc[(MP) * 2 + mm][n] = __builtin_amdgcn_mfma_f32_16x16x32_f16( \
                H8(af[mm][s]), H8(bf[n][s]), acc[(MP) * 2 + mm][n], 0, 0, 0);   \
            else acc[(MP) * 2 + mm][n] = __builtin_amdgcn_mfma_f32_16x16x32_bf16( \
                af[mm][s], bf[n][s], acc[(MP) * 2 + mm][n], 0, 0, 0);           \
        }                                                                       \
        __builtin_amdgcn_s_setprio(0);                                          \
    } while (0)

    stageAh(0, 0); stageBh(0, 0); stageBh(0, 1); stageAh(0, 1);
    stageAh(1, 0); stageBh(1, 0); stageBh(1, 1); stageAh(1, 1);

    for (int t = 0; t < T; ++t) {
        int k0t = 2 * t, k1t = 2 * t + 1;
        if (t > 0) stageAh(k1t, 0);
        asm volatile("s_waitcnt vmcnt(2)" ::: "memory");
        __builtin_amdgcn_s_barrier();
        CPH(k0t, 0, 1);
        if (t > 0) stageBh(k1t, 0);
        CPH(k0t, 1, 0);
        if (t > 0) stageBh(k1t, 1);
        CPH(k0t, 2, 0);
        if (t > 0) stageAh(k1t, 1);
        CPH(k0t, 3, 0);
        __builtin_amdgcn_s_barrier();
        if (k0t + 2 < KT) {
            stageAh(k0t + 2, 0);
            asm volatile("s_waitcnt vmcnt(2)" ::: "memory");
        } else {
            asm volatile("s_waitcnt vmcnt(0)" ::: "memory");
        }
        __builtin_amdgcn_s_barrier();
        CPH(k1t, 0, 1);
        if (k0t + 2 < KT) stageBh(k0t + 2, 0);
        CPH(k1t, 1, 0);
        if (k0t + 2 < KT) stageBh(k0t + 2, 1);
        CPH(k1t, 2, 0);
        if (k0t + 2 < KT) stageAh(k0t + 2, 1);
        CPH(k1t, 3, 0);
        __builtin_amdgcn_s_barrier();
    }
#undef CPH

    unsigned short* Sb = smem;
    __builtin_amdgcn_s_barrier();
#pragma unroll
    for (int m = 0; m < 8; ++m)
#pragma unroll
        for (int n = 0; n < 4; ++n)
#pragma unroll
            for (int q = 0; q < 4; ++q) {
                int rl = wrow0 + m * 16 + g * 4 + q;
                int cl = wcol0 + n * 16 + lr;
                float x = acc[m][n][q] + bv[n];
                if (ACT == 0) x = fmaxf(x, 0.f);
                else x = tanhf(x);
                Sb[rl * 256 + cl] = FP16 ? f2h(x) : f2bf(x);
            }
    __syncthreads();
#pragma unroll
    for (int it = 0; it < 16; ++it) {
        int idx = tid + it * 512;
        int row = idx >> 5, sl = idx & 31;
        *(short8*)&out0[(size_t)(m0 + row) * NTOT + n0 + sl * 8]
            = *(const short8*)&Sb[row * 256 + sl * 8];
    }
}

// ---------------------------------------------------------------------------
// Paired D-deep BN=128 kernel (proven r15/r16) for G1/G4.
// ---------------------------------------------------------------------------
template <int NT, int D, int OUT, int ACT>
__global__ __launch_bounds__(256, 2) void mfma_gemm128(
    const unsigned short* __restrict__ Ah_g, int K,
    const unsigned short* __restrict__ Wh,
    const float* __restrict__ bias,
    void* __restrict__ out0, int NTOT)
{
    constexpr int BN = 128;
    constexpr int WM = 4, WN = 4, NWC = 2;
    constexpr int ASTR = 4096;
    constexpr int BSTR = 4096;
    constexpr int BOFF = D * ASTR;
    constexpr int PAIR = 4;
    extern __shared__ unsigned short smem[];

    const int tid = threadIdx.x;
    int per = gridDim.x >> 3;
    int xcd = blockIdx.x & 7;
    int lid = blockIdx.x >> 3;
    int tile = xcd * per + lid;
    const int m0 = (tile >> 3) * 128;
    const int nb = tile & 7;
    const int n0 = nb * BN;
    const int w = tid >> 6, lane = tid & 63;
    const int g = lane >> 4, lr = lane & 15;
    const int wrow0 = (w / NWC) * (WM * 16);
    const int wcol0 = (w % NWC) * (WN * 16);
    const int KS = K >> 5;

    auto stageA = [&](int i, int ks) {
        unsigned short* Ah = smem + i * ASTR;
#pragma unroll
        for (int it = 0; it < 2; ++it) {
            int t0 = it * 256 + w * 64;
            int t = t0 + lane;
            int row = t & 127, kb = t >> 7;
            size_t go = (size_t)(m0 + row) * K + ks * 32 + kb * 8;
            gload16(Ah_g + go, Ah + (size_t)t0 * 8);
        }
    };
    auto stageB = [&](int j, int ks) {
        unsigned short* Bh = smem + BOFF + j * BSTR;
        size_t bo = ((size_t)nb * KS + ks) * (BN * 32);
#pragma unroll
        for (int it = 0; it < 2; ++it) {
            int t0 = it * 256 + w * 64;
            size_t go = bo + (size_t)(t0 + lane) * 8;
            gload16(Wh + go, Bh + (size_t)t0 * 8);
        }
    };

    float bv[WN];
#pragma unroll
    for (int n = 0; n < WN; ++n) bv[n] = bias[n0 + wcol0 + n * 16 + lr];
    __builtin_amdgcn_sched_barrier(0);

    f32x4 acc[WM][WN];
#pragma unroll
    for (int m = 0; m < WM; ++m)
#pragma unroll
        for (int n = 0; n < WN; ++n) {
            acc[m][n][0] = 0.f; acc[m][n][1] = 0.f;
            acc[m][n][2] = 0.f; acc[m][n][3] = 0.f;
        }

#pragma unroll
    for (int i = 0; i < D - 1; ++i)
        if (i < KS) { stageB(i, i); stageA(i, i); }

    for (int ks = 0; ks < KS; ++ks) {
        __builtin_amdgcn_s_barrier();
        if (ks + D - 1 < KS) {
            stageB((ks + D - 1) % D, ks + D - 1);
            stageA((ks + D - 1) % D, ks + D - 1);
        }
        int futP = KS - 1 - ks; if (futP > D - 1) futP = D - 1;
        vm_wait(futP * PAIR);
        __builtin_amdgcn_s_barrier();
        __builtin_amdgcn_sched_barrier(0);

        unsigned short* Ah = smem + (ks % D) * ASTR;
        unsigned short* Bh = smem + BOFF + (ks % D) * BSTR;

        short8 ah[WM], bh[WN];
#pragma unroll
        for (int m = 0; m < WM; ++m) {
            int ro = (g << 7) + wrow0 + m * 16 + lr;
            ah[m] = *(const short8*)&Ah[ro * 8];
        }
#pragma unroll
        for (int n = 0; n < WN; ++n) {
            int co = g * BN + wcol0 + n * 16 + lr;
            bh[n] = *(const short8*)&Bh[co * 8];
        }
#pragma unroll
        for (int m = 0; m < WM; ++m)
#pragma unroll
            for (int n = 0; n < WN; ++n) {
                if constexpr (NT == 4) {
                    acc[m][n] = __builtin_amdgcn_mfma_f32_16x16x32_f16(
                        H8(ah[m]), H8(bh[n]), acc[m][n], 0, 0, 0);
                } else {
                    acc[m][n] = __builtin_amdgcn_mfma_f32_16x16x32_bf16(
                        ah[m], bh[n], acc[m][n], 0, 0, 0);
                }
            }
    }

    unsigned short* Sb = smem;
    __syncthreads();
#pragma unroll
    for (int m = 0; m < WM; ++m)
#pragma unroll
        for (int n = 0; n < WN; ++n)
#pragma unroll
            for (int q = 0; q < 4; ++q) {
                int rl = wrow0 + m * 16 + g * 4 + q;
                int cl = wcol0 + n * 16 + lr;
                float x = acc[m][n][q] + bv[n];
                if (ACT == 0) x = fmaxf(x, 0.f);
                else x = tanhf(x);
                Sb[rl * BN + cl] = (OUT == 4) ? f2h(x) : f2bf(x);
            }
    __syncthreads();
    constexpr int SL = BN / 8;
    unsigned short* dst = (unsigned short*)out0;
#pragma unroll
    for (int it = 0; it < (128 * SL) / 256; ++it) {
        int idx = tid + it * 256;
        int row = idx / SL, sl = idx % SL;
        *(short8*)&dst[(size_t)(m0 + row) * NTOT + n0 + sl * 8]
            = *(const short8*)&Sb[row * BN + sl * 8];
    }
}

// ---------------------------------------------------------------------------
// BM=64 MFMA GEMM (G3: NT4/BN64 fp16->fp16, G6: NT1/BN32 bf16->fp32).
// OUT: 2 = fp32, 4 = fp16.
// ---------------------------------------------------------------------------
template <int NT, int BN, int OUT, int ACT>
__global__ __launch_bounds__(256) void mfma_gemm64(
    const unsigned short* __restrict__ Ah_g, int K,
    const unsigned short* __restrict__ Wh,
    const float* __restrict__ bias,
    void* __restrict__ out, int NTOT)
{
    constexpr int WM = (BN == 64) ? 2 : 1;
    constexpr int WN = 2;
    constexpr int ABUF = 2048;
    constexpr int BBUF = BN * 32;
    constexpr int BUFSH = ABUF + BBUF;
    __shared__ unsigned short smem[2 * BUFSH];

    const int tid = threadIdx.x;
    const int m0 = blockIdx.x * 64;
    const int w = tid >> 6, lane = tid & 63;
    const int g = lane >> 4, lr = lane & 15;
    const int wrow0 = (BN == 64) ? ((w >> 1) * 32) : (w * 16);
    const int wcol0 = (BN == 64) ? ((w & 1) * 32) : 0;
    const int KS = K >> 5;

    auto stage = [&](unsigned short* buf, int ks) {
        unsigned short* Ah = buf;
        unsigned short* Bh = buf + ABUF;
        {
            int t0 = w * 64;
            int t = t0 + lane;
            int row = t & 63, kb = t >> 6;
            size_t go = (size_t)(m0 + row) * K + ks * 32 + kb * 8;
            gload16(Ah_g + go, Ah + (size_t)t0 * 8);
        }
        size_t bo = (size_t)ks * (BN * 32);
        constexpr int BT = BN * 4;
        if constexpr (BT == 256) {
            int t0 = w * 64;
            size_t go = bo + (size_t)(t0 + lane) * 8;
            gload16(Wh + go, Bh + (size_t)t0 * 8);
        } else {
            if (tid < BT) {
                int t0 = w * 64;
                size_t go = bo + (size_t)(t0 + lane) * 8;
                gload16(Wh + go, Bh + (size_t)t0 * 8);
            }
        }
    };

    f32x4 acc[WM][WN];
#pragma unroll
    for (int m = 0; m < WM; ++m)
#pragma unroll
        for (int n = 0; n < WN; ++n) {
            acc[m][n][0] = 0.f; acc[m][n][1] = 0.f;
            acc[m][n][2] = 0.f; acc[m][n][3] = 0.f;
        }

    stage(smem, 0);

    for (int ks = 0; ks < KS; ++ks) {
        __syncthreads();
        unsigned short* buf = smem + (size_t)(ks & 1) * BUFSH;
        if (ks + 1 < KS)
            stage(smem + (size_t)((ks + 1) & 1) * BUFSH, ks + 1);

        unsigned short* Ah = buf;
        unsigned short* Bh = buf + ABUF;

        short8 ah[WM], bh[WN];
#pragma unroll
        for (int m = 0; m < WM; ++m) {
            int ro = (g << 6) + wrow0 + m * 16 + lr;
            ah[m] = *(const short8*)&Ah[ro * 8];
        }
#pragma unroll
        for (int n = 0; n < WN; ++n) {
            int co = g * BN + wcol0 + n * 16 + lr;
            bh[n] = *(const short8*)&Bh[co * 8];
        }
#pragma unroll
        for (int m = 0; m < WM; ++m)
#pragma unroll
            for (int n = 0; n < WN; ++n) {
                if constexpr (NT == 4) {
                    acc[m][n] = __builtin_amdgcn_mfma_f32_16x16x32_f16(
                        H8(ah[m]), H8(bh[n]), acc[m][n], 0, 0, 0);
                } else {
                    acc[m][n] = __builtin_amdgcn_mfma_f32_16x16x32_bf16(
                        ah[m], bh[n], acc[m][n], 0, 0, 0);
                }
            }
    }

    float bv[WN];
#pragma unroll
    for (int n = 0; n < WN; ++n) bv[n] = bias[wcol0 + n * 16 + lr];

    __syncthreads();
    if constexpr (OUT == 2) {
        float* Sf = (float*)smem;
#pragma unroll
        for (int m = 0; m < WM; ++m)
#pragma unroll
            for (int n = 0; n < WN; ++n)
#pragma unroll
                for (int q = 0; q < 4; ++q) {
                    int rl = wrow0 + m * 16 + g * 4 + q;
                    int cl = wcol0 + n * 16 + lr;
                    float x = acc[m][n][q] + bv[n];
                    if (ACT == 0) x = fmaxf(x, 0.f);
                    else x = tanhf(x);
                    Sf[rl * BN + cl] = x;
                }
        __syncthreads();
        constexpr int SL = BN / 4;
#pragma unroll
        for (int it = 0; it < (64 * SL) / 256; ++it) {
            int idx = tid + it * 256;
            int row = idx / SL, sl = idx % SL;
            *(f32x4*)((float*)out + (size_t)(m0 + row) * NTOT + sl * 4)
                = *(const f32x4*)&Sf[row * BN + sl * 4];
        }
    } else {
        unsigned short* Sb = smem;
#pragma unroll
        for (int m = 0; m < WM; ++m)
#pragma unroll
            for (int n = 0; n < WN; ++n)
#pragma unroll
                for (int q = 0; q < 4; ++q) {
                    int rl = wrow0 + m * 16 + g * 4 + q;
                    int cl = wcol0 + n * 16 + lr;
                    float x = acc[m][n][q] + bv[n];
                    if (ACT == 0) x = fmaxf(x, 0.f);
                    else x = tanhf(x);
                    Sb[rl * BN + cl] = f2h(x);
                }
        __syncthreads();
        constexpr int SL = BN / 8;
        unsigned short* dst = (unsigned short*)out;
#pragma unroll
        for (int it = 0; it < (64 * SL) / 256; ++it) {
            int idx = tid + it * 256;
            int row = idx / SL, sl = idx % SL;
            *(short8*)&dst[(size_t)(m0 + row) * NTOT + sl * 8]
                = *(const short8*)&Sb[row * BN + sl * 8];
        }
    }
}

// ---------------------------------------------------------------------------
// fp32 fixup GEMM v3 (proven r19): 64-row tiles, K-step 32, bias+relu epilogue.
// ---------------------------------------------------------------------------
template <int BN, int ACT>
__global__ __launch_bounds__(256) void gemm_fix(
    const int* __restrict__ mrows,
    const float* __restrict__ A, int K,
    const float* __restrict__ W, const float* __restrict__ bias,
    float* __restrict__ Co, int N)
{
    const int m0 = blockIdx.x * 64;
    if (m0 >= *mrows) return;

    constexpr int TN = BN / 16;
    __shared__ float At[32][68];
    __shared__ float Bt[32][BN + 4];

    const int tid = threadIdx.x;
    const int n0 = blockIdx.y * BN;
    const int rg = tid >> 4;
    const int cg = tid & 15;

    float acc[4][TN];
#pragma unroll
    for (int i = 0; i < 4; ++i)
#pragma unroll
        for (int j = 0; j < TN; ++j) acc[i][j] = 0.f;

    for (int k0 = 0; k0 < K; k0 += 32) {
#pragma unroll
        for (int it = 0; it < 2; ++it) {
            int idx = tid + it * 256;
            int row = idx >> 3, lf = idx & 7;
            float4 v = *(const float4*)(A + (size_t)(m0 + row) * K + k0 + lf * 4);
            At[lf * 4 + 0][row] = v.x;
            At[lf * 4 + 1][row] = v.y;
            At[lf * 4 + 2][row] = v.z;
            At[lf * 4 + 3][row] = v.w;
        }
        constexpr int NF4 = BN / 4;
        constexpr int NEL = 32 * NF4;
#pragma unroll
        for (int it = 0; it < NEL / 256; ++it) {
            int idx = tid + it * 256;
            int kk = idx / NF4;
            int f = idx % NF4;
            float4 v = *(const float4*)(W + (size_t)(k0 + kk) * N + n0 + f * 4);
            *(float4*)&Bt[kk][f * 4] = v;
        }
        __syncthreads();

#pragma unroll
        for (int kk = 0; kk < 32; ++kk) {
            float a[4];
            float4 av = *(const float4*)&At[kk][rg * 4];
            a[0] = av.x; a[1] = av.y; a[2] = av.z; a[3] = av.w;
            float b[TN];
            if constexpr (BN == 128) {
                float4 b0 = *(const float4*)&Bt[kk][cg * 8];
                float4 b1 = *(const float4*)&Bt[kk][cg * 8 + 4];
                b[0] = b0.x; b[1] = b0.y; b[2] = b0.z; b[3] = b0.w;
                b[4] = b1.x; b[5] = b1.y; b[6] = b1.z; b[7] = b1.w;
            } else {
                float4 b0 = *(const float4*)&Bt[kk][cg * 4];
                b[0] = b0.x; b[1] = b0.y; b[2] = b0.z; b[3] = b0.w;
            }
#pragma unroll
            for (int i = 0; i < 4; ++i)
#pragma unroll
                for (int j = 0; j < TN; ++j)
                    acc[i][j] = fmaf(a[i], b[j], acc[i][j]);
        }
        __syncthreads();
    }

#pragma unroll
    for (int i = 0; i < 4; ++i) {
        size_t row = (size_t)(m0 + rg * 4 + i);
        if constexpr (BN == 128) {
            float e[8];
#pragma unroll
            for (int j = 0; j < 8; ++j) {
                float v = acc[i][j] + bias[n0 + cg * 8 + j];
                if (ACT == 0) v = fmaxf(v, 0.f);
                e[j] = v;
            }
            float4 v0, v1;
            v0.x = e[0]; v0.y = e[1]; v0.z = e[2]; v0.w = e[3];
            v1.x = e[4]; v1.y = e[5]; v1.z = e[6]; v1.w = e[7];
            *(float4*)&Co[row * N + n0 + cg * 8] = v0;
            *(float4*)&Co[row * N + n0 + cg * 8 + 4] = v1;
        } else {
            float e[4];
#pragma unroll
            for (int j = 0; j < 4; ++j) {
                float v = acc[i][j] + bias[n0 + cg * 4 + j];
                if (ACT == 0) v = fmaxf(v, 0.f);
                e[j] = v;
            }
            float4 v0;
            v0.x = e[0]; v0.y = e[1]; v0.z = e[2]; v0.w = e[3];
            *(float4*)&Co[row * N + n0 + cg * 4] = v0;
        }
    }
}

// ---------------------------------------------------------------------------
// NEW round-20: split-K fixup GEMM (L2 layer).  blockIdx.z picks K-half and
// destination partial buffer; no bias/relu (done in fix_combine).  Fixes the
// 1-block/CU imbalance at cnt~2000 (r19 counters: VALUBusy 39%).
// ---------------------------------------------------------------------------
__global__ __launch_bounds__(256) void gemm_fix_sk(
    const int* __restrict__ mrows,
    const float* __restrict__ A, int K,
    const float* __restrict__ W,
    float* __restrict__ Ca, float* __restrict__ Cb, int N)
{
    constexpr int BN = 128;
    const int m0 = blockIdx.x * 64;
    if (m0 >= *mrows) return;

    __shared__ float At[32][68];
    __shared__ float Bt[32][BN + 4];

    const int tid = threadIdx.x;
    const int n0 = blockIdx.y * BN;
    const int rg = tid >> 4;
    const int cg = tid & 15;
    const int kBase = blockIdx.z * (K >> 1);
    const int kEnd = kBase + (K >> 1);
    float* Co = blockIdx.z ? Cb : Ca;

    float acc[4][8];
#pragma unroll
    for (int i = 0; i < 4; ++i)
#pragma unroll
        for (int j = 0; j < 8; ++j) acc[i][j] = 0.f;

    for (int k0 = kBase; k0 < kEnd; k0 += 32) {
#pragma unroll
        for (int it = 0; it < 2; ++it) {
            int idx = tid + it * 256;
            int row = idx >> 3, lf = idx & 7;
            float4 v = *(const float4*)(A + (size_t)(m0 + row) * K + k0 + lf * 4);
            At[lf * 4 + 0][row] = v.x;
            At[lf * 4 + 1][row] = v.y;
            At[lf * 4 + 2][row] = v.z;
            At[lf * 4 + 3][row] = v.w;
        }
#pragma unroll
        for (int it = 0; it < 4; ++it) {
            int idx = tid + it * 256;
            int kk = idx >> 5;
            int f = idx & 31;
            float4 v = *(const float4*)(W + (size_t)(k0 + kk) * N + n0 + f * 4);
            *(float4*)&Bt[kk][f * 4] = v;
        }
        __syncthreads();

#pragma unroll
        for (int kk = 0; kk < 32; ++kk) {
            float a[4];
            float4 av = *(const float4*)&At[kk][rg * 4];
            a[0] = av.x; a[1] = av.y; a[2] = av.z; a[3] = av.w;
            float b[8];
            float4 b0 = *(const float4*)&Bt[kk][cg * 8];
            float4 b1 = *(const float4*)&Bt[kk][cg * 8 + 4];
            b[0] = b0.x; b[1] = b0.y; b[2] = b0.z; b[3] = b0.w;
            b[4] = b1.x; b[5] = b1.y; b[6] = b1.z; b[7] = b1.w;
#pragma unroll
            for (int i = 0; i < 4; ++i)
#pragma unroll
                for (int j = 0; j < 8; ++j)
                    acc[i][j] = fmaf(a[i], b[j], acc[i][j]);
        }
        __syncthreads();
    }

#pragma unroll
    for (int i = 0; i < 4; ++i) {
        size_t row = (size_t)(m0 + rg * 4 + i);
        float4 v0, v1;
        v0.x = acc[i][0]; v0.y = acc[i][1]; v0.z = acc[i][2]; v0.w = acc[i][3];
        v1.x = acc[i][4]; v1.y = acc[i][5]; v1.z = acc[i][6]; v1.w = acc[i][7];
        *(float4*)&Co[row * N + n0 + cg * 8] = v0;
        *(float4*)&Co[row * N + n0 + cg * 8 + 4] = v1;
    }
}

// combine: out = relu(pa + pb + bias); one row per block (N=1024, 256 thr x f32x4)
__global__ __launch_bounds__(256) void fix_combine(
    const int* __restrict__ mrows,
    const float* __restrict__ Pa, const float* __restrict__ Pb,
    const float* __restrict__ bias, float* __restrict__ Co, int N)
{
    int row = blockIdx.x;
    if (row >= *mrows) return;
    int t = threadIdx.x;
    size_t o = (size_t)row * N + t * 4;
    f32x4 a = *(const f32x4*)&Pa[o];
    f32x4 b = *(const f32x4*)&Pb[o];
    f32x4 bi = *(const f32x4*)&bias[t * 4];
    f32x4 r;
#pragma unroll
    for (int j = 0; j < 4; ++j)
        r[j] = fmaxf(a[j] + b[j] + bi[j], 0.f);
    *(f32x4*)&Co[o] = r;
}

// ---------------------------------------------------------------------------
__global__ void sa_pre(const float* __restrict__ state, const float* __restrict__ action,
                       unsigned short* __restrict__ saH)
{
    int idx = blockIdx.x * 256 + threadIdx.x;
    int row = idx / 12, q = idx % 12;
    const float* src = (q < 8) ? (state + (size_t)row * 64 + q * 8)
                               : (action + (size_t)row * 32 + (q - 8) * 8);
    f32x4 v0 = *(const f32x4*)src;
    f32x4 v1 = *(const f32x4*)(src + 4);
    short8 h;
#pragma unroll
    for (int j = 0; j < 8; ++j) {
        float x = (j < 4) ? v0[j] : v1[j - 4];
        h[j] = (short)f2h(x);
    }
    *(short8*)&saH[(size_t)row * 96 + q * 8] = h;
}

// ---------------------------------------------------------------------------
// MFMA VQ score (proven round 18).
// ---------------------------------------------------------------------------
__global__ __launch_bounds__(256) void vq_score(
    const unsigned short* __restrict__ mzH,
    const unsigned short* __restrict__ cbH,
    const float* __restrict__ cbn,
    float4* __restrict__ part)
{
    __shared__ float cn[1024];
    const int tid = threadIdx.x;
    const int w = tid >> 6, lane = tid & 63;
    const int g = lane >> 4, lr = lane & 15;
    const int rowbase = blockIdx.x * 64 + w * 16;

#pragma unroll
    for (int it = 0; it < 4; ++it) cn[tid + it * 256] = cbn[tid + it * 256];

    short8 af[2];
#pragma unroll
    for (int s = 0; s < 2; ++s)
        af[s] = *(const short8*)&mzH[(size_t)(rowbase + lr) * 64 + s * 32 + g * 8];
    __syncthreads();

    float best[4], sec[4];
    int bidx[4];
#pragma unroll
    for (int q = 0; q < 4; ++q) { best[q] = 3.4e38f; sec[q] = 3.4e38f; bidx[q] = 0x7fffffff; }

#pragma unroll 4
    for (int nf = 0; nf < 64; ++nf) {
        int code = nf * 16 + lr;
        short8 bf0 = *(const short8*)&cbH[(size_t)code * 64 + g * 8];
        short8 bf1 = *(const short8*)&cbH[(size_t)code * 64 + 32 + g * 8];
        f32x4 acc;
        acc[0] = 0.f; acc[1] = 0.f; acc[2] = 0.f; acc[3] = 0.f;
        acc = __builtin_amdgcn_mfma_f32_16x16x32_f16(H8(af[0]), H8(bf0), acc, 0, 0, 0);
        acc = __builtin_amdgcn_mfma_f32_16x16x32_f16(H8(af[1]), H8(bf1), acc, 0, 0, 0);
        float cnv = cn[code];
#pragma unroll
        for (int q = 0; q < 4; ++q) {
            float s = cnv - 2.0f * acc[q];
            if (s < best[q] || (s == best[q] && code < bidx[q])) {
                sec[q] = best[q];
                best[q] = s;
                bidx[q] = code;
            } else {
                sec[q] = fminf(sec[q], s);
            }
        }
    }

#pragma unroll
    for (int q = 0; q < 4; ++q) {
#pragma unroll
        for (int m = 1; m < 16; m <<= 1) {
            float ob = __shfl_xor(best[q], m, 64);
            int oi = __shfl_xor(bidx[q], m, 64);
            float os = __shfl_xor(sec[q], m, 64);
            if (ob < best[q] || (ob == best[q] && oi < bidx[q])) {
                sec[q] = fminf(best[q], os);
                best[q] = ob;
                bidx[q] = oi;
            } else {
                sec[q] = fminf(sec[q], ob);
            }
        }
    }
    if (lr == 0) {
#pragma unroll
        for (int q = 0; q < 4; ++q) {
            float4 p;
            p.x = best[q];
            p.y = sec[q];
            p.z = __int_as_float(bidx[q]);
            p.w = 0.f;
            part[(size_t)(rowbase + g * 4 + q)] = p;
        }
    }
}

// ---------------------------------------------------------------------------
// VQ merge (round-20): flag + table-gather latent head + state half of xz.
// mean/std come from CBm/CBs (bitwise-identical to the old per-row matvec).
// ---------------------------------------------------------------------------
__global__ __launch_bounds__(256) void vq_merge(
    const float4* __restrict__ part,
    const float* __restrict__ state_c,
    const float* __restrict__ CBm, const float* __restrict__ CBs,
    const float* __restrict__ eps,
    float* __restrict__ mean_out, float* __restrict__ std_out,
    unsigned short* __restrict__ xz,
    int* __restrict__ ctr, int* __restrict__ list, int rowbase)
{
    __shared__ int sidx[128];

    const int tid = threadIdx.x;
    const int m0 = blockIdx.x * 128;

    if (tid < 128) {
        float4 p0 = part[(size_t)(m0 + tid)];
        sidx[tid] = __float_as_int(p0.z);
        if (p0.y - p0.x < TAU) {
            int p = atomicAdd(ctr, 1);
            list[p] = rowbase + m0 + tid;
        }
    }

    // state half -> xz cols 0..63
    {
        int row = tid >> 1;
        int d0 = (tid & 1) * 32;
        size_t so = (size_t)(m0 + row) * 64 + d0;
        size_t xo = (size_t)(m0 + row) * 128 + d0;
#pragma unroll
        for (int q = 0; q < 8; ++q) {
            f32x4 v = *(const f32x4*)&state_c[so + q * 4];
            unsigned short o[4];
            o[0] = f2bf(v[0]); o[1] = f2bf(v[1]);
            o[2] = f2bf(v[2]); o[3] = f2bf(v[3]);
            *(uint2*)&xz[xo + q * 4] = *(uint2*)o;
        }
    }
    __syncthreads();

    {
        int row = tid >> 1;
        int d0 = (tid & 1) * 32;
        int e = sidx[row];
        const float* cm = CBm + (size_t)e * 64 + d0;
        const float* cs = CBs + (size_t)e * 64 + d0;
        size_t ro = (size_t)(m0 + row) * 64 + d0;
        size_t xo = (size_t)(m0 + row) * 128 + 64 + d0;
#pragma unroll
        for (int q = 0; q < 8; ++q) {
            f32x4 mv = *(const f32x4*)&cm[q * 4];
            f32x4 sv = *(const f32x4*)&cs[q * 4];
            f32x4 ev = *(const f32x4*)&eps[ro + q * 4];
            unsigned short o[4];
#pragma unroll
            for (int j = 0; j < 4; ++j) {
                float z = fmaf(sv[j], ev[j], mv[j]);
                o[j] = f2bf(z);
            }
            *(f32x4*)&mean_out[ro + q * 4] = mv;
            *(f32x4*)&std_out[ro + q * 4] = sv;
            *(uint2*)&xz[xo + q * 4] = *(uint2*)o;
        }
    }
}

// ---------------------------------------------------------------------------
__global__ void gather_fix(const int* __restrict__ ctr, int* __restrict__ meta,
                           const int* __restrict__ list,
                           const float* __restrict__ state,
                           const float* __restrict__ action,
                           float* __restrict__ sa_fix)
{
    int cnt = *ctr; if (cnt > FMAX) cnt = FMAX;
    if (blockIdx.x == 0 && threadIdx.x == 0)
        meta[0] = (cnt + 63) & ~63;
    int t = blockIdx.x * 256 + threadIdx.x;
    if (t >= cnt * 24) return;
    int f = t / 24, q = t % 24;
    size_t g = (size_t)list[f];
    f32x4 v = (q < 16) ? *(const f32x4*)&state[g * 64 + q * 4]
                       : *(const f32x4*)&action[g * 32 + (q - 16) * 4];
    *(f32x4*)&sa_fix[(size_t)f * 96 + q * 4] = v;
}

// ---------------------------------------------------------------------------
// vq_fix (round-20): exact fp32 argmin on flagged rows; latent head via tables.
// ---------------------------------------------------------------------------
__global__ __launch_bounds__(256) void vq_fix(
    const int* __restrict__ ctr, const int* __restrict__ list,
    const float* __restrict__ mz_fix,
    const float* __restrict__ codebook, const float* __restrict__ cbn,
    const float* __restrict__ CBm, const float* __restrict__ CBs,
    const float* __restrict__ eps,
    float* __restrict__ mean_out, float* __restrict__ std_out,
    unsigned short* __restrict__ xz)
{
    __shared__ float mzs[8][64];
    __shared__ float zns[8];
    __shared__ float sv[2048];
    __shared__ int si[2048];
    __shared__ int am_s[8];

    int cnt = *ctr; if (cnt > FMAX) cnt = FMAX;
    const int base = blockIdx.x * 8;
    if (base >= cnt) return;
    const int nr = min(8, cnt - base);
    const int tid = threadIdx.x;

    if (tid < 128) {
        int rr = tid >> 4, q = tid & 15;
        int src = base + ((rr < nr) ? rr : 0);
        *(f32x4*)&mzs[rr][q * 4] = *(const f32x4*)&mz_fix[(size_t)src * 64 + q * 4];
    }
    __syncthreads();
    if (tid < 8) {
        float s = 0.f;
#pragma unroll
        for (int k = 0; k < 64; ++k) s = fmaf(mzs[tid][k], mzs[tid][k], s);
        zns[tid] = s;
    }
    __syncthreads();

    float bb[8];
    int bi[8];
#pragma unroll
    for (int rr = 0; rr < 8; ++rr) { bb[rr] = 3.4e38f; bi[rr] = 0x7fffffff; }
    for (int j = 0; j < 4; ++j) {
        int code = tid + j * 256;
        const f32x4* cp = (const f32x4*)(codebook + (size_t)code * 64);
        float dot[8];
#pragma unroll
        for (int rr = 0; rr < 8; ++rr) dot[rr] = 0.f;
        for (int t = 0; t < 16; ++t) {
            f32x4 cv = cp[t];
#pragma unroll
            for (int e = 0; e < 4; ++e) {
                float cvv = cv[e];
#pragma unroll
                for (int rr = 0; rr < 8; ++rr)
                    dot[rr] = fmaf(mzs[rr][t * 4 + e], cvv, dot[rr]);
            }
        }
        float cnv = cbn[code];
#pragma unroll
        for (int rr = 0; rr < 8; ++rr) {
            float s = (zns[rr] + cnv) - 2.0f * dot[rr];
            if (s < bb[rr] || (s == bb[rr] && code < bi[rr])) {
                bb[rr] = s; bi[rr] = code;
            }
        }
    }
#pragma unroll
    for (int rr = 0; rr < 8; ++rr) {
        sv[rr * 256 + tid] = bb[rr];
        si[rr * 256 + tid] = bi[rr];
    }
    __syncthreads();
    if (tid < 8) {
        float b = 3.4e38f;
        int ix = 0x7fffffff;
        for (int t = 0; t < 256; ++t) {
            float v = sv[tid * 256 + t];
            int iv = si[tid * 256 + t];
            if (v < b || (v == b && iv < ix)) { b = v; ix = iv; }
        }
        am_s[tid] = ix;
    }
    __syncthreads();

    for (int jo = 0; jo < 2; ++jo) {
        int o = tid + jo * 256;
        int rr = o >> 6, d = o & 63;
        if (rr < nr) {
            int e = am_s[rr];
            size_t g = (size_t)list[base + rr];
            float mv = CBm[(size_t)e * 64 + d];
            float sd = CBs[(size_t)e * 64 + d];
            float z = fmaf(sd, eps[g * 64 + d], mv);
            mean_out[g * 64 + d] = mv;
            std_out[g * 64 + d] = sd;
            xz[g * 128 + 64 + d] = f2bf(z);
        }
    }
}

// ---------------------------------------------------------------------------
extern "C" void kernel_launch(void* const* d_in, const int* in_sizes, int n_in,
                              void* d_out, int out_size, void* d_ws, size_t ws_size,
                              hipStream_t stream)
{
    const float* state    = (const float*)d_in[0];
    const float* action   = (const float*)d_in[1];
    const float* eps      = (const float*)d_in[2];
    const float* enc_w1   = (const float*)d_in[3];
    const float* enc_b1   = (const float*)d_in[4];
    const float* enc_w2   = (const float*)d_in[5];
    const float* enc_b2   = (const float*)d_in[6];
    const float* enc_w3   = (const float*)d_in[7];
    const float* enc_b3   = (const float*)d_in[8];
    const float* mean_w   = (const float*)d_in[9];
    const float* mean_b   = (const float*)d_in[10];
    const float* logstd_w = (const float*)d_in[11];
    const float* logstd_b = (const float*)d_in[12];
    const float* codebook = (const float*)d_in[13];
    const float* dec_w1   = (const float*)d_in[14];
    const float* dec_b1   = (const float*)d_in[15];
    const float* dec_w2   = (const float*)d_in[16];
    const float* dec_b2   = (const float*)d_in[17];
    const float* dec_w3   = (const float*)d_in[18];
    const float* dec_b3   = (const float*)d_in[19];

    float* out = (float*)d_out;
    float* u_out = out;
    float* mean_out = out + (size_t)B_TOTAL * 32;
    float* std_out = mean_out + (size_t)B_TOTAL * 64;

    // ---- fixed ws region ----
    char* base = (char*)d_ws;
    float* cbn = (float*)base;                                   // 4096
    unsigned short* W1h = (unsigned short*)(base + 4096);        // fp16
    unsigned short* W2h = (unsigned short*)(base + 397312);      // fp16 (256-layout)
    unsigned short* W3h = (unsigned short*)(base + 4591616);     // fp16
    unsigned short* W4h = (unsigned short*)(base + 4853760);     // bf16
    unsigned short* W5h = (unsigned short*)(base + 5115904);     // bf16 (256-layout)
    unsigned short* W6h = (unsigned short*)(base + 7213056);     // bf16
    int* ctr            = (int*)(base + 7278592);                // 256
    int* flag_list      = (int*)(base + 7278848);                // 262144
    int* meta           = (int*)(base + 7540992);                // 256
    float4* part        = (float4*)(base + 7541248);             // B*16 = 1048576
    unsigned short* cbH = (unsigned short*)(base + 8589824);     // 131072
    float* CBm          = (float*)(base + 8720896);              // 262144
    float* CBs          = (float*)(base + 8983040);              // 262144
    const size_t FIXED  = 9245184;

    unsigned short* xz_g = (unsigned short*)(base + FIXED);      // 16 MB
    const size_t XZ_SZ = (size_t)B_TOTAL * 128 * 2;

    // dyn region: saH 192 + h1H 2048 + h2H 2048 + mz 256 = 4544 B per row
    const size_t per_row = 4544;
    size_t avail = (ws_size > FIXED + XZ_SZ) ? (ws_size - FIXED - XZ_SZ) : 0;
    long maxC = (long)(avail / per_row);
    int C = (int)(maxC / 1024) * 1024;
    if (C > B_TOTAL) C = B_TOTAL;
    if (C < 18432) C = 18432;   // >= fix-alias region (79.43 MB)

    char* dyn = base + FIXED + XZ_SZ;
    unsigned short* saH = (unsigned short*)dyn;                   // [C,96] fp16
    unsigned short* h1H = saH + (size_t)C * 96;                   // [C,1024] fp16
    unsigned short* h2H = h1H + (size_t)C * 1024;                 // [C,1024] fp16
    unsigned short* mzH = h2H + (size_t)C * 1024;                 // [C,64] fp16
    unsigned short* hc = h1H;   // decoder reuse (bf16)
    unsigned short* hd = h2H;

    float* sa_fix  = (float*)dyn;                                 // 2359296
    float* h1_fix  = (float*)(dyn + 2359296);                     // 25165824
    float* h2_fix  = (float*)(dyn + 27525120);                    // 25165824
    float* mz_fix  = (float*)(dyn + 52690944);                    // 1572864
    float* h2_fixB = (float*)(dyn + 54263808);                    // 25165824

    // dynamic-LDS attrs; fall back to proven kernels if denied
    bool deep = hipFuncSetAttribute(
        reinterpret_cast<const void*>(&mfma_gemm128<4, 3, 4, 0>),
        hipFuncAttributeMaxDynamicSharedMemorySize, 49152) == hipSuccess;
    deep = deep && hipFuncSetAttribute(
        reinterpret_cast<const void*>(&mfma_gemm128<1, 4, 1, 0>),
        hipFuncAttributeMaxDynamicSharedMemorySize, 65536) == hipSuccess;
    bool d256 = hipFuncSetAttribute(
        reinterpret_cast<const void*>(&mfma_gemm256<1, 0>),
        hipFuncAttributeMaxDynamicSharedMemorySize, 131072) == hipSuccess;
    d256 = d256 && hipFuncSetAttribute(
        reinterpret_cast<const void*>(&mfma_gemm256<0, 0>),
        hipFuncAttributeMaxDynamicSharedMemorySize, 131072) == hipSuccess;
    d256 = d256 && deep;

    // ---- once per call ----
    cb_norms<<<dim3(4), dim3(256), 0, stream>>>(codebook, cbn, cbH);
    cb_head<<<dim3(256), dim3(256), 0, stream>>>(
        codebook, mean_w, mean_b, logstd_w, logstd_b, CBm, CBs);
    zero_ctr<<<dim3(1), dim3(64), 0, stream>>>(ctr);
    w_xform<2, 128><<<dim3(3, 8), dim3(256), 0, stream>>>(enc_w1, 96, 1024, W1h, nullptr);
    if (d256) wx256<1><<<dim3(16, 8), dim3(256), 0, stream>>>(enc_w2, 1024, W2h);
    else w_xform<2, 128><<<dim3(32, 8), dim3(256), 0, stream>>>(enc_w2, 1024, 1024, W2h, nullptr);
    w_xform<2, 64><<<dim3(32, 1), dim3(256), 0, stream>>>(enc_w3, 1024, 64, W3h, nullptr);
    w_xform<1, 128><<<dim3(4, 8), dim3(256), 0, stream>>>(dec_w1, 128, 1024, W4h, nullptr);
    if (d256) wx256<0><<<dim3(16, 8), dim3(256), 0, stream>>>(dec_w2, 1024, W5h);
    else w_xform<1, 128><<<dim3(32, 8), dim3(256), 0, stream>>>(dec_w2, 1024, 1024, W5h, nullptr);
    w_xform<1, 32><<<dim3(32, 1), dim3(256), 0, stream>>>(dec_w3, 1024, 32, W6h, nullptr);

    // ---- phase A: encoder + VQ ----
    for (int r0 = 0; r0 < B_TOTAL; r0 += C) {
        int M = (r0 + C <= B_TOTAL) ? C : (B_TOTAL - r0);
        int mt = M / 128;

        sa_pre<<<dim3(M * 12 / 256), dim3(256), 0, stream>>>(
            state + (size_t)r0 * SDIM, action + (size_t)r0 * ADIM, saH);

        mfma_gemm128<4, 3, 4, 0><<<dim3(mt * 8), dim3(256), 49152, stream>>>(
            saH, 96, W1h, enc_b1, h1H, 1024);
        if (d256)
            mfma_gemm256<1, 0><<<dim3((M / 256) * 4), dim3(512), 131072, stream>>>(
                h1H, 1024, W2h, enc_b2, h2H, 1024);
        else
            mfma_gemm128<4, 3, 4, 0><<<dim3(mt * 8), dim3(256), 49152, stream>>>(
                h1H, 1024, W2h, enc_b2, h2H, 1024);
        mfma_gemm64<4, 64, 4, 0><<<dim3(M / 64), dim3(256), 0, stream>>>(
            h2H, 1024, W3h, enc_b3, mzH, 64);

        vq_score<<<dim3(M / 64), dim3(256), 0, stream>>>(
            mzH, cbH, cbn, part + r0);
        vq_merge<<<dim3(mt), dim3(256), 0, stream>>>(
            part + r0, state + (size_t)r0 * SDIM, CBm, CBs,
            eps + (size_t)r0 * LDIM,
            mean_out + (size_t)r0 * LDIM, std_out + (size_t)r0 * LDIM,
            xz_g + (size_t)r0 * 128, ctr, flag_list, r0);
    }

    // ---- phase B: exact-fp32 fixup (L2 split-K x2 + combine) ----
    gather_fix<<<dim3(FMAX * 24 / 256), dim3(256), 0, stream>>>(
        ctr, meta, flag_list, state, action, sa_fix);
    gemm_fix<128, 0><<<dim3(FMAX / 64, 8), dim3(256), 0, stream>>>(
        meta, sa_fix, 96, enc_w1, enc_b1, h1_fix, 1024);
    gemm_fix_sk<<<dim3(FMAX / 64, 8, 2), dim3(256), 0, stream>>>(
        meta, h1_fix, 1024, enc_w2, h2_fix, h2_fixB, 1024);
    fix_combine<<<dim3(FMAX), dim3(256), 0, stream>>>(
        meta, h2_fix, h2_fixB, enc_b2, h2_fix, 1024);
    gemm_fix<64, 0><<<dim3(FMAX / 64, 1), dim3(256), 0, stream>>>(
        meta, h2_fix, 1024, enc_w3, enc_b3, mz_fix, 64);
    vq_fix<<<dim3(FMAX / 8), dim3(256), 0, stream>>>(
        ctr, flag_list, mz_fix, codebook, cbn, CBm, CBs, eps,
        mean_out, std_out, xz_g);

    // ---- phase C: decoder ----
    for (int r0 = 0; r0 < B_TOTAL; r0 += C) {
        int M = (r0 + C <= B_TOTAL) ? C : (B_TOTAL - r0);
        int mt = M / 128;

        mfma_gemm128<1, 4, 1, 0><<<dim3(mt * 8), dim3(256), 65536, stream>>>(
            xz_g + (size_t)r0 * 128, 128, W4h, dec_b1, hc, 1024);
        if (d256)
            mfma_gemm256<0, 0><<<dim3((M / 256) * 4), dim3(512), 131072, stream>>>(
                hc, 1024, W5h, dec_b2, hd, 1024);
        else
            mfma_gemm128<1, 4, 1, 0><<<dim3(mt * 8), dim3(256), 65536, stream>>>(
                hc, 1024, W5h, dec_b2, hd, 1024);
        mfma_gemm64<1, 32, 2, 1><<<dim3(M / 64), dim3(256), 0, stream>>>(
            hd, 1024, W6h, dec_b3, u_out + (size_t)r0 * ADIM, 32);
    }
}